// Round 1
// baseline (3599.458 us; speedup 1.0000x reference)
//
#include <hip/hip_runtime.h>
#include <hip/hip_bf16.h>

#define F 128
#define C_CLS 40

// ---------------- prep: deg=1 (self loop), fold importance into W1 ----------------
__global__ __launch_bounds__(256) void prep_kernel(float* deg, float* w1p,
    const float* __restrict__ W1, const float* __restrict__ imp, int n) {
  int i = blockIdx.x * 256 + threadIdx.x;
  if (i < n) deg[i] = 1.0f;
  if (i < F * F) w1p[i] = W1[i] * imp[i & (F - 1)];
}

__global__ __launch_bounds__(256) void count_kernel(const int* __restrict__ col,
                                                    float* deg, int ne) {
  int e = blockIdx.x * 256 + threadIdx.x;
  if (e < ne) unsafeAtomicAdd(&deg[col[e]], 1.0f);
}

__global__ __launch_bounds__(256) void dinv_kernel(const float* __restrict__ deg,
    float* dinv, float* invdeg, int n) {
  int i = blockIdx.x * 256 + threadIdx.x;
  if (i < n) {
    float d = deg[i];
    dinv[i] = rsqrtf(d);
    invdeg[i] = 1.0f / d;
  }
}

// ---------------- GEMM: OUT[r][c] = sum_k IN[r][k]*W[c][k] + bias[c] ----------------
// 64 rows x 128 cols per block, 256 threads, each thread 8 rows x 4 cols.
__global__ __launch_bounds__(256) void gemm128(const float* __restrict__ IN,
    const float* __restrict__ W, const float* __restrict__ bias,
    float* __restrict__ OUT, int nrows, int relu) {
  __shared__ float xT[32][68];   // [k][r], stride 68 (16B aligned, conflict-padded)
  __shared__ float wT[32][132];  // [k][c]
  int t = threadIdx.x;
  int rbase = blockIdx.x * 64;
  int c0 = (t & 31) * 4;
  int r0 = (t >> 5) * 8;
  float acc[8][4];
#pragma unroll
  for (int i = 0; i < 8; ++i)
#pragma unroll
    for (int j = 0; j < 4; ++j) acc[i][j] = 0.f;

  for (int k0 = 0; k0 < F; k0 += 32) {
    __syncthreads();
    for (int idx = t; idx < 64 * 32; idx += 256) {
      int r = idx >> 5, kk = idx & 31;
      int gr = rbase + r;
      xT[kk][r] = (gr < nrows) ? IN[(size_t)gr * F + k0 + kk] : 0.f;
    }
    for (int idx = t; idx < 128 * 32; idx += 256) {
      int c = idx >> 5, kk = idx & 31;
      wT[kk][c] = W[c * F + k0 + kk];
    }
    __syncthreads();
#pragma unroll 8
    for (int k = 0; k < 32; ++k) {
      float4 wv = *(const float4*)&wT[k][c0];
      float4 x0 = *(const float4*)&xT[k][r0];
      float4 x1 = *(const float4*)&xT[k][r0 + 4];
      float xr[8] = {x0.x, x0.y, x0.z, x0.w, x1.x, x1.y, x1.z, x1.w};
      float wc[4] = {wv.x, wv.y, wv.z, wv.w};
#pragma unroll
      for (int i = 0; i < 8; ++i)
#pragma unroll
        for (int j = 0; j < 4; ++j) acc[i][j] += xr[i] * wc[j];
    }
  }
  float4 bv = *(const float4*)&bias[c0];
#pragma unroll
  for (int i = 0; i < 8; ++i) {
    int r = rbase + r0 + i;
    if (r < nrows) {
      float4 o;
      o.x = acc[i][0] + bv.x;
      o.y = acc[i][1] + bv.y;
      o.z = acc[i][2] + bv.z;
      o.w = acc[i][3] + bv.w;
      if (relu) {
        o.x = fmaxf(o.x, 0.f); o.y = fmaxf(o.y, 0.f);
        o.z = fmaxf(o.z, 0.f); o.w = fmaxf(o.w, 0.f);
      }
      *(float4*)&OUT[(size_t)r * F + c0] = o;
    }
  }
}

// ---------------- scatter: C[col[e]] += dinv[row]*dinv[col] * B[row[e]] ----------------
// one thread per (edge, float4-chunk): 32 threads per edge
__global__ __launch_bounds__(256) void scatter_kernel(const int* __restrict__ row,
    const int* __restrict__ col, const float* __restrict__ dinv,
    const float* __restrict__ B, float* __restrict__ C, int ne) {
  int gid = blockIdx.x * 256 + threadIdx.x;
  int e = gid >> 5;
  if (e >= ne) return;
  int j = (gid & 31) << 2;
  int r = row[e], c = col[e];
  float f = dinv[r] * dinv[c];
  float4 v = *(const float4*)&B[(size_t)r * F + j];
  float* dst = &C[(size_t)c * F + j];
  unsafeAtomicAdd(dst + 0, v.x * f);
  unsafeAtomicAdd(dst + 1, v.y * f);
  unsafeAtomicAdd(dst + 2, v.z * f);
  unsafeAtomicAdd(dst + 3, v.w * f);
}

// ---------------- finalize: A = relu((A + B*invdeg)*invdeg + bc) ----------------
__global__ __launch_bounds__(256) void finalize_kernel(float* __restrict__ A,
    const float* __restrict__ B, const float* __restrict__ invdeg,
    const float* __restrict__ bc, int n) {
  int gid = blockIdx.x * 256 + threadIdx.x;
  int i = gid >> 5;
  if (i >= n) return;
  int j = (gid & 31) << 2;
  float id = invdeg[i];
  float4 a = *(float4*)&A[(size_t)i * F + j];
  float4 b = *(const float4*)&B[(size_t)i * F + j];
  float4 bcv = *(const float4*)&bc[j];
  float4 o;
  o.x = fmaxf((a.x + b.x * id) * id + bcv.x, 0.f);
  o.y = fmaxf((a.y + b.y * id) * id + bcv.y, 0.f);
  o.z = fmaxf((a.z + b.z * id) * id + bcv.z, 0.f);
  o.w = fmaxf((a.w + b.w * id) * id + bcv.w, 0.f);
  *(float4*)&A[(size_t)i * F + j] = o;
}

// ---------------- final: logits = X@W2.T + b2, then log_softmax over 40 ----------------
// 256 threads = 4 waves; each wave processes 8 rows; W2 staged in LDS
__global__ __launch_bounds__(256) void logits_kernel(const float* __restrict__ X,
    const float* __restrict__ W2, const float* __restrict__ b2,
    float* __restrict__ out, int nrows) {
  __shared__ float w2s[C_CLS][132];
  __shared__ float b2s[C_CLS];
  __shared__ float xs[4][F];
  int t = threadIdx.x;
  for (int idx = t; idx < C_CLS * F; idx += 256) {
    int j = idx >> 7, k = idx & 127;
    w2s[j][k] = W2[idx];
  }
  if (t < C_CLS) b2s[t] = b2[t];
  __syncthreads();
  int wave = t >> 6, lane = t & 63;
  int rowbase = blockIdx.x * 32 + wave * 8;
  for (int rep = 0; rep < 8; ++rep) {
    int row = rowbase + rep;
    bool valid = row < nrows;
    if (valid) {
      float2 xv = *(const float2*)&X[(size_t)row * F + lane * 2];
      xs[wave][lane * 2] = xv.x;
      xs[wave][lane * 2 + 1] = xv.y;
    }
    float acc = 0.f;
    if (valid && lane < C_CLS) {
      const float* wr = &w2s[lane][0];
#pragma unroll
      for (int k = 0; k < F; k += 4) {
        float4 xv4 = *(const float4*)&xs[wave][k];
        float4 wv4 = *(const float4*)&wr[k];
        acc += xv4.x * wv4.x + xv4.y * wv4.y + xv4.z * wv4.z + xv4.w * wv4.w;
      }
      acc += b2s[lane];
    }
    float val = (valid && lane < C_CLS) ? acc : -INFINITY;
    float m = val;
#pragma unroll
    for (int off = 32; off; off >>= 1) m = fmaxf(m, __shfl_xor(m, off));
    float ev = (valid && lane < C_CLS) ? __expf(acc - m) : 0.f;
    float s = ev;
#pragma unroll
    for (int off = 32; off; off >>= 1) s += __shfl_xor(s, off);
    if (valid && lane < C_CLS) {
      float lse = logf(s) + m;
      out[(size_t)row * C_CLS + lane] = acc - lse;
    }
  }
}

extern "C" void kernel_launch(void* const* d_in, const int* in_sizes, int n_in,
                              void* d_out, int out_size, void* d_ws, size_t ws_size,
                              hipStream_t stream) {
  const float* x    = (const float*)d_in[0];
  const int*   ei   = (const int*)d_in[1];
  const float* imp  = (const float*)d_in[2];
  const float* W1   = (const float*)d_in[3];
  const float* bl1  = (const float*)d_in[4];
  const float* bc1  = (const float*)d_in[5];
  const float* W2   = (const float*)d_in[6];
  const float* bl2  = (const float*)d_in[7];
  const float* bc2  = (const float*)d_in[8];
  const float* W3   = (const float*)d_in[9];
  const float* bl3  = (const float*)d_in[10];
  const float* bc3  = (const float*)d_in[11];
  const float* Wl1  = (const float*)d_in[12];
  const float* bli1 = (const float*)d_in[13];
  const float* Wl2  = (const float*)d_in[14];
  const float* bli2 = (const float*)d_in[15];
  float* out = (float*)d_out;

  const int N = in_sizes[0] / F;      // 100000
  const int E = in_sizes[1] / 2;      // 600000

  float* ws = (float*)d_ws;
  float* A      = ws;
  float* B      = A + (size_t)N * F;
  float* deg    = B + (size_t)N * F;
  float* dinv   = deg + N;
  float* invdeg = dinv + N;
  float* w1p    = invdeg + N;

  const int* rowv = ei;
  const int* colv = ei + E;

  int nbN   = (N + 255) / 256;
  int nbE   = (E + 255) / 256;
  int nbG   = (N + 63) / 64;
  int nbNF  = (N * 32 + 255) / 256;
  int nbEF  = (E * 32 + 255) / 256;
  int nbLo  = (N + 31) / 32;

  prep_kernel<<<nbN, 256, 0, stream>>>(deg, w1p, W1, imp, N);
  count_kernel<<<nbE, 256, 0, stream>>>(colv, deg, E);
  dinv_kernel<<<nbN, 256, 0, stream>>>(deg, dinv, invdeg, N);

  // ---- conv layer 1 (input x, importance folded into w1p) ----
  gemm128<<<nbG, 256, 0, stream>>>(x, w1p, bl1, B, N, 0);
  hipMemsetAsync(A, 0, (size_t)N * F * sizeof(float), stream);
  scatter_kernel<<<nbEF, 256, 0, stream>>>(rowv, colv, dinv, B, A, E);
  finalize_kernel<<<nbNF, 256, 0, stream>>>(A, B, invdeg, bc1, N);

  // ---- conv layer 2 ----
  gemm128<<<nbG, 256, 0, stream>>>(A, W2, bl2, B, N, 0);
  hipMemsetAsync(A, 0, (size_t)N * F * sizeof(float), stream);
  scatter_kernel<<<nbEF, 256, 0, stream>>>(rowv, colv, dinv, B, A, E);
  finalize_kernel<<<nbNF, 256, 0, stream>>>(A, B, invdeg, bc2, N);

  // ---- conv layer 3 ----
  gemm128<<<nbG, 256, 0, stream>>>(A, W3, bl3, B, N, 0);
  hipMemsetAsync(A, 0, (size_t)N * F * sizeof(float), stream);
  scatter_kernel<<<nbEF, 256, 0, stream>>>(rowv, colv, dinv, B, A, E);
  finalize_kernel<<<nbNF, 256, 0, stream>>>(A, B, invdeg, bc3, N);

  // ---- dense head ----
  gemm128<<<nbG, 256, 0, stream>>>(A, Wl1, bli1, B, N, 1);
  logits_kernel<<<nbLo, 256, 0, stream>>>(B, Wl2, bli2, out, N);
}

// Round 2
// 667.816 us; speedup vs baseline: 5.3899x; 5.3899x over previous
//
#include <hip/hip_runtime.h>
#include <hip/hip_bf16.h>

#define F 128
#define C_CLS 40

// ---------------- prep: zero counts, fold importance into W1 ----------------
__global__ __launch_bounds__(256) void prep_kernel(int* cnt, float* w1p,
    const float* __restrict__ W1, const float* __restrict__ imp, int n) {
  int i = blockIdx.x * 256 + threadIdx.x;
  if (i < n) cnt[i] = 0;
  if (i < F * F) w1p[i] = W1[i] * imp[i & (F - 1)];
}

__global__ __launch_bounds__(256) void count_kernel(const int* __restrict__ col,
                                                    int* cnt, int ne) {
  int e = blockIdx.x * 256 + threadIdx.x;
  if (e < ne) atomicAdd(&cnt[col[e]], 1);
}

// deg = cnt + 1 (self-loop); dinv = deg^-0.5; invdeg = 1/deg
__global__ __launch_bounds__(256) void dinv_kernel(const int* __restrict__ cnt,
    float* dinv, float* invdeg, int n) {
  int i = blockIdx.x * 256 + threadIdx.x;
  if (i < n) {
    float d = (float)(cnt[i] + 1);
    dinv[i] = rsqrtf(d);
    invdeg[i] = 1.0f / d;
  }
}

// ---------------- 2-level exclusive scan of cnt -> off ----------------
// scan1: each block scans 1024 elements (256 thr x 4), writes local-exclusive
// values to off[] and its block total to bsums[].
__global__ __launch_bounds__(256) void scan1_kernel(const int* __restrict__ cnt,
    int* off, int* bsums, int n) {
  __shared__ int lds[256];
  int t = threadIdx.x;
  int base = blockIdx.x * 1024 + t * 4;
  int v[4], s = 0;
#pragma unroll
  for (int j = 0; j < 4; ++j) { v[j] = (base + j < n) ? cnt[base + j] : 0; s += v[j]; }
  lds[t] = s;
  __syncthreads();
  int incl = s;
  for (int d = 1; d < 256; d <<= 1) {
    int y = (t >= d) ? lds[t - d] : 0;
    __syncthreads();
    incl += y;
    lds[t] = incl;
    __syncthreads();
  }
  int run = incl - s;
#pragma unroll
  for (int j = 0; j < 4; ++j) {
    if (base + j < n) off[base + j] = run;
    run += v[j];
  }
  if (t == 255) bsums[blockIdx.x] = incl;
}

// scan2: single block exclusive-scans the (<=128) block sums into boffs
__global__ __launch_bounds__(128) void scan2_kernel(const int* __restrict__ bsums,
    int* boffs, int nb) {
  __shared__ int lds[128];
  int t = threadIdx.x;
  int s = (t < nb) ? bsums[t] : 0;
  lds[t] = s;
  __syncthreads();
  int incl = s;
  for (int d = 1; d < 128; d <<= 1) {
    int y = (t >= d) ? lds[t - d] : 0;
    __syncthreads();
    incl += y;
    lds[t] = incl;
    __syncthreads();
  }
  if (t < nb) boffs[t] = incl - s;
}

// scan3: add block offsets; init cursor; set off[n]=E
__global__ __launch_bounds__(256) void scan3_kernel(int* off, int* cursor,
    const int* __restrict__ boffs, int n, int ne) {
  int i = blockIdx.x * 256 + threadIdx.x;
  if (i < n) {
    int v = off[i] + boffs[i >> 10];
    off[i] = v;
    cursor[i] = v;
  }
  if (i == 0) off[n] = ne;
}

// counting-sort fill: csr_src[p] = row, csr_norm[p] = dinv[row]*dinv[col]
__global__ __launch_bounds__(256) void fill_kernel(const int* __restrict__ row,
    const int* __restrict__ col, const float* __restrict__ dinv,
    int* cursor, int* csr_src, float* csr_norm, int ne) {
  int e = blockIdx.x * 256 + threadIdx.x;
  if (e >= ne) return;
  int r = row[e], c = col[e];
  int p = atomicAdd(&cursor[c], 1);
  csr_src[p] = r;
  csr_norm[p] = dinv[r] * dinv[c];
}

// ---------------- GEMM: OUT[r][c] = sum_k IN[r][k]*W[c][k] + bias[c] ----------------
// 64 rows x 128 cols per block, 256 threads, each thread 8 rows x 4 cols.
__global__ __launch_bounds__(256) void gemm128(const float* __restrict__ IN,
    const float* __restrict__ W, const float* __restrict__ bias,
    float* __restrict__ OUT, int nrows, int relu) {
  __shared__ float xT[32][68];
  __shared__ float wT[32][132];
  int t = threadIdx.x;
  int rbase = blockIdx.x * 64;
  int c0 = (t & 31) * 4;
  int r0 = (t >> 5) * 8;
  float acc[8][4];
#pragma unroll
  for (int i = 0; i < 8; ++i)
#pragma unroll
    for (int j = 0; j < 4; ++j) acc[i][j] = 0.f;

  for (int k0 = 0; k0 < F; k0 += 32) {
    __syncthreads();
    for (int idx = t; idx < 64 * 32; idx += 256) {
      int r = idx >> 5, kk = idx & 31;
      int gr = rbase + r;
      xT[kk][r] = (gr < nrows) ? IN[(size_t)gr * F + k0 + kk] : 0.f;
    }
    for (int idx = t; idx < 128 * 32; idx += 256) {
      int c = idx >> 5, kk = idx & 31;
      wT[kk][c] = W[c * F + k0 + kk];
    }
    __syncthreads();
#pragma unroll 8
    for (int k = 0; k < 32; ++k) {
      float4 wv = *(const float4*)&wT[k][c0];
      float4 x0 = *(const float4*)&xT[k][r0];
      float4 x1 = *(const float4*)&xT[k][r0 + 4];
      float xr[8] = {x0.x, x0.y, x0.z, x0.w, x1.x, x1.y, x1.z, x1.w};
      float wc[4] = {wv.x, wv.y, wv.z, wv.w};
#pragma unroll
      for (int i = 0; i < 8; ++i)
#pragma unroll
        for (int j = 0; j < 4; ++j) acc[i][j] += xr[i] * wc[j];
    }
  }
  float4 bv = *(const float4*)&bias[c0];
#pragma unroll
  for (int i = 0; i < 8; ++i) {
    int r = rbase + r0 + i;
    if (r < nrows) {
      float4 o;
      o.x = acc[i][0] + bv.x;
      o.y = acc[i][1] + bv.y;
      o.z = acc[i][2] + bv.z;
      o.w = acc[i][3] + bv.w;
      if (relu) {
        o.x = fmaxf(o.x, 0.f); o.y = fmaxf(o.y, 0.f);
        o.z = fmaxf(o.z, 0.f); o.w = fmaxf(o.w, 0.f);
      }
      *(float4*)&OUT[(size_t)r * F + c0] = o;
    }
  }
}

// ---------------- gather + finalize (fused) ----------------
// one wave (64 threads) per target node; each lane owns 2 features (float2).
// A[i] = relu((sum_e nrm[e]*B[src[e]] + B[i]*invdeg[i]) * invdeg[i] + bc)
__global__ __launch_bounds__(256) void gather_kernel(const int* __restrict__ off,
    const int* __restrict__ csr_src, const float* __restrict__ csr_norm,
    const float* __restrict__ B, const float* __restrict__ invdeg,
    const float* __restrict__ bc, float* __restrict__ A, int n) {
  int node = blockIdx.x * 4 + (threadIdx.x >> 6);
  if (node >= n) return;
  int lane = threadIdx.x & 63;
  int j = lane * 2;
  int e = off[node], e1 = off[node + 1];
  float ax = 0.f, ay = 0.f;
  // 2-wide software pipeline for a little more MLP
  for (; e + 1 < e1; e += 2) {
    int s0 = csr_src[e], s1 = csr_src[e + 1];
    float f0 = csr_norm[e], f1 = csr_norm[e + 1];
    float2 v0 = *(const float2*)&B[(size_t)s0 * F + j];
    float2 v1 = *(const float2*)&B[(size_t)s1 * F + j];
    ax += f0 * v0.x + f1 * v1.x;
    ay += f0 * v0.y + f1 * v1.y;
  }
  if (e < e1) {
    int s0 = csr_src[e];
    float f0 = csr_norm[e];
    float2 v0 = *(const float2*)&B[(size_t)s0 * F + j];
    ax += f0 * v0.x;
    ay += f0 * v0.y;
  }
  float id = invdeg[node];
  float2 self = *(const float2*)&B[(size_t)node * F + j];
  float2 bcv = *(const float2*)&bc[j];
  float2 o;
  o.x = fmaxf((ax + self.x * id) * id + bcv.x, 0.f);
  o.y = fmaxf((ay + self.y * id) * id + bcv.y, 0.f);
  *(float2*)&A[(size_t)node * F + j] = o;
}

// ---------------- final: logits = X@W2.T + b2, then log_softmax over 40 ----------------
__global__ __launch_bounds__(256) void logits_kernel(const float* __restrict__ X,
    const float* __restrict__ W2, const float* __restrict__ b2,
    float* __restrict__ out, int nrows) {
  __shared__ float w2s[C_CLS][132];
  __shared__ float b2s[C_CLS];
  __shared__ float xs[4][F];
  int t = threadIdx.x;
  for (int idx = t; idx < C_CLS * F; idx += 256) {
    int j = idx >> 7, k = idx & 127;
    w2s[j][k] = W2[idx];
  }
  if (t < C_CLS) b2s[t] = b2[t];
  __syncthreads();
  int wave = t >> 6, lane = t & 63;
  int rowbase = blockIdx.x * 32 + wave * 8;
  for (int rep = 0; rep < 8; ++rep) {
    int row = rowbase + rep;
    bool valid = row < nrows;
    if (valid) {
      float2 xv = *(const float2*)&X[(size_t)row * F + lane * 2];
      xs[wave][lane * 2] = xv.x;
      xs[wave][lane * 2 + 1] = xv.y;
    }
    float acc = 0.f;
    if (valid && lane < C_CLS) {
      const float* wr = &w2s[lane][0];
#pragma unroll
      for (int k = 0; k < F; k += 4) {
        float4 xv4 = *(const float4*)&xs[wave][k];
        float4 wv4 = *(const float4*)&wr[k];
        acc += xv4.x * wv4.x + xv4.y * wv4.y + xv4.z * wv4.z + xv4.w * wv4.w;
      }
      acc += b2s[lane];
    }
    float val = (valid && lane < C_CLS) ? acc : -INFINITY;
    float m = val;
#pragma unroll
    for (int off = 32; off; off >>= 1) m = fmaxf(m, __shfl_xor(m, off));
    float ev = (valid && lane < C_CLS) ? __expf(acc - m) : 0.f;
    float s = ev;
#pragma unroll
    for (int off = 32; off; off >>= 1) s += __shfl_xor(s, off);
    if (valid && lane < C_CLS) {
      float lse = logf(s) + m;
      out[(size_t)row * C_CLS + lane] = acc - lse;
    }
  }
}

extern "C" void kernel_launch(void* const* d_in, const int* in_sizes, int n_in,
                              void* d_out, int out_size, void* d_ws, size_t ws_size,
                              hipStream_t stream) {
  const float* x    = (const float*)d_in[0];
  const int*   ei   = (const int*)d_in[1];
  const float* imp  = (const float*)d_in[2];
  const float* W1   = (const float*)d_in[3];
  const float* bl1  = (const float*)d_in[4];
  const float* bc1  = (const float*)d_in[5];
  const float* W2   = (const float*)d_in[6];
  const float* bl2  = (const float*)d_in[7];
  const float* bc2  = (const float*)d_in[8];
  const float* W3   = (const float*)d_in[9];
  const float* bl3  = (const float*)d_in[10];
  const float* bc3  = (const float*)d_in[11];
  const float* Wl1  = (const float*)d_in[12];
  const float* bli1 = (const float*)d_in[13];
  const float* Wl2  = (const float*)d_in[14];
  const float* bli2 = (const float*)d_in[15];
  float* out = (float*)d_out;

  const int N = in_sizes[0] / F;      // 100000
  const int E = in_sizes[1] / 2;      // 600000

  float* ws = (float*)d_ws;
  float* A      = ws;                         // N*F
  float* B      = A + (size_t)N * F;          // N*F
  float* w1p    = B + (size_t)N * F;          // F*F
  float* dinv   = w1p + F * F;                // N
  float* invdeg = dinv + N;                   // N
  float* csr_norm = invdeg + N;               // E
  int*   cnt    = (int*)(csr_norm + E);       // N
  int*   off    = cnt + N;                    // N+1
  int*   cursor = off + N + 1;                // N
  int*   csr_src = cursor + N;                // E
  int*   bsums  = csr_src + E;                // <=128
  int*   boffs  = bsums + 128;                // <=128

  const int* rowv = ei;
  const int* colv = ei + E;

  int nbN  = (N + 255) / 256;
  int nbE  = (E + 255) / 256;
  int nbG  = (N + 63) / 64;
  int nbS1 = (N + 1023) / 1024;               // 98 blocks, <=128
  int nbGa = (N + 3) / 4;
  int nbLo = (N + 31) / 32;

  // ---- one-time CSR build (reused for all 3 conv layers) ----
  prep_kernel<<<nbN, 256, 0, stream>>>(cnt, w1p, W1, imp, N);
  count_kernel<<<nbE, 256, 0, stream>>>(colv, cnt, E);
  dinv_kernel<<<nbN, 256, 0, stream>>>(cnt, dinv, invdeg, N);
  scan1_kernel<<<nbS1, 256, 0, stream>>>(cnt, off, bsums, N);
  scan2_kernel<<<1, 128, 0, stream>>>(bsums, boffs, nbS1);
  scan3_kernel<<<nbN, 256, 0, stream>>>(off, cursor, boffs, N, E);
  fill_kernel<<<nbE, 256, 0, stream>>>(rowv, colv, dinv, cursor, csr_src, csr_norm, E);

  // ---- conv layer 1 (importance folded into w1p) ----
  gemm128<<<nbG, 256, 0, stream>>>(x, w1p, bl1, B, N, 0);
  gather_kernel<<<nbGa, 256, 0, stream>>>(off, csr_src, csr_norm, B, invdeg, bc1, A, N);

  // ---- conv layer 2 ----
  gemm128<<<nbG, 256, 0, stream>>>(A, W2, bl2, B, N, 0);
  gather_kernel<<<nbGa, 256, 0, stream>>>(off, csr_src, csr_norm, B, invdeg, bc2, A, N);

  // ---- conv layer 3 ----
  gemm128<<<nbG, 256, 0, stream>>>(A, W3, bl3, B, N, 0);
  gather_kernel<<<nbGa, 256, 0, stream>>>(off, csr_src, csr_norm, B, invdeg, bc3, A, N);

  // ---- dense head ----
  gemm128<<<nbG, 256, 0, stream>>>(A, Wl1, bli1, B, N, 1);
  logits_kernel<<<nbLo, 256, 0, stream>>>(B, Wl2, bli2, out, N);
}

// Round 3
// 580.011 us; speedup vs baseline: 6.2058x; 1.1514x over previous
//
#include <hip/hip_runtime.h>
#include <hip/hip_bf16.h>

#define F 128
#define C_CLS 40

typedef __attribute__((ext_vector_type(8))) short short8;
typedef __attribute__((ext_vector_type(4))) float float4v;

// ---------------- prep: zero counts, fold importance into W1 ----------------
__global__ __launch_bounds__(256) void prep_kernel(int* cnt, float* w1p,
    const float* __restrict__ W1, const float* __restrict__ imp, int n) {
  int i = blockIdx.x * 256 + threadIdx.x;
  if (i < n) cnt[i] = 0;
  if (i < F * F) w1p[i] = W1[i] * imp[i & (F - 1)];
}

__global__ __launch_bounds__(256) void count_kernel(const int* __restrict__ col,
                                                    int* cnt, int ne) {
  int e = blockIdx.x * 256 + threadIdx.x;
  if (e < ne) atomicAdd(&cnt[col[e]], 1);
}

__global__ __launch_bounds__(256) void dinv_kernel(const int* __restrict__ cnt,
    float* dinv, float* invdeg, int n) {
  int i = blockIdx.x * 256 + threadIdx.x;
  if (i < n) {
    float d = (float)(cnt[i] + 1);
    dinv[i] = rsqrtf(d);
    invdeg[i] = 1.0f / d;
  }
}

// ---------------- 2-level exclusive scan ----------------
__global__ __launch_bounds__(256) void scan1_kernel(const int* __restrict__ cnt,
    int* off, int* bsums, int n) {
  __shared__ int lds[256];
  int t = threadIdx.x;
  int base = blockIdx.x * 1024 + t * 4;
  int v[4], s = 0;
#pragma unroll
  for (int j = 0; j < 4; ++j) { v[j] = (base + j < n) ? cnt[base + j] : 0; s += v[j]; }
  lds[t] = s;
  __syncthreads();
  int incl = s;
  for (int d = 1; d < 256; d <<= 1) {
    int y = (t >= d) ? lds[t - d] : 0;
    __syncthreads();
    incl += y;
    lds[t] = incl;
    __syncthreads();
  }
  int run = incl - s;
#pragma unroll
  for (int j = 0; j < 4; ++j) {
    if (base + j < n) off[base + j] = run;
    run += v[j];
  }
  if (t == 255) bsums[blockIdx.x] = incl;
}

__global__ __launch_bounds__(128) void scan2_kernel(const int* __restrict__ bsums,
    int* boffs, int nb) {
  __shared__ int lds[128];
  int t = threadIdx.x;
  int s = (t < nb) ? bsums[t] : 0;
  lds[t] = s;
  __syncthreads();
  int incl = s;
  for (int d = 1; d < 128; d <<= 1) {
    int y = (t >= d) ? lds[t - d] : 0;
    __syncthreads();
    incl += y;
    lds[t] = incl;
    __syncthreads();
  }
  if (t < nb) boffs[t] = incl - s;
}

__global__ __launch_bounds__(256) void scan3_kernel(int* off, int* cursor,
    const int* __restrict__ boffs, int n, int ne) {
  int i = blockIdx.x * 256 + threadIdx.x;
  if (i < n) {
    int v = off[i] + boffs[i >> 10];
    off[i] = v;
    cursor[i] = v;
  }
  if (i == 0) off[n] = ne;
}

__global__ __launch_bounds__(256) void fill_kernel(const int* __restrict__ row,
    const int* __restrict__ col, const float* __restrict__ dinv,
    int* cursor, int* csr_src, float* csr_norm, int ne) {
  int e = blockIdx.x * 256 + threadIdx.x;
  if (e >= ne) return;
  int r = row[e], c = col[e];
  int p = atomicAdd(&cursor[c], 1);
  csr_src[p] = r;
  csr_norm[p] = dinv[r] * dinv[c];
}

// ---------------- split fp32 -> bf16 hi + bf16 lo ----------------
__device__ inline void split_bf16(float f, unsigned short& hi, unsigned short& lo) {
  __hip_bfloat16 h = __float2bfloat16(f);
  float fh = __bfloat162float(h);
  __hip_bfloat16 l = __float2bfloat16(f - fh);
  hi = *(unsigned short*)&h;
  lo = *(unsigned short*)&l;
}

// XOR swizzle to break staging-write bank conflicts (reader applies same map)
__device__ inline int swz(int lane) { return lane ^ ((lane >> 4) & 3); }

// ---------------- MFMA GEMM: OUT[r][c] = sum_k IN[r][k]*W[c][k] + bias[c] ----------------
// Block: 128 rows x 128 cols, 256 thr (4 waves, each 32 rows x 128 cols).
// Split-precision: acc += Ahi*Whi + Ahi*Wlo + Alo*Whi  (~fp32 accuracy).
// LDS: fragment-ready 16B chunks: chunk(rt, ks, lane) holds
//   X[rt*16 + (lane&15)][k0 + ks*32 + (lane>>4)*8 + j], j=0..7  (bf16)
__global__ __launch_bounds__(256) void gemm_mfma(const float* __restrict__ IN,
    const float* __restrict__ W, const float* __restrict__ bias,
    float* __restrict__ OUT, int nrows, int relu) {
  __shared__ unsigned short Ah[8192], Al[8192], Wh[8192], Wl[8192];  // 64 KB
  const int t = threadIdx.x;
  const int rbase = blockIdx.x * 128;
  const int w = t >> 6, lane = t & 63;
  const int quad = lane >> 4, cl = lane & 15;

  float4v acc[2][8];
#pragma unroll
  for (int rt = 0; rt < 2; ++rt)
#pragma unroll
    for (int ct = 0; ct < 8; ++ct) acc[rt][ct] = (float4v){0.f, 0.f, 0.f, 0.f};

  for (int kc = 0; kc < 2; ++kc) {
    const int k0 = kc * 64;
    __syncthreads();
    // ---- stage A and W (1024 (row,octet) pairs each; 8 floats -> hi/lo b128) ----
#pragma unroll
    for (int pp = 0; pp < 4; ++pp) {
      int pair = t + pp * 256;
      int r = pair >> 3, oct = pair & 7;
      int rt = r >> 4, ks = oct >> 2;
      int ln = swz((r & 15) + ((oct & 3) << 4));
      int chunk = ((rt * 2 + ks) * 64 + ln) * 8;
      // A
      {
        int gr = rbase + r;
        float v[8];
        if (gr < nrows) {
          float4 f0 = *(const float4*)&IN[(size_t)gr * F + k0 + oct * 8];
          float4 f1 = *(const float4*)&IN[(size_t)gr * F + k0 + oct * 8 + 4];
          v[0] = f0.x; v[1] = f0.y; v[2] = f0.z; v[3] = f0.w;
          v[4] = f1.x; v[5] = f1.y; v[6] = f1.z; v[7] = f1.w;
        } else {
#pragma unroll
          for (int j = 0; j < 8; ++j) v[j] = 0.f;
        }
        unsigned short hi[8], lo[8];
#pragma unroll
        for (int j = 0; j < 8; ++j) split_bf16(v[j], hi[j], lo[j]);
        *(short8*)&Ah[chunk] = *(short8*)hi;
        *(short8*)&Al[chunk] = *(short8*)lo;
      }
      // W (always 128 valid cols)
      {
        float4 f0 = *(const float4*)&W[(size_t)r * F + k0 + oct * 8];
        float4 f1 = *(const float4*)&W[(size_t)r * F + k0 + oct * 8 + 4];
        float v[8] = {f0.x, f0.y, f0.z, f0.w, f1.x, f1.y, f1.z, f1.w};
        unsigned short hi[8], lo[8];
#pragma unroll
        for (int j = 0; j < 8; ++j) split_bf16(v[j], hi[j], lo[j]);
        *(short8*)&Wh[chunk] = *(short8*)hi;
        *(short8*)&Wl[chunk] = *(short8*)lo;
      }
    }
    __syncthreads();
    // ---- MFMA compute ----
    const int sl = swz(lane);
#pragma unroll
    for (int ks = 0; ks < 2; ++ks) {
      short8 a_h[2], a_l[2];
#pragma unroll
      for (int rt = 0; rt < 2; ++rt) {
        int chunk = (((w * 2 + rt) * 2 + ks) * 64 + sl) * 8;
        a_h[rt] = *(short8*)&Ah[chunk];
        a_l[rt] = *(short8*)&Al[chunk];
      }
#pragma unroll
      for (int ct = 0; ct < 8; ++ct) {
        int chunk = ((ct * 2 + ks) * 64 + sl) * 8;
        short8 b_h = *(short8*)&Wh[chunk];
        short8 b_l = *(short8*)&Wl[chunk];
#pragma unroll
        for (int rt = 0; rt < 2; ++rt) {
          acc[rt][ct] = __builtin_amdgcn_mfma_f32_16x16x32_bf16(a_h[rt], b_h, acc[rt][ct], 0, 0, 0);
          acc[rt][ct] = __builtin_amdgcn_mfma_f32_16x16x32_bf16(a_h[rt], b_l, acc[rt][ct], 0, 0, 0);
          acc[rt][ct] = __builtin_amdgcn_mfma_f32_16x16x32_bf16(a_l[rt], b_h, acc[rt][ct], 0, 0, 0);
        }
      }
    }
  }
  // ---- epilogue: bias (+relu), C/D layout col=lane&15, row=quad*4+reg ----
#pragma unroll
  for (int ct = 0; ct < 8; ++ct) {
    int gc = ct * 16 + cl;
    float bv = bias[gc];
#pragma unroll
    for (int rt = 0; rt < 2; ++rt) {
#pragma unroll
      for (int reg = 0; reg < 4; ++reg) {
        int gr = rbase + w * 32 + rt * 16 + quad * 4 + reg;
        if (gr < nrows) {
          float val = acc[rt][ct][reg] + bv;
          if (relu) val = fmaxf(val, 0.f);
          OUT[(size_t)gr * F + gc] = val;
        }
      }
    }
  }
}

// ---------------- gather + finalize (fused) ----------------
__global__ __launch_bounds__(256) void gather_kernel(const int* __restrict__ off,
    const int* __restrict__ csr_src, const float* __restrict__ csr_norm,
    const float* __restrict__ B, const float* __restrict__ invdeg,
    const float* __restrict__ bc, float* __restrict__ A, int n) {
  int node = blockIdx.x * 4 + (threadIdx.x >> 6);
  if (node >= n) return;
  int lane = threadIdx.x & 63;
  int j = lane * 2;
  int e = off[node], e1 = off[node + 1];
  float ax = 0.f, ay = 0.f;
  for (; e + 1 < e1; e += 2) {
    int s0 = csr_src[e], s1 = csr_src[e + 1];
    float f0 = csr_norm[e], f1 = csr_norm[e + 1];
    float2 v0 = *(const float2*)&B[(size_t)s0 * F + j];
    float2 v1 = *(const float2*)&B[(size_t)s1 * F + j];
    ax += f0 * v0.x + f1 * v1.x;
    ay += f0 * v0.y + f1 * v1.y;
  }
  if (e < e1) {
    int s0 = csr_src[e];
    float f0 = csr_norm[e];
    float2 v0 = *(const float2*)&B[(size_t)s0 * F + j];
    ax += f0 * v0.x;
    ay += f0 * v0.y;
  }
  float id = invdeg[node];
  float2 self = *(const float2*)&B[(size_t)node * F + j];
  float2 bcv = *(const float2*)&bc[j];
  float2 o;
  o.x = fmaxf((ax + self.x * id) * id + bcv.x, 0.f);
  o.y = fmaxf((ay + self.y * id) * id + bcv.y, 0.f);
  *(float2*)&A[(size_t)node * F + j] = o;
}

// ---------------- final: logits = X@W2.T + b2, then log_softmax over 40 ----------------
__global__ __launch_bounds__(256) void logits_kernel(const float* __restrict__ X,
    const float* __restrict__ W2, const float* __restrict__ b2,
    float* __restrict__ out, int nrows) {
  __shared__ float w2s[C_CLS][132];
  __shared__ float b2s[C_CLS];
  __shared__ float xs[4][F];
  int t = threadIdx.x;
  for (int idx = t; idx < C_CLS * F; idx += 256) {
    int j = idx >> 7, k = idx & 127;
    w2s[j][k] = W2[idx];
  }
  if (t < C_CLS) b2s[t] = b2[t];
  __syncthreads();
  int wave = t >> 6, lane = t & 63;
  int rowbase = blockIdx.x * 32 + wave * 8;
  for (int rep = 0; rep < 8; ++rep) {
    int row = rowbase + rep;
    bool valid = row < nrows;
    if (valid) {
      float2 xv = *(const float2*)&X[(size_t)row * F + lane * 2];
      xs[wave][lane * 2] = xv.x;
      xs[wave][lane * 2 + 1] = xv.y;
    }
    float acc = 0.f;
    if (valid && lane < C_CLS) {
      const float* wr = &w2s[lane][0];
#pragma unroll
      for (int k = 0; k < F; k += 4) {
        float4 xv4 = *(const float4*)&xs[wave][k];
        float4 wv4 = *(const float4*)&wr[k];
        acc += xv4.x * wv4.x + xv4.y * wv4.y + xv4.z * wv4.z + xv4.w * wv4.w;
      }
      acc += b2s[lane];
    }
    float val = (valid && lane < C_CLS) ? acc : -INFINITY;
    float m = val;
#pragma unroll
    for (int off = 32; off; off >>= 1) m = fmaxf(m, __shfl_xor(m, off));
    float ev = (valid && lane < C_CLS) ? __expf(acc - m) : 0.f;
    float s = ev;
#pragma unroll
    for (int off = 32; off; off >>= 1) s += __shfl_xor(s, off);
    if (valid && lane < C_CLS) {
      float lse = logf(s) + m;
      out[(size_t)row * C_CLS + lane] = acc - lse;
    }
  }
}

extern "C" void kernel_launch(void* const* d_in, const int* in_sizes, int n_in,
                              void* d_out, int out_size, void* d_ws, size_t ws_size,
                              hipStream_t stream) {
  const float* x    = (const float*)d_in[0];
  const int*   ei   = (const int*)d_in[1];
  const float* imp  = (const float*)d_in[2];
  const float* W1   = (const float*)d_in[3];
  const float* bl1  = (const float*)d_in[4];
  const float* bc1  = (const float*)d_in[5];
  const float* W2   = (const float*)d_in[6];
  const float* bl2  = (const float*)d_in[7];
  const float* bc2  = (const float*)d_in[8];
  const float* W3   = (const float*)d_in[9];
  const float* bl3  = (const float*)d_in[10];
  const float* bc3  = (const float*)d_in[11];
  const float* Wl1  = (const float*)d_in[12];
  const float* bli1 = (const float*)d_in[13];
  const float* Wl2  = (const float*)d_in[14];
  const float* bli2 = (const float*)d_in[15];
  float* out = (float*)d_out;

  const int N = in_sizes[0] / F;      // 100000
  const int E = in_sizes[1] / 2;      // 600000

  float* ws = (float*)d_ws;
  float* A      = ws;                         // N*F
  float* B      = A + (size_t)N * F;          // N*F
  float* w1p    = B + (size_t)N * F;          // F*F
  float* dinv   = w1p + F * F;                // N
  float* invdeg = dinv + N;                   // N
  float* csr_norm = invdeg + N;               // E
  int*   cnt    = (int*)(csr_norm + E);       // N
  int*   off    = cnt + N;                    // N+1
  int*   cursor = off + N + 1;                // N
  int*   csr_src = cursor + N;                // E
  int*   bsums  = csr_src + E;                // <=128
  int*   boffs  = bsums + 128;                // <=128

  const int* rowv = ei;
  const int* colv = ei + E;

  int nbN  = (N + 255) / 256;
  int nbE  = (E + 255) / 256;
  int nbG  = (N + 127) / 128;
  int nbS1 = (N + 1023) / 1024;
  int nbGa = (N + 3) / 4;
  int nbLo = (N + 31) / 32;

  // ---- one-time CSR build (reused for all 3 conv layers) ----
  prep_kernel<<<nbN, 256, 0, stream>>>(cnt, w1p, W1, imp, N);
  count_kernel<<<nbE, 256, 0, stream>>>(colv, cnt, E);
  dinv_kernel<<<nbN, 256, 0, stream>>>(cnt, dinv, invdeg, N);
  scan1_kernel<<<nbS1, 256, 0, stream>>>(cnt, off, bsums, N);
  scan2_kernel<<<1, 128, 0, stream>>>(bsums, boffs, nbS1);
  scan3_kernel<<<nbN, 256, 0, stream>>>(off, cursor, boffs, N, E);
  fill_kernel<<<nbE, 256, 0, stream>>>(rowv, colv, dinv, cursor, csr_src, csr_norm, E);

  // ---- conv layer 1 (importance folded into w1p) ----
  gemm_mfma<<<nbG, 256, 0, stream>>>(x, w1p, bl1, B, N, 0);
  gather_kernel<<<nbGa, 256, 0, stream>>>(off, csr_src, csr_norm, B, invdeg, bc1, A, N);

  // ---- conv layer 2 ----
  gemm_mfma<<<nbG, 256, 0, stream>>>(A, W2, bl2, B, N, 0);
  gather_kernel<<<nbGa, 256, 0, stream>>>(off, csr_src, csr_norm, B, invdeg, bc2, A, N);

  // ---- conv layer 3 ----
  gemm_mfma<<<nbG, 256, 0, stream>>>(A, W3, bl3, B, N, 0);
  gather_kernel<<<nbGa, 256, 0, stream>>>(off, csr_src, csr_norm, B, invdeg, bc3, A, N);

  // ---- dense head ----
  gemm_mfma<<<nbG, 256, 0, stream>>>(A, Wl1, bli1, B, N, 1);
  logits_kernel<<<nbLo, 256, 0, stream>>>(B, Wl2, bli2, out, N);
}

// Round 4
// 521.086 us; speedup vs baseline: 6.9076x; 1.1131x over previous
//
#include <hip/hip_runtime.h>
#include <hip/hip_bf16.h>

#define F 128
#define C_CLS 40

typedef __attribute__((ext_vector_type(8))) short short8;
typedef __attribute__((ext_vector_type(4))) float float4v;

// ---------------- prep: zero counts, fold importance into W1 ----------------
__global__ __launch_bounds__(256) void prep_kernel(int* cnt, float* w1p,
    const float* __restrict__ W1, const float* __restrict__ imp, int n) {
  int i = blockIdx.x * 256 + threadIdx.x;
  if (i < n) cnt[i] = 0;
  if (i < F * F) w1p[i] = W1[i] * imp[i & (F - 1)];
}

__global__ __launch_bounds__(256) void count_kernel(const int* __restrict__ col,
                                                    int* cnt, int ne) {
  int e = blockIdx.x * 256 + threadIdx.x;
  if (e < ne) atomicAdd(&cnt[col[e]], 1);
}

__global__ __launch_bounds__(256) void dinv_kernel(const int* __restrict__ cnt,
    float* dinv, float* invdeg, int n) {
  int i = blockIdx.x * 256 + threadIdx.x;
  if (i < n) {
    float d = (float)(cnt[i] + 1);
    dinv[i] = rsqrtf(d);
    invdeg[i] = 1.0f / d;
  }
}

// ---------------- 2-level exclusive scan ----------------
__global__ __launch_bounds__(256) void scan1_kernel(const int* __restrict__ cnt,
    int* off, int* bsums, int n) {
  __shared__ int lds[256];
  int t = threadIdx.x;
  int base = blockIdx.x * 1024 + t * 4;
  int v[4], s = 0;
#pragma unroll
  for (int j = 0; j < 4; ++j) { v[j] = (base + j < n) ? cnt[base + j] : 0; s += v[j]; }
  lds[t] = s;
  __syncthreads();
  int incl = s;
  for (int d = 1; d < 256; d <<= 1) {
    int y = (t >= d) ? lds[t - d] : 0;
    __syncthreads();
    incl += y;
    lds[t] = incl;
    __syncthreads();
  }
  int run = incl - s;
#pragma unroll
  for (int j = 0; j < 4; ++j) {
    if (base + j < n) off[base + j] = run;
    run += v[j];
  }
  if (t == 255) bsums[blockIdx.x] = incl;
}

__global__ __launch_bounds__(128) void scan2_kernel(const int* __restrict__ bsums,
    int* boffs, int nb) {
  __shared__ int lds[128];
  int t = threadIdx.x;
  int s = (t < nb) ? bsums[t] : 0;
  lds[t] = s;
  __syncthreads();
  int incl = s;
  for (int d = 1; d < 128; d <<= 1) {
    int y = (t >= d) ? lds[t - d] : 0;
    __syncthreads();
    incl += y;
    lds[t] = incl;
    __syncthreads();
  }
  if (t < nb) boffs[t] = incl - s;
}

__global__ __launch_bounds__(256) void scan3_kernel(int* off, int* cursor,
    const int* __restrict__ boffs, int n, int ne) {
  int i = blockIdx.x * 256 + threadIdx.x;
  if (i < n) {
    int v = off[i] + boffs[i >> 10];
    off[i] = v;
    cursor[i] = v;
  }
  if (i == 0) off[n] = ne;
}

__global__ __launch_bounds__(256) void fill_kernel(const int* __restrict__ row,
    const int* __restrict__ col, const float* __restrict__ dinv,
    int* cursor, int* csr_src, float* csr_norm, int ne) {
  int e = blockIdx.x * 256 + threadIdx.x;
  if (e >= ne) return;
  int r = row[e], c = col[e];
  int p = atomicAdd(&cursor[c], 1);
  csr_src[p] = r;
  csr_norm[p] = dinv[r] * dinv[c];
}

// ---------------- split fp32 -> bf16 hi + bf16 lo ----------------
__device__ inline void split_bf16(float f, unsigned short& hi, unsigned short& lo) {
  __hip_bfloat16 h = __float2bfloat16(f);
  float fh = __bfloat162float(h);
  __hip_bfloat16 l = __float2bfloat16(f - fh);
  hi = *(unsigned short*)&h;
  lo = *(unsigned short*)&l;
}

__device__ inline int swz(int lane) { return lane ^ ((lane >> 4) & 3); }

// ---------------- MFMA GEMM: OUT[r][c] = sum_k IN[r][k]*W[c][k] + bias[c] ----------------
__global__ __launch_bounds__(256) void gemm_mfma(const float* __restrict__ IN,
    const float* __restrict__ W, const float* __restrict__ bias,
    float* __restrict__ OUT, int nrows, int relu) {
  __shared__ unsigned short Ah[8192], Al[8192], Wh[8192], Wl[8192];  // 64 KB
  const int t = threadIdx.x;
  const int rbase = blockIdx.x * 128;
  const int w = t >> 6, lane = t & 63;
  const int quad = lane >> 4, cl = lane & 15;

  float4v acc[2][8];
#pragma unroll
  for (int rt = 0; rt < 2; ++rt)
#pragma unroll
    for (int ct = 0; ct < 8; ++ct) acc[rt][ct] = (float4v){0.f, 0.f, 0.f, 0.f};

  for (int kc = 0; kc < 2; ++kc) {
    const int k0 = kc * 64;
    __syncthreads();
#pragma unroll
    for (int pp = 0; pp < 4; ++pp) {
      int pair = t + pp * 256;
      int r = pair >> 3, oct = pair & 7;
      int rt = r >> 4, ks = oct >> 2;
      int ln = swz((r & 15) + ((oct & 3) << 4));
      int chunk = ((rt * 2 + ks) * 64 + ln) * 8;
      {
        int gr = rbase + r;
        float v[8];
        if (gr < nrows) {
          float4 f0 = *(const float4*)&IN[(size_t)gr * F + k0 + oct * 8];
          float4 f1 = *(const float4*)&IN[(size_t)gr * F + k0 + oct * 8 + 4];
          v[0] = f0.x; v[1] = f0.y; v[2] = f0.z; v[3] = f0.w;
          v[4] = f1.x; v[5] = f1.y; v[6] = f1.z; v[7] = f1.w;
        } else {
#pragma unroll
          for (int j = 0; j < 8; ++j) v[j] = 0.f;
        }
        unsigned short hi[8], lo[8];
#pragma unroll
        for (int j = 0; j < 8; ++j) split_bf16(v[j], hi[j], lo[j]);
        *(short8*)&Ah[chunk] = *(short8*)hi;
        *(short8*)&Al[chunk] = *(short8*)lo;
      }
      {
        float4 f0 = *(const float4*)&W[(size_t)r * F + k0 + oct * 8];
        float4 f1 = *(const float4*)&W[(size_t)r * F + k0 + oct * 8 + 4];
        float v[8] = {f0.x, f0.y, f0.z, f0.w, f1.x, f1.y, f1.z, f1.w};
        unsigned short hi[8], lo[8];
#pragma unroll
        for (int j = 0; j < 8; ++j) split_bf16(v[j], hi[j], lo[j]);
        *(short8*)&Wh[chunk] = *(short8*)hi;
        *(short8*)&Wl[chunk] = *(short8*)lo;
      }
    }
    __syncthreads();
    const int sl = swz(lane);
#pragma unroll
    for (int ks = 0; ks < 2; ++ks) {
      short8 a_h[2], a_l[2];
#pragma unroll
      for (int rt = 0; rt < 2; ++rt) {
        int chunk = (((w * 2 + rt) * 2 + ks) * 64 + sl) * 8;
        a_h[rt] = *(short8*)&Ah[chunk];
        a_l[rt] = *(short8*)&Al[chunk];
      }
#pragma unroll
      for (int ct = 0; ct < 8; ++ct) {
        int chunk = ((ct * 2 + ks) * 64 + sl) * 8;
        short8 b_h = *(short8*)&Wh[chunk];
        short8 b_l = *(short8*)&Wl[chunk];
#pragma unroll
        for (int rt = 0; rt < 2; ++rt) {
          acc[rt][ct] = __builtin_amdgcn_mfma_f32_16x16x32_bf16(a_h[rt], b_h, acc[rt][ct], 0, 0, 0);
          acc[rt][ct] = __builtin_amdgcn_mfma_f32_16x16x32_bf16(a_h[rt], b_l, acc[rt][ct], 0, 0, 0);
          acc[rt][ct] = __builtin_amdgcn_mfma_f32_16x16x32_bf16(a_l[rt], b_h, acc[rt][ct], 0, 0, 0);
        }
      }
    }
  }
#pragma unroll
  for (int ct = 0; ct < 8; ++ct) {
    int gc = ct * 16 + cl;
    float bv = bias[gc];
#pragma unroll
    for (int rt = 0; rt < 2; ++rt) {
#pragma unroll
      for (int reg = 0; reg < 4; ++reg) {
        int gr = rbase + w * 32 + rt * 16 + quad * 4 + reg;
        if (gr < nrows) {
          float val = acc[rt][ct][reg] + bv;
          if (relu) val = fmaxf(val, 0.f);
          OUT[(size_t)gr * F + gc] = val;
        }
      }
    }
  }
}

// ---------------- gather + finalize (fused) ----------------
// one wave per node; the two wave-halves take edges e (even) and e+1 (odd);
// each lane owns 4 features (float4). Halves combined via shfl_xor(32).
__global__ __launch_bounds__(256) void gather_kernel(const int* __restrict__ off,
    const int* __restrict__ csr_src, const float* __restrict__ csr_norm,
    const float* __restrict__ B, const float* __restrict__ invdeg,
    const float* __restrict__ bc, float* __restrict__ A, int n) {
  int node = blockIdx.x * 4 + (threadIdx.x >> 6);
  if (node >= n) return;
  int lane = threadIdx.x & 63;
  int half = lane >> 5;
  int j = (lane & 31) * 4;
  int e0 = off[node], e1 = off[node + 1];
  float4 a = {0.f, 0.f, 0.f, 0.f};
  for (int e = e0 + half; e < e1; e += 2) {
    int s = csr_src[e];
    float f = csr_norm[e];
    float4 v = *(const float4*)&B[(size_t)s * F + j];
    a.x += f * v.x; a.y += f * v.y; a.z += f * v.z; a.w += f * v.w;
  }
  a.x += __shfl_xor(a.x, 32);
  a.y += __shfl_xor(a.y, 32);
  a.z += __shfl_xor(a.z, 32);
  a.w += __shfl_xor(a.w, 32);
  if (half == 0) {
    float id = invdeg[node];
    float4 self = *(const float4*)&B[(size_t)node * F + j];
    float4 bcv = *(const float4*)&bc[j];
    float4 o;
    o.x = fmaxf((a.x + self.x * id) * id + bcv.x, 0.f);
    o.y = fmaxf((a.y + self.y * id) * id + bcv.y, 0.f);
    o.z = fmaxf((a.z + self.z * id) * id + bcv.z, 0.f);
    o.w = fmaxf((a.w + self.w * id) * id + bcv.w, 0.f);
    *(float4*)&A[(size_t)node * F + j] = o;
  }
}

// ---------------- logits via MFMA + fused log_softmax ----------------
// 4 waves/block, one 16-row tile per wave. Classes padded 40 -> 48 (3 tiles).
// Split bf16 hi/lo for fp32-equivalent accuracy.
__global__ __launch_bounds__(256) void logits_mfma(const float* __restrict__ X,
    const float* __restrict__ W2, const float* __restrict__ b2,
    float* __restrict__ out, int nrows) {
  __shared__ unsigned short W2h[6144], W2l[6144];  // (ct,ks,lane) -> 8 shorts
  __shared__ float b2s[48];
  const int t = threadIdx.x;
#pragma unroll
  for (int pp = 0; pp < 3; ++pp) {
    int idx = t + pp * 256;              // 0..767 = 3ct x 4ks x 64lane
    int ln = idx & 63, ks = (idx >> 6) & 3, ct = idx >> 8;
    int nn = ct * 16 + (ln & 15);
    int k = ks * 32 + (ln >> 4) * 8;
    float v[8];
    if (nn < C_CLS) {
      float4 f0 = *(const float4*)&W2[(size_t)nn * F + k];
      float4 f1 = *(const float4*)&W2[(size_t)nn * F + k + 4];
      v[0] = f0.x; v[1] = f0.y; v[2] = f0.z; v[3] = f0.w;
      v[4] = f1.x; v[5] = f1.y; v[6] = f1.z; v[7] = f1.w;
    } else {
#pragma unroll
      for (int j = 0; j < 8; ++j) v[j] = 0.f;
    }
    unsigned short hi[8], lo[8];
#pragma unroll
    for (int j = 0; j < 8; ++j) split_bf16(v[j], hi[j], lo[j]);
    int chunk = ((ct * 4 + ks) * 64 + ln) * 8;
    *(short8*)&W2h[chunk] = *(short8*)hi;
    *(short8*)&W2l[chunk] = *(short8*)lo;
  }
  if (t < 48) b2s[t] = (t < C_CLS) ? b2[t] : -1e30f;
  __syncthreads();

  const int w = t >> 6, lane = t & 63;
  const int quad = lane >> 4, cl = lane & 15;
  const int row0 = (blockIdx.x * 4 + w) * 16;

  float4v acc[3];
#pragma unroll
  for (int ct = 0; ct < 3; ++ct) acc[ct] = (float4v){0.f, 0.f, 0.f, 0.f};

#pragma unroll
  for (int ks = 0; ks < 4; ++ks) {
    int gr = row0 + cl;
    float v[8];
    if (gr < nrows) {
      float4 f0 = *(const float4*)&X[(size_t)gr * F + ks * 32 + quad * 8];
      float4 f1 = *(const float4*)&X[(size_t)gr * F + ks * 32 + quad * 8 + 4];
      v[0] = f0.x; v[1] = f0.y; v[2] = f0.z; v[3] = f0.w;
      v[4] = f1.x; v[5] = f1.y; v[6] = f1.z; v[7] = f1.w;
    } else {
#pragma unroll
      for (int j = 0; j < 8; ++j) v[j] = 0.f;
    }
    unsigned short hi[8], lo[8];
#pragma unroll
    for (int j = 0; j < 8; ++j) split_bf16(v[j], hi[j], lo[j]);
    short8 a_h = *(short8*)hi, a_l = *(short8*)lo;
#pragma unroll
    for (int ct = 0; ct < 3; ++ct) {
      int chunk = ((ct * 4 + ks) * 64 + lane) * 8;
      short8 b_h = *(short8*)&W2h[chunk];
      short8 b_l = *(short8*)&W2l[chunk];
      acc[ct] = __builtin_amdgcn_mfma_f32_16x16x32_bf16(a_h, b_h, acc[ct], 0, 0, 0);
      acc[ct] = __builtin_amdgcn_mfma_f32_16x16x32_bf16(a_h, b_l, acc[ct], 0, 0, 0);
      acc[ct] = __builtin_amdgcn_mfma_f32_16x16x32_bf16(a_l, b_h, acc[ct], 0, 0, 0);
    }
  }

  // bias + per-row log_softmax; row r = quad*4+reg lives in the 16 lanes of quad
  float b0 = b2s[cl], b1 = b2s[16 + cl], b2v = b2s[32 + cl];
  float lse[4];
#pragma unroll
  for (int reg = 0; reg < 4; ++reg) {
    float v0 = acc[0][reg] + b0;
    float v1 = acc[1][reg] + b1;
    float v2 = acc[2][reg] + b2v;
    acc[0][reg] = v0; acc[1][reg] = v1; acc[2][reg] = v2;
    float m = fmaxf(fmaxf(v0, v1), v2);
#pragma unroll
    for (int o = 1; o < 16; o <<= 1) m = fmaxf(m, __shfl_xor(m, o));
    float s = __expf(v0 - m) + __expf(v1 - m) + __expf(v2 - m);
#pragma unroll
    for (int o = 1; o < 16; o <<= 1) s += __shfl_xor(s, o);
    lse[reg] = logf(s) + m;
  }
#pragma unroll
  for (int reg = 0; reg < 4; ++reg) {
    int gr = row0 + quad * 4 + reg;
    if (gr < nrows) {
      out[(size_t)gr * C_CLS + cl] = acc[0][reg] - lse[reg];
      out[(size_t)gr * C_CLS + 16 + cl] = acc[1][reg] - lse[reg];
      if (cl < 8) out[(size_t)gr * C_CLS + 32 + cl] = acc[2][reg] - lse[reg];
    }
  }
}

extern "C" void kernel_launch(void* const* d_in, const int* in_sizes, int n_in,
                              void* d_out, int out_size, void* d_ws, size_t ws_size,
                              hipStream_t stream) {
  const float* x    = (const float*)d_in[0];
  const int*   ei   = (const int*)d_in[1];
  const float* imp  = (const float*)d_in[2];
  const float* W1   = (const float*)d_in[3];
  const float* bl1  = (const float*)d_in[4];
  const float* bc1  = (const float*)d_in[5];
  const float* W2   = (const float*)d_in[6];
  const float* bl2  = (const float*)d_in[7];
  const float* bc2  = (const float*)d_in[8];
  const float* W3   = (const float*)d_in[9];
  const float* bl3  = (const float*)d_in[10];
  const float* bc3  = (const float*)d_in[11];
  const float* Wl1  = (const float*)d_in[12];
  const float* bli1 = (const float*)d_in[13];
  const float* Wl2  = (const float*)d_in[14];
  const float* bli2 = (const float*)d_in[15];
  float* out = (float*)d_out;

  const int N = in_sizes[0] / F;      // 100000
  const int E = in_sizes[1] / 2;      // 600000

  float* ws = (float*)d_ws;
  float* A      = ws;                         // N*F
  float* B      = A + (size_t)N * F;          // N*F
  float* w1p    = B + (size_t)N * F;          // F*F
  float* dinv   = w1p + F * F;                // N
  float* invdeg = dinv + N;                   // N
  float* csr_norm = invdeg + N;               // E
  int*   cnt    = (int*)(csr_norm + E);       // N
  int*   off    = cnt + N;                    // N+1
  int*   cursor = off + N + 1;                // N
  int*   csr_src = cursor + N;                // E
  int*   bsums  = csr_src + E;                // <=128
  int*   boffs  = bsums + 128;                // <=128

  const int* rowv = ei;
  const int* colv = ei + E;

  int nbN  = (N + 255) / 256;
  int nbE  = (E + 255) / 256;
  int nbG  = (N + 127) / 128;
  int nbS1 = (N + 1023) / 1024;
  int nbGa = (N + 3) / 4;
  int nbLo = (N + 63) / 64;

  // ---- one-time CSR build (reused for all 3 conv layers) ----
  prep_kernel<<<nbN, 256, 0, stream>>>(cnt, w1p, W1, imp, N);
  count_kernel<<<nbE, 256, 0, stream>>>(colv, cnt, E);
  dinv_kernel<<<nbN, 256, 0, stream>>>(cnt, dinv, invdeg, N);
  scan1_kernel<<<nbS1, 256, 0, stream>>>(cnt, off, bsums, N);
  scan2_kernel<<<1, 128, 0, stream>>>(bsums, boffs, nbS1);
  scan3_kernel<<<nbN, 256, 0, stream>>>(off, cursor, boffs, N, E);
  fill_kernel<<<nbE, 256, 0, stream>>>(rowv, colv, dinv, cursor, csr_src, csr_norm, E);

  // ---- conv layer 1 (importance folded into w1p) ----
  gemm_mfma<<<nbG, 256, 0, stream>>>(x, w1p, bl1, B, N, 0);
  gather_kernel<<<nbGa, 256, 0, stream>>>(off, csr_src, csr_norm, B, invdeg, bc1, A, N);

  // ---- conv layer 2 ----
  gemm_mfma<<<nbG, 256, 0, stream>>>(A, W2, bl2, B, N, 0);
  gather_kernel<<<nbGa, 256, 0, stream>>>(off, csr_src, csr_norm, B, invdeg, bc2, A, N);

  // ---- conv layer 3 ----
  gemm_mfma<<<nbG, 256, 0, stream>>>(A, W3, bl3, B, N, 0);
  gather_kernel<<<nbGa, 256, 0, stream>>>(off, csr_src, csr_norm, B, invdeg, bc3, A, N);

  // ---- dense head ----
  gemm_mfma<<<nbG, 256, 0, stream>>>(A, Wl1, bli1, B, N, 1);
  logits_mfma<<<nbLo, 256, 0, stream>>>(B, Wl2, bli2, out, N);
}

// Round 5
// 482.104 us; speedup vs baseline: 7.4661x; 1.0809x over previous
//
#include <hip/hip_runtime.h>
#include <hip/hip_bf16.h>

#define F 128
#define C_CLS 40

typedef __attribute__((ext_vector_type(8))) short short8;
typedef __attribute__((ext_vector_type(4))) float float4v;
typedef unsigned short ushort;

__device__ inline float bf2f(ushort u) {
  unsigned int x = ((unsigned int)u) << 16;
  return __builtin_bit_cast(float, x);
}
__device__ inline ushort f2bf(float f) {
  __hip_bfloat16 h = __float2bfloat16(f);
  return __builtin_bit_cast(ushort, h);
}
__device__ inline void split_bf16(float f, ushort& hi, ushort& lo) {
  hi = f2bf(f);
  lo = f2bf(f - bf2f(hi));
}
__device__ inline int swz(int lane) { return lane ^ ((lane >> 4) & 3); }

// ---------------- prep: zero counts, fold importance into W1 (fp32) ----------------
__global__ __launch_bounds__(256) void prep_kernel(int* cnt, float* w1p,
    const float* __restrict__ W1, const float* __restrict__ imp, int n) {
  int i = blockIdx.x * 256 + threadIdx.x;
  if (i < n) cnt[i] = 0;
  if (i < F * F) w1p[i] = W1[i] * imp[i & (F - 1)];
}

// ---------------- convert x (fp32) -> X16 (bf16), 8 elems/thread ----------------
__global__ __launch_bounds__(256) void cvt_kernel(const float* __restrict__ x,
    ushort* __restrict__ X16, int n8) {
  int i = blockIdx.x * 256 + threadIdx.x;
  if (i >= n8) return;
  float4 f0 = *(const float4*)&x[(size_t)i * 8];
  float4 f1 = *(const float4*)&x[(size_t)i * 8 + 4];
  ushort h[8] = {f2bf(f0.x), f2bf(f0.y), f2bf(f0.z), f2bf(f0.w),
                 f2bf(f1.x), f2bf(f1.y), f2bf(f1.z), f2bf(f1.w)};
  *(short8*)&X16[(size_t)i * 8] = *(short8*)h;
}

// ---------------- one-time weight split into fragment-ordered hi/lo ----------------
// Main planes p in {w1p, W2, W3, Wl1}: 2048 chunks each, layout
//   chunk c = kc*1024 + ct*128 + ks*64 + ln  (slot-lane ln; data lane = swz(ln))
//   element j: col = ct*16 + (dl&15), k = kc*64 + ks*32 + (dl>>4)*8 + j
// Head plane (48x128 padded): 768 chunks: c = ct*256 + ks*64 + ln (no swizzle)
__global__ __launch_bounds__(256) void wsplit_kernel(
    const float* __restrict__ w1p, const float* __restrict__ W2,
    const float* __restrict__ W3, const float* __restrict__ Wl1,
    const float* __restrict__ Wh2, ushort* __restrict__ WhP,
    ushort* __restrict__ WlP, ushort* __restrict__ W2hH, ushort* __restrict__ W2lH) {
  int ci = blockIdx.x * 256 + threadIdx.x;
  if (ci < 8192) {
    const float* src[4] = {w1p, W2, W3, Wl1};
    int p = ci >> 11, c = ci & 2047;
    int kc = c >> 10, ct = (c >> 7) & 7, ks = (c >> 6) & 1, ln = c & 63;
    int dl = swz(ln);
    int col = ct * 16 + (dl & 15);
    int k = kc * 64 + ks * 32 + (dl >> 4) * 8;
    float4 f0 = *(const float4*)&src[p][(size_t)col * F + k];
    float4 f1 = *(const float4*)&src[p][(size_t)col * F + k + 4];
    float v[8] = {f0.x, f0.y, f0.z, f0.w, f1.x, f1.y, f1.z, f1.w};
    ushort hi[8], lo[8];
#pragma unroll
    for (int j = 0; j < 8; ++j) split_bf16(v[j], hi[j], lo[j]);
    *(short8*)&WhP[(size_t)ci * 8] = *(short8*)hi;
    *(short8*)&WlP[(size_t)ci * 8] = *(short8*)lo;
  } else if (ci < 8192 + 768) {
    int c = ci - 8192;
    int ct = c >> 8, ks = (c >> 6) & 3, ln = c & 63;
    int col = ct * 16 + (ln & 15);
    int k = ks * 32 + (ln >> 4) * 8;
    float v[8];
    if (col < C_CLS) {
      float4 f0 = *(const float4*)&Wh2[(size_t)col * F + k];
      float4 f1 = *(const float4*)&Wh2[(size_t)col * F + k + 4];
      v[0] = f0.x; v[1] = f0.y; v[2] = f0.z; v[3] = f0.w;
      v[4] = f1.x; v[5] = f1.y; v[6] = f1.z; v[7] = f1.w;
    } else {
#pragma unroll
      for (int j = 0; j < 8; ++j) v[j] = 0.f;
    }
    ushort hi[8], lo[8];
#pragma unroll
    for (int j = 0; j < 8; ++j) split_bf16(v[j], hi[j], lo[j]);
    *(short8*)&W2hH[(size_t)c * 8] = *(short8*)hi;
    *(short8*)&W2lH[(size_t)c * 8] = *(short8*)lo;
  }
}

__global__ __launch_bounds__(256) void count_kernel(const int* __restrict__ col,
                                                    int* cnt, int ne) {
  int e = blockIdx.x * 256 + threadIdx.x;
  if (e < ne) atomicAdd(&cnt[col[e]], 1);
}

__global__ __launch_bounds__(256) void dinv_kernel(const int* __restrict__ cnt,
    float* dinv, float* invdeg, int n) {
  int i = blockIdx.x * 256 + threadIdx.x;
  if (i < n) {
    float d = (float)(cnt[i] + 1);
    dinv[i] = rsqrtf(d);
    invdeg[i] = 1.0f / d;
  }
}

// ---------------- 2-level exclusive scan ----------------
__global__ __launch_bounds__(256) void scan1_kernel(const int* __restrict__ cnt,
    int* off, int* bsums, int n) {
  __shared__ int lds[256];
  int t = threadIdx.x;
  int base = blockIdx.x * 1024 + t * 4;
  int v[4], s = 0;
#pragma unroll
  for (int j = 0; j < 4; ++j) { v[j] = (base + j < n) ? cnt[base + j] : 0; s += v[j]; }
  lds[t] = s;
  __syncthreads();
  int incl = s;
  for (int d = 1; d < 256; d <<= 1) {
    int y = (t >= d) ? lds[t - d] : 0;
    __syncthreads();
    incl += y;
    lds[t] = incl;
    __syncthreads();
  }
  int run = incl - s;
#pragma unroll
  for (int j = 0; j < 4; ++j) {
    if (base + j < n) off[base + j] = run;
    run += v[j];
  }
  if (t == 255) bsums[blockIdx.x] = incl;
}

__global__ __launch_bounds__(128) void scan2_kernel(const int* __restrict__ bsums,
    int* boffs, int nb) {
  __shared__ int lds[128];
  int t = threadIdx.x;
  int s = (t < nb) ? bsums[t] : 0;
  lds[t] = s;
  __syncthreads();
  int incl = s;
  for (int d = 1; d < 128; d <<= 1) {
    int y = (t >= d) ? lds[t - d] : 0;
    __syncthreads();
    incl += y;
    lds[t] = incl;
    __syncthreads();
  }
  if (t < nb) boffs[t] = incl - s;
}

__global__ __launch_bounds__(256) void scan3_kernel(int* off, int* cursor,
    const int* __restrict__ boffs, int n, int ne) {
  int i = blockIdx.x * 256 + threadIdx.x;
  if (i < n) {
    int v = off[i] + boffs[i >> 10];
    off[i] = v;
    cursor[i] = v;
  }
  if (i == 0) off[n] = ne;
}

__global__ __launch_bounds__(256) void fill_kernel(const int* __restrict__ row,
    const int* __restrict__ col, const float* __restrict__ dinv,
    int* cursor, int* csr_src, float* csr_norm, int ne) {
  int e = blockIdx.x * 256 + threadIdx.x;
  if (e >= ne) return;
  int r = row[e], c = col[e];
  int p = atomicAdd(&cursor[c], 1);
  csr_src[p] = r;
  csr_norm[p] = dinv[r] * dinv[c];
}

// ---------------- bf16 MFMA GEMM: OUT = bf16(relu?(IN @ W.T + bias)) ----------------
// IN: bf16 row-major [nrows x 128]; W: pre-split hi/lo fragment-ordered.
// Block 128x128, 4 waves, split-weight: acc += a*Wh + a*Wl.
__global__ __launch_bounds__(256) void gemm_bf16(const ushort* __restrict__ IN,
    const ushort* __restrict__ Wh, const ushort* __restrict__ Wl,
    const float* __restrict__ bias, ushort* __restrict__ OUT, int nrows, int relu) {
  __shared__ ushort sA[8192], sWh[8192], sWl[8192];  // 48 KB
  const int t = threadIdx.x;
  const int rbase = blockIdx.x * 128;
  const int w = t >> 6, lane = t & 63;
  const int quad = lane >> 4, cl = lane & 15;

  float4v acc[2][8];
#pragma unroll
  for (int rt = 0; rt < 2; ++rt)
#pragma unroll
    for (int ct = 0; ct < 8; ++ct) acc[rt][ct] = (float4v){0.f, 0.f, 0.f, 0.f};

  for (int kc = 0; kc < 2; ++kc) {
    const int k0 = kc * 64;
    __syncthreads();
    // stage A: 1024 chunks (8 rt x 2 ks x 64 dl), 4 per thread
#pragma unroll
    for (int pp = 0; pp < 4; ++pp) {
      int ci = t + pp * 256;
      int dl = ci & 63, ks = (ci >> 6) & 1, rt = ci >> 7;
      int slot = ((rt * 2 + ks) * 64 + swz(dl)) * 8;
      int gr = rbase + rt * 16 + (dl & 15);
      int k = k0 + ks * 32 + (dl >> 4) * 8;
      short8 v;
      if (gr < nrows) v = *(const short8*)&IN[(size_t)gr * F + k];
      else v = (short8){0, 0, 0, 0, 0, 0, 0, 0};
      *(short8*)&sA[slot] = v;
      // stage W hi/lo: pure sequential copy (swizzle baked in global layout)
      *(short8*)&sWh[ci * 8] = *(const short8*)&Wh[(size_t)(kc * 1024 + ci) * 8];
      *(short8*)&sWl[ci * 8] = *(const short8*)&Wl[(size_t)(kc * 1024 + ci) * 8];
    }
    __syncthreads();
    const int sl = swz(lane);
#pragma unroll
    for (int ks = 0; ks < 2; ++ks) {
      short8 a[2];
#pragma unroll
      for (int rt = 0; rt < 2; ++rt)
        a[rt] = *(short8*)&sA[(((w * 2 + rt) * 2 + ks) * 64 + sl) * 8];
#pragma unroll
      for (int ct = 0; ct < 8; ++ct) {
        int chunk = ((ct * 2 + ks) * 64 + sl) * 8;
        short8 b_h = *(short8*)&sWh[chunk];
        short8 b_l = *(short8*)&sWl[chunk];
#pragma unroll
        for (int rt = 0; rt < 2; ++rt) {
          acc[rt][ct] = __builtin_amdgcn_mfma_f32_16x16x32_bf16(a[rt], b_h, acc[rt][ct], 0, 0, 0);
          acc[rt][ct] = __builtin_amdgcn_mfma_f32_16x16x32_bf16(a[rt], b_l, acc[rt][ct], 0, 0, 0);
        }
      }
    }
  }
  // epilogue: bias (+relu), C/D layout col=lane&15, row=quad*4+reg; store bf16
#pragma unroll
  for (int ct = 0; ct < 8; ++ct) {
    int gc = ct * 16 + cl;
    float bv = bias[gc];
#pragma unroll
    for (int rt = 0; rt < 2; ++rt) {
#pragma unroll
      for (int reg = 0; reg < 4; ++reg) {
        int gr = rbase + w * 32 + rt * 16 + quad * 4 + reg;
        if (gr < nrows) {
          float val = acc[rt][ct][reg] + bv;
          if (relu) val = fmaxf(val, 0.f);
          OUT[(size_t)gr * F + gc] = f2bf(val);
        }
      }
    }
  }
}

// ---------------- gather + finalize (fused), bf16 in / bf16 out ----------------
// one wave per node; halves take alternating edges; lane owns 4 feats (8 B).
__global__ __launch_bounds__(256) void gather_kernel(const int* __restrict__ off,
    const int* __restrict__ csr_src, const float* __restrict__ csr_norm,
    const ushort* __restrict__ B, const float* __restrict__ invdeg,
    const float* __restrict__ bc, ushort* __restrict__ A, int n) {
  int node = blockIdx.x * 4 + (threadIdx.x >> 6);
  if (node >= n) return;
  int lane = threadIdx.x & 63;
  int half = lane >> 5;
  int j = (lane & 31) * 4;
  int e0 = off[node], e1 = off[node + 1];
  float ax = 0.f, ay = 0.f, az = 0.f, aw = 0.f;
  for (int e = e0 + half; e < e1; e += 2) {
    int s = csr_src[e];
    float f = csr_norm[e];
    ushort4 v = *(const ushort4*)&B[(size_t)s * F + j];
    ax += f * bf2f(v.x); ay += f * bf2f(v.y);
    az += f * bf2f(v.z); aw += f * bf2f(v.w);
  }
  ax += __shfl_xor(ax, 32);
  ay += __shfl_xor(ay, 32);
  az += __shfl_xor(az, 32);
  aw += __shfl_xor(aw, 32);
  if (half == 0) {
    float id = invdeg[node];
    ushort4 sv = *(const ushort4*)&B[(size_t)node * F + j];
    float4 bcv = *(const float4*)&bc[j];
    ushort4 o;
    o.x = f2bf(fmaxf((ax + bf2f(sv.x) * id) * id + bcv.x, 0.f));
    o.y = f2bf(fmaxf((ay + bf2f(sv.y) * id) * id + bcv.y, 0.f));
    o.z = f2bf(fmaxf((az + bf2f(sv.z) * id) * id + bcv.z, 0.f));
    o.w = f2bf(fmaxf((aw + bf2f(sv.w) * id) * id + bcv.w, 0.f));
    *(ushort4*)&A[(size_t)node * F + j] = o;
  }
}

// ---------------- logits via MFMA + fused log_softmax (bf16 input) ----------------
__global__ __launch_bounds__(256) void logits_mfma(const ushort* __restrict__ X,
    const ushort* __restrict__ W2h, const ushort* __restrict__ W2l,
    const float* __restrict__ b2, float* __restrict__ out, int nrows) {
  __shared__ ushort sWh[6144], sWl[6144];
  __shared__ float b2s[48];
  const int t = threadIdx.x;
#pragma unroll
  for (int pp = 0; pp < 3; ++pp) {
    int c = t + pp * 256;
    *(short8*)&sWh[c * 8] = *(const short8*)&W2h[(size_t)c * 8];
    *(short8*)&sWl[c * 8] = *(const short8*)&W2l[(size_t)c * 8];
  }
  if (t < 48) b2s[t] = (t < C_CLS) ? b2[t] : -1e30f;
  __syncthreads();

  const int w = t >> 6, lane = t & 63;
  const int quad = lane >> 4, cl = lane & 15;
  const int row0 = (blockIdx.x * 4 + w) * 16;

  float4v acc[3];
#pragma unroll
  for (int ct = 0; ct < 3; ++ct) acc[ct] = (float4v){0.f, 0.f, 0.f, 0.f};

#pragma unroll
  for (int ks = 0; ks < 4; ++ks) {
    int gr = row0 + cl;
    short8 a;
    if (gr < nrows) a = *(const short8*)&X[(size_t)gr * F + ks * 32 + quad * 8];
    else a = (short8){0, 0, 0, 0, 0, 0, 0, 0};
#pragma unroll
    for (int ct = 0; ct < 3; ++ct) {
      int chunk = ((ct * 4 + ks) * 64 + lane) * 8;
      short8 b_h = *(short8*)&sWh[chunk];
      short8 b_l = *(short8*)&sWl[chunk];
      acc[ct] = __builtin_amdgcn_mfma_f32_16x16x32_bf16(a, b_h, acc[ct], 0, 0, 0);
      acc[ct] = __builtin_amdgcn_mfma_f32_16x16x32_bf16(a, b_l, acc[ct], 0, 0, 0);
    }
  }

  float b0 = b2s[cl], b1 = b2s[16 + cl], b2v = b2s[32 + cl];
  float lse[4];
#pragma unroll
  for (int reg = 0; reg < 4; ++reg) {
    float v0 = acc[0][reg] + b0;
    float v1 = acc[1][reg] + b1;
    float v2 = acc[2][reg] + b2v;
    acc[0][reg] = v0; acc[1][reg] = v1; acc[2][reg] = v2;
    float m = fmaxf(fmaxf(v0, v1), v2);
#pragma unroll
    for (int o = 1; o < 16; o <<= 1) m = fmaxf(m, __shfl_xor(m, o));
    float s = __expf(v0 - m) + __expf(v1 - m) + __expf(v2 - m);
#pragma unroll
    for (int o = 1; o < 16; o <<= 1) s += __shfl_xor(s, o);
    lse[reg] = logf(s) + m;
  }
#pragma unroll
  for (int reg = 0; reg < 4; ++reg) {
    int gr = row0 + quad * 4 + reg;
    if (gr < nrows) {
      out[(size_t)gr * C_CLS + cl] = acc[0][reg] - lse[reg];
      out[(size_t)gr * C_CLS + 16 + cl] = acc[1][reg] - lse[reg];
      if (cl < 8) out[(size_t)gr * C_CLS + 32 + cl] = acc[2][reg] - lse[reg];
    }
  }
}

extern "C" void kernel_launch(void* const* d_in, const int* in_sizes, int n_in,
                              void* d_out, int out_size, void* d_ws, size_t ws_size,
                              hipStream_t stream) {
  const float* x    = (const float*)d_in[0];
  const int*   ei   = (const int*)d_in[1];
  const float* imp  = (const float*)d_in[2];
  const float* W1   = (const float*)d_in[3];
  const float* bl1  = (const float*)d_in[4];
  const float* bc1  = (const float*)d_in[5];
  const float* W2   = (const float*)d_in[6];
  const float* bl2  = (const float*)d_in[7];
  const float* bc2  = (const float*)d_in[8];
  const float* W3   = (const float*)d_in[9];
  const float* bl3  = (const float*)d_in[10];
  const float* bc3  = (const float*)d_in[11];
  const float* Wl1  = (const float*)d_in[12];
  const float* bli1 = (const float*)d_in[13];
  const float* Wl2  = (const float*)d_in[14];
  const float* bli2 = (const float*)d_in[15];
  float* out = (float*)d_out;

  const int N = in_sizes[0] / F;      // 100000
  const int E = in_sizes[1] / 2;      // 600000

  ushort* X16 = (ushort*)d_ws;                 // N*F
  ushort* A16 = X16 + (size_t)N * F;           // N*F
  ushort* B16 = A16 + (size_t)N * F;           // N*F
  ushort* WhP = B16 + (size_t)N * F;           // 8192*8
  ushort* WlP = WhP + 65536;                   // 8192*8
  ushort* W2hH = WlP + 65536;                  // 768*8
  ushort* W2lH = W2hH + 6144;                  // 768*8
  float* w1p    = (float*)(W2lH + 6144);       // F*F
  float* dinv   = w1p + F * F;                 // N
  float* invdeg = dinv + N;                    // N
  float* csr_norm = invdeg + N;                // E
  int*   cnt    = (int*)(csr_norm + E);        // N
  int*   off    = cnt + N;                     // N+1
  int*   cursor = off + N + 1;                 // N
  int*   csr_src = cursor + N;                 // E
  int*   bsums  = csr_src + E;                 // <=128
  int*   boffs  = bsums + 128;                 // <=128

  const int* rowv = ei;
  const int* colv = ei + E;

  int nbN  = (N + 255) / 256;
  int nbE  = (E + 255) / 256;
  int nbG  = (N + 127) / 128;
  int nbS1 = (N + 1023) / 1024;
  int nbGa = (N + 3) / 4;
  int nbLo = (N + 63) / 64;
  int nbCv = (N * F / 8 + 255) / 256;

  // ---- one-time prep: CSR build + weight pre-split + x conversion ----
  prep_kernel<<<nbN, 256, 0, stream>>>(cnt, w1p, W1, imp, N);
  cvt_kernel<<<nbCv, 256, 0, stream>>>(x, X16, N * F / 8);
  wsplit_kernel<<<35, 256, 0, stream>>>(w1p, W2, W3, Wl1, Wl2, WhP, WlP, W2hH, W2lH);
  count_kernel<<<nbE, 256, 0, stream>>>(colv, cnt, E);
  dinv_kernel<<<nbN, 256, 0, stream>>>(cnt, dinv, invdeg, N);
  scan1_kernel<<<nbS1, 256, 0, stream>>>(cnt, off, bsums, N);
  scan2_kernel<<<1, 128, 0, stream>>>(bsums, boffs, nbS1);
  scan3_kernel<<<nbN, 256, 0, stream>>>(off, cursor, boffs, N, E);
  fill_kernel<<<nbE, 256, 0, stream>>>(rowv, colv, dinv, cursor, csr_src, csr_norm, E);

  // ---- conv layer 1 ----
  gemm_bf16<<<nbG, 256, 0, stream>>>(X16, WhP, WlP, bl1, B16, N, 0);
  gather_kernel<<<nbGa, 256, 0, stream>>>(off, csr_src, csr_norm, B16, invdeg, bc1, A16, N);

  // ---- conv layer 2 ----
  gemm_bf16<<<nbG, 256, 0, stream>>>(A16, WhP + 16384, WlP + 16384, bl2, B16, N, 0);
  gather_kernel<<<nbGa, 256, 0, stream>>>(off, csr_src, csr_norm, B16, invdeg, bc2, A16, N);

  // ---- conv layer 3 ----
  gemm_bf16<<<nbG, 256, 0, stream>>>(A16, WhP + 32768, WlP + 32768, bl3, B16, N, 0);
  gather_kernel<<<nbGa, 256, 0, stream>>>(off, csr_src, csr_norm, B16, invdeg, bc3, A16, N);

  // ---- dense head ----
  gemm_bf16<<<nbG, 256, 0, stream>>>(A16, WhP + 49152, WlP + 49152, bli1, B16, N, 1);
  logits_mfma<<<nbLo, 256, 0, stream>>>(B16, W2hH, W2lH, bli2, out, N);
}

// Round 6
// 451.048 us; speedup vs baseline: 7.9802x; 1.0689x over previous
//
#include <hip/hip_runtime.h>
#include <hip/hip_bf16.h>

#define F 128
#define C_CLS 40

typedef __attribute__((ext_vector_type(8))) short short8;
typedef __attribute__((ext_vector_type(4))) float float4v;
typedef unsigned short ushort;

__device__ inline float bf2f(ushort u) {
  unsigned int x = ((unsigned int)u) << 16;
  return __builtin_bit_cast(float, x);
}
__device__ inline ushort f2bf(float f) {
  __hip_bfloat16 h = __float2bfloat16(f);
  return __builtin_bit_cast(ushort, h);
}
__device__ inline void split_bf16(float f, ushort& hi, ushort& lo) {
  hi = f2bf(f);
  lo = f2bf(f - bf2f(hi));
}
__device__ inline int swz(int lane) { return lane ^ ((lane >> 4) & 3); }

// ---------------- prep: zero counts, fold importance into W1 (fp32) ----------------
__global__ __launch_bounds__(256) void prep_kernel(int* cnt, float* w1p,
    const float* __restrict__ W1, const float* __restrict__ imp, int n) {
  int i = blockIdx.x * 256 + threadIdx.x;
  if (i < n) cnt[i] = 0;
  if (i < F * F) w1p[i] = W1[i] * imp[i & (F - 1)];
}

// ---------------- convert x (fp32) -> X16 (bf16), 8 elems/thread ----------------
__global__ __launch_bounds__(256) void cvt_kernel(const float* __restrict__ x,
    ushort* __restrict__ X16, int n8) {
  int i = blockIdx.x * 256 + threadIdx.x;
  if (i >= n8) return;
  float4 f0 = *(const float4*)&x[(size_t)i * 8];
  float4 f1 = *(const float4*)&x[(size_t)i * 8 + 4];
  ushort h[8] = {f2bf(f0.x), f2bf(f0.y), f2bf(f0.z), f2bf(f0.w),
                 f2bf(f1.x), f2bf(f1.y), f2bf(f1.z), f2bf(f1.w)};
  *(short8*)&X16[(size_t)i * 8] = *(short8*)h;
}

// ---------------- one-time weight split into fragment-ordered hi/lo ----------------
__global__ __launch_bounds__(256) void wsplit_kernel(
    const float* __restrict__ w1p, const float* __restrict__ W2,
    const float* __restrict__ W3, const float* __restrict__ Wl1,
    const float* __restrict__ Wh2, ushort* __restrict__ WhP,
    ushort* __restrict__ WlP, ushort* __restrict__ W2hH, ushort* __restrict__ W2lH) {
  int ci = blockIdx.x * 256 + threadIdx.x;
  if (ci < 8192) {
    const float* src[4] = {w1p, W2, W3, Wl1};
    int p = ci >> 11, c = ci & 2047;
    int kc = c >> 10, ct = (c >> 7) & 7, ks = (c >> 6) & 1, ln = c & 63;
    int dl = swz(ln);
    int col = ct * 16 + (dl & 15);
    int k = kc * 64 + ks * 32 + (dl >> 4) * 8;
    float4 f0 = *(const float4*)&src[p][(size_t)col * F + k];
    float4 f1 = *(const float4*)&src[p][(size_t)col * F + k + 4];
    float v[8] = {f0.x, f0.y, f0.z, f0.w, f1.x, f1.y, f1.z, f1.w};
    ushort hi[8], lo[8];
#pragma unroll
    for (int j = 0; j < 8; ++j) split_bf16(v[j], hi[j], lo[j]);
    *(short8*)&WhP[(size_t)ci * 8] = *(short8*)hi;
    *(short8*)&WlP[(size_t)ci * 8] = *(short8*)lo;
  } else if (ci < 8192 + 768) {
    int c = ci - 8192;
    int ct = c >> 8, ks = (c >> 6) & 3, ln = c & 63;
    int col = ct * 16 + (ln & 15);
    int k = ks * 32 + (ln >> 4) * 8;
    float v[8];
    if (col < C_CLS) {
      float4 f0 = *(const float4*)&Wh2[(size_t)col * F + k];
      float4 f1 = *(const float4*)&Wh2[(size_t)col * F + k + 4];
      v[0] = f0.x; v[1] = f0.y; v[2] = f0.z; v[3] = f0.w;
      v[4] = f1.x; v[5] = f1.y; v[6] = f1.z; v[7] = f1.w;
    } else {
#pragma unroll
      for (int j = 0; j < 8; ++j) v[j] = 0.f;
    }
    ushort hi[8], lo[8];
#pragma unroll
    for (int j = 0; j < 8; ++j) split_bf16(v[j], hi[j], lo[j]);
    *(short8*)&W2hH[(size_t)c * 8] = *(short8*)hi;
    *(short8*)&W2lH[(size_t)c * 8] = *(short8*)lo;
  }
}

__global__ __launch_bounds__(256) void count_kernel(const int* __restrict__ col,
                                                    int* cnt, int ne) {
  int e = blockIdx.x * 256 + threadIdx.x;
  if (e < ne) atomicAdd(&cnt[col[e]], 1);
}

__global__ __launch_bounds__(256) void dinv_kernel(const int* __restrict__ cnt,
    float* dinv, float* invdeg, int n) {
  int i = blockIdx.x * 256 + threadIdx.x;
  if (i < n) {
    float d = (float)(cnt[i] + 1);
    dinv[i] = rsqrtf(d);
    invdeg[i] = 1.0f / d;
  }
}

// ---------------- 2-level exclusive scan ----------------
__global__ __launch_bounds__(256) void scan1_kernel(const int* __restrict__ cnt,
    int* off, int* bsums, int n) {
  __shared__ int lds[256];
  int t = threadIdx.x;
  int base = blockIdx.x * 1024 + t * 4;
  int v[4], s = 0;
#pragma unroll
  for (int j = 0; j < 4; ++j) { v[j] = (base + j < n) ? cnt[base + j] : 0; s += v[j]; }
  lds[t] = s;
  __syncthreads();
  int incl = s;
  for (int d = 1; d < 256; d <<= 1) {
    int y = (t >= d) ? lds[t - d] : 0;
    __syncthreads();
    incl += y;
    lds[t] = incl;
    __syncthreads();
  }
  int run = incl - s;
#pragma unroll
  for (int j = 0; j < 4; ++j) {
    if (base + j < n) off[base + j] = run;
    run += v[j];
  }
  if (t == 255) bsums[blockIdx.x] = incl;
}

__global__ __launch_bounds__(128) void scan2_kernel(const int* __restrict__ bsums,
    int* boffs, int nb) {
  __shared__ int lds[128];
  int t = threadIdx.x;
  int s = (t < nb) ? bsums[t] : 0;
  lds[t] = s;
  __syncthreads();
  int incl = s;
  for (int d = 1; d < 128; d <<= 1) {
    int y = (t >= d) ? lds[t - d] : 0;
    __syncthreads();
    incl += y;
    lds[t] = incl;
    __syncthreads();
  }
  if (t < nb) boffs[t] = incl - s;
}

__global__ __launch_bounds__(256) void scan3_kernel(int* off, int* cursor,
    const int* __restrict__ boffs, int n, int ne) {
  int i = blockIdx.x * 256 + threadIdx.x;
  if (i < n) {
    int v = off[i] + boffs[i >> 10];
    off[i] = v;
    cursor[i] = v;
  }
  if (i == 0) off[n] = ne;
}

__global__ __launch_bounds__(256) void fill_kernel(const int* __restrict__ row,
    const int* __restrict__ col, const float* __restrict__ dinv,
    int* cursor, int* csr_src, float* csr_norm, int ne) {
  int e = blockIdx.x * 256 + threadIdx.x;
  if (e >= ne) return;
  int r = row[e], c = col[e];
  int p = atomicAdd(&cursor[c], 1);
  csr_src[p] = r;
  csr_norm[p] = dinv[r] * dinv[c];
}

// ---------------- bf16 MFMA GEMM, single-barrier structure ----------------
// Weights (full K=128, hi+lo, fragment-ordered w/ baked swizzle) staged once
// into 64 KB LDS; A fragments loaded per-lane straight from global (no LDS,
// no second barrier). Block: 128 rows x 128 cols, 4 waves x (32r x 128c).
__global__ __launch_bounds__(256) void gemm_bf16(const ushort* __restrict__ IN,
    const ushort* __restrict__ Wh, const ushort* __restrict__ Wl,
    const float* __restrict__ bias, ushort* __restrict__ OUT, int nrows, int relu) {
  __shared__ ushort sWh[16384], sWl[16384];  // 64 KB
  const int t = threadIdx.x;
  const int rbase = blockIdx.x * 128;
  const int w = t >> 6, lane = t & 63;
  const int quad = lane >> 4, cl = lane & 15;

  // stage all weights once (sequential copy; swizzle baked into global layout)
#pragma unroll
  for (int pp = 0; pp < 8; ++pp) {
    int ci = t + pp * 256;  // 0..2047
    *(short8*)&sWh[ci * 8] = *(const short8*)&Wh[(size_t)ci * 8];
    *(short8*)&sWl[ci * 8] = *(const short8*)&Wl[(size_t)ci * 8];
  }
  __syncthreads();

  float4v acc[2][8];
#pragma unroll
  for (int rt = 0; rt < 2; ++rt)
#pragma unroll
    for (int ct = 0; ct < 8; ++ct) acc[rt][ct] = (float4v){0.f, 0.f, 0.f, 0.f};

  const int sl = swz(lane);
  const int arow0 = rbase + w * 32 + cl;
#pragma unroll
  for (int ks = 0; ks < 4; ++ks) {
    short8 a[2];
#pragma unroll
    for (int rt = 0; rt < 2; ++rt) {
      int gr = arow0 + rt * 16;
      if (gr < nrows) a[rt] = *(const short8*)&IN[(size_t)gr * F + ks * 32 + quad * 8];
      else a[rt] = (short8){0, 0, 0, 0, 0, 0, 0, 0};
    }
    const int base = ((ks >> 1) * 1024 + (ks & 1) * 64 + sl) * 8;
#pragma unroll
    for (int ct = 0; ct < 8; ++ct) {
      int chunk = base + ct * 128 * 8;
      short8 b_h = *(short8*)&sWh[chunk];
      short8 b_l = *(short8*)&sWl[chunk];
#pragma unroll
      for (int rt = 0; rt < 2; ++rt) {
        acc[rt][ct] = __builtin_amdgcn_mfma_f32_16x16x32_bf16(a[rt], b_h, acc[rt][ct], 0, 0, 0);
        acc[rt][ct] = __builtin_amdgcn_mfma_f32_16x16x32_bf16(a[rt], b_l, acc[rt][ct], 0, 0, 0);
      }
    }
  }
  // epilogue: bias (+relu), C/D layout col=lane&15, row=quad*4+reg; store bf16
#pragma unroll
  for (int ct = 0; ct < 8; ++ct) {
    int gc = ct * 16 + cl;
    float bv = bias[gc];
#pragma unroll
    for (int rt = 0; rt < 2; ++rt) {
#pragma unroll
      for (int reg = 0; reg < 4; ++reg) {
        int gr = rbase + w * 32 + rt * 16 + quad * 4 + reg;
        if (gr < nrows) {
          float val = acc[rt][ct][reg] + bv;
          if (relu) val = fmaxf(val, 0.f);
          OUT[(size_t)gr * F + gc] = f2bf(val);
        }
      }
    }
  }
}

// ---------------- gather + finalize (fused), bf16 in / bf16 out ----------------
// one wave per node; 4 groups of 16 lanes take alternating edges (4 chains in
// flight); each lane owns 8 feats (16 B). Groups combined via shfl_xor(16,32).
__global__ __launch_bounds__(256) void gather_kernel(const int* __restrict__ off,
    const int* __restrict__ csr_src, const float* __restrict__ csr_norm,
    const ushort* __restrict__ B, const float* __restrict__ invdeg,
    const float* __restrict__ bc, ushort* __restrict__ A, int n) {
  int node = blockIdx.x * 4 + (threadIdx.x >> 6);
  if (node >= n) return;
  int lane = threadIdx.x & 63;
  int g = lane >> 4;
  int j = (lane & 15) * 8;
  int e0 = off[node], e1 = off[node + 1];
  float acc[8] = {0.f, 0.f, 0.f, 0.f, 0.f, 0.f, 0.f, 0.f};
  for (int e = e0 + g; e < e1; e += 4) {
    int s = csr_src[e];
    float f = csr_norm[e];
    short8 v = *(const short8*)&B[(size_t)s * F + j];
#pragma unroll
    for (int q = 0; q < 8; ++q) acc[q] += f * bf2f((ushort)v[q]);
  }
#pragma unroll
  for (int q = 0; q < 8; ++q) {
    acc[q] += __shfl_xor(acc[q], 16);
    acc[q] += __shfl_xor(acc[q], 32);
  }
  if (g == 0) {
    float id = invdeg[node];
    short8 sv = *(const short8*)&B[(size_t)node * F + j];
    ushort o[8];
#pragma unroll
    for (int q = 0; q < 8; ++q)
      o[q] = f2bf(fmaxf((acc[q] + bf2f((ushort)sv[q]) * id) * id + bc[j + q], 0.f));
    *(short8*)&A[(size_t)node * F + j] = *(short8*)o;
  }
}

// ---------------- logits via MFMA + fused log_softmax (bf16 input) ----------------
__global__ __launch_bounds__(256) void logits_mfma(const ushort* __restrict__ X,
    const ushort* __restrict__ W2h, const ushort* __restrict__ W2l,
    const float* __restrict__ b2, float* __restrict__ out, int nrows) {
  __shared__ ushort sWh[6144], sWl[6144];
  __shared__ float b2s[48];
  const int t = threadIdx.x;
#pragma unroll
  for (int pp = 0; pp < 3; ++pp) {
    int c = t + pp * 256;
    *(short8*)&sWh[c * 8] = *(const short8*)&W2h[(size_t)c * 8];
    *(short8*)&sWl[c * 8] = *(const short8*)&W2l[(size_t)c * 8];
  }
  if (t < 48) b2s[t] = (t < C_CLS) ? b2[t] : -1e30f;
  __syncthreads();

  const int w = t >> 6, lane = t & 63;
  const int quad = lane >> 4, cl = lane & 15;
  const int row0 = (blockIdx.x * 4 + w) * 16;

  float4v acc[3];
#pragma unroll
  for (int ct = 0; ct < 3; ++ct) acc[ct] = (float4v){0.f, 0.f, 0.f, 0.f};

#pragma unroll
  for (int ks = 0; ks < 4; ++ks) {
    int gr = row0 + cl;
    short8 a;
    if (gr < nrows) a = *(const short8*)&X[(size_t)gr * F + ks * 32 + quad * 8];
    else a = (short8){0, 0, 0, 0, 0, 0, 0, 0};
#pragma unroll
    for (int ct = 0; ct < 3; ++ct) {
      int chunk = ((ct * 4 + ks) * 64 + lane) * 8;
      short8 b_h = *(short8*)&sWh[chunk];
      short8 b_l = *(short8*)&sWl[chunk];
      acc[ct] = __builtin_amdgcn_mfma_f32_16x16x32_bf16(a, b_h, acc[ct], 0, 0, 0);
      acc[ct] = __builtin_amdgcn_mfma_f32_16x16x32_bf16(a, b_l, acc[ct], 0, 0, 0);
    }
  }

  float b0 = b2s[cl], b1 = b2s[16 + cl], b2v = b2s[32 + cl];
  float lse[4];
#pragma unroll
  for (int reg = 0; reg < 4; ++reg) {
    float v0 = acc[0][reg] + b0;
    float v1 = acc[1][reg] + b1;
    float v2 = acc[2][reg] + b2v;
    acc[0][reg] = v0; acc[1][reg] = v1; acc[2][reg] = v2;
    float m = fmaxf(fmaxf(v0, v1), v2);
#pragma unroll
    for (int o = 1; o < 16; o <<= 1) m = fmaxf(m, __shfl_xor(m, o));
    float s = __expf(v0 - m) + __expf(v1 - m) + __expf(v2 - m);
#pragma unroll
    for (int o = 1; o < 16; o <<= 1) s += __shfl_xor(s, o);
    lse[reg] = logf(s) + m;
  }
#pragma unroll
  for (int reg = 0; reg < 4; ++reg) {
    int gr = row0 + quad * 4 + reg;
    if (gr < nrows) {
      out[(size_t)gr * C_CLS + cl] = acc[0][reg] - lse[reg];
      out[(size_t)gr * C_CLS + 16 + cl] = acc[1][reg] - lse[reg];
      if (cl < 8) out[(size_t)gr * C_CLS + 32 + cl] = acc[2][reg] - lse[reg];
    }
  }
}

extern "C" void kernel_launch(void* const* d_in, const int* in_sizes, int n_in,
                              void* d_out, int out_size, void* d_ws, size_t ws_size,
                              hipStream_t stream) {
  const float* x    = (const float*)d_in[0];
  const int*   ei   = (const int*)d_in[1];
  const float* imp  = (const float*)d_in[2];
  const float* W1   = (const float*)d_in[3];
  const float* bl1  = (const float*)d_in[4];
  const float* bc1  = (const float*)d_in[5];
  const float* W2   = (const float*)d_in[6];
  const float* bl2  = (const float*)d_in[7];
  const float* bc2  = (const float*)d_in[8];
  const float* W3   = (const float*)d_in[9];
  const float* bl3  = (const float*)d_in[10];
  const float* bc3  = (const float*)d_in[11];
  const float* Wl1  = (const float*)d_in[12];
  const float* bli1 = (const float*)d_in[13];
  const float* Wl2  = (const float*)d_in[14];
  const float* bli2 = (const float*)d_in[15];
  float* out = (float*)d_out;

  const int N = in_sizes[0] / F;      // 100000
  const int E = in_sizes[1] / 2;      // 600000

  ushort* X16 = (ushort*)d_ws;                 // N*F
  ushort* A16 = X16 + (size_t)N * F;           // N*F
  ushort* B16 = A16 + (size_t)N * F;           // N*F
  ushort* WhP = B16 + (size_t)N * F;           // 8192*8
  ushort* WlP = WhP + 65536;                   // 8192*8
  ushort* W2hH = WlP + 65536;                  // 768*8
  ushort* W2lH = W2hH + 6144;                  // 768*8
  float* w1p    = (float*)(W2lH + 6144);       // F*F
  float* dinv   = w1p + F * F;                 // N
  float* invdeg = dinv + N;                    // N
  float* csr_norm = invdeg + N;                // E
  int*   cnt    = (int*)(csr_norm + E);        // N
  int*   off    = cnt + N;                     // N+1
  int*   cursor = off + N + 1;                 // N
  int*   csr_src = cursor + N;                 // E
  int*   bsums  = csr_src + E;                 // <=128
  int*   boffs  = bsums + 128;                 // <=128

  const int* rowv = ei;
  const int* colv = ei + E;

  int nbN  = (N + 255) / 256;
  int nbE  = (E + 255) / 256;
  int nbG  = (N + 127) / 128;
  int nbS1 = (N + 1023) / 1024;
  int nbGa = (N + 3) / 4;
  int nbLo = (N + 63) / 64;
  int nbCv = (N * F / 8 + 255) / 256;

  // ---- one-time prep: CSR build + weight pre-split + x conversion ----
  prep_kernel<<<nbN, 256, 0, stream>>>(cnt, w1p, W1, imp, N);
  cvt_kernel<<<nbCv, 256, 0, stream>>>(x, X16, N * F / 8);
  wsplit_kernel<<<35, 256, 0, stream>>>(w1p, W2, W3, Wl1, Wl2, WhP, WlP, W2hH, W2lH);
  count_kernel<<<nbE, 256, 0, stream>>>(colv, cnt, E);
  dinv_kernel<<<nbN, 256, 0, stream>>>(cnt, dinv, invdeg, N);
  scan1_kernel<<<nbS1, 256, 0, stream>>>(cnt, off, bsums, N);
  scan2_kernel<<<1, 128, 0, stream>>>(bsums, boffs, nbS1);
  scan3_kernel<<<nbN, 256, 0, stream>>>(off, cursor, boffs, N, E);
  fill_kernel<<<nbE, 256, 0, stream>>>(rowv, colv, dinv, cursor, csr_src, csr_norm, E);

  // ---- conv layer 1 ----
  gemm_bf16<<<nbG, 256, 0, stream>>>(X16, WhP, WlP, bl1, B16, N, 0);
  gather_kernel<<<nbGa, 256, 0, stream>>>(off, csr_src, csr_norm, B16, invdeg, bc1, A16, N);

  // ---- conv layer 2 ----
  gemm_bf16<<<nbG, 256, 0, stream>>>(A16, WhP + 16384, WlP + 16384, bl2, B16, N, 0);
  gather_kernel<<<nbGa, 256, 0, stream>>>(off, csr_src, csr_norm, B16, invdeg, bc2, A16, N);

  // ---- conv layer 3 ----
  gemm_bf16<<<nbG, 256, 0, stream>>>(A16, WhP + 32768, WlP + 32768, bl3, B16, N, 0);
  gather_kernel<<<nbGa, 256, 0, stream>>>(off, csr_src, csr_norm, B16, invdeg, bc3, A16, N);

  // ---- dense head ----
  gemm_bf16<<<nbG, 256, 0, stream>>>(A16, WhP + 49152, WlP + 49152, bli1, B16, N, 1);
  logits_mfma<<<nbLo, 256, 0, stream>>>(B16, W2hH, W2lH, bli2, out, N);
}

// Round 7
// 436.620 us; speedup vs baseline: 8.2439x; 1.0330x over previous
//
#include <hip/hip_runtime.h>
#include <hip/hip_bf16.h>

#define F 128
#define C_CLS 40
#define NWSPLIT 35

typedef __attribute__((ext_vector_type(8))) short short8;
typedef __attribute__((ext_vector_type(4))) float float4v;
typedef unsigned short ushort;

__device__ inline float bf2f(ushort u) {
  unsigned int x = ((unsigned int)u) << 16;
  return __builtin_bit_cast(float, x);
}
__device__ inline ushort f2bf(float f) {
  __hip_bfloat16 h = __float2bfloat16(f);
  return __builtin_bit_cast(ushort, h);
}
__device__ inline void split_bf16(float f, ushort& hi, ushort& lo) {
  hi = f2bf(f);
  lo = f2bf(f - bf2f(hi));
}
__device__ inline int swz(int lane) { return lane ^ ((lane >> 4) & 3); }

// ---------------- setup (heterogeneous): cvt | weight-split | count8 ----------------
// blocks [0,nbCv): x fp32 -> X16 bf16
// blocks [nbCv, nbCv+35): split all weights into fragment-ordered hi/lo
//                         (importance folded into W1 inline)
// blocks [nbCv+35, ...): privatized degree count, slice = local_block & 7
__global__ __launch_bounds__(256) void setup_kernel(
    const float* __restrict__ x, ushort* __restrict__ X16, int n8,
    const float* __restrict__ W1, const float* __restrict__ imp,
    const float* __restrict__ W2, const float* __restrict__ W3,
    const float* __restrict__ Wl1, const float* __restrict__ Wh2,
    ushort* __restrict__ WhP, ushort* __restrict__ WlP,
    ushort* __restrict__ W2hH, ushort* __restrict__ W2lH,
    const int* __restrict__ col, int* __restrict__ cnt8,
    int ne, int n, int nbCv) {
  int b = blockIdx.x;
  if (b < nbCv) {
    int i = b * 256 + threadIdx.x;
    if (i >= n8) return;
    float4 f0 = *(const float4*)&x[(size_t)i * 8];
    float4 f1 = *(const float4*)&x[(size_t)i * 8 + 4];
    ushort h[8] = {f2bf(f0.x), f2bf(f0.y), f2bf(f0.z), f2bf(f0.w),
                   f2bf(f1.x), f2bf(f1.y), f2bf(f1.z), f2bf(f1.w)};
    *(short8*)&X16[(size_t)i * 8] = *(short8*)h;
  } else if (b < nbCv + NWSPLIT) {
    int ci = (b - nbCv) * 256 + threadIdx.x;
    if (ci < 8192) {
      const float* src[4] = {W1, W2, W3, Wl1};
      int p = ci >> 11, c = ci & 2047;
      int kc = c >> 10, ct = (c >> 7) & 7, ks = (c >> 6) & 1, ln = c & 63;
      int dl = swz(ln);
      int colw = ct * 16 + (dl & 15);
      int k = kc * 64 + ks * 32 + (dl >> 4) * 8;
      float4 f0 = *(const float4*)&src[p][(size_t)colw * F + k];
      float4 f1 = *(const float4*)&src[p][(size_t)colw * F + k + 4];
      float v[8] = {f0.x, f0.y, f0.z, f0.w, f1.x, f1.y, f1.z, f1.w};
      if (p == 0) {
        float4 i0 = *(const float4*)&imp[k];
        float4 i1 = *(const float4*)&imp[k + 4];
        v[0] *= i0.x; v[1] *= i0.y; v[2] *= i0.z; v[3] *= i0.w;
        v[4] *= i1.x; v[5] *= i1.y; v[6] *= i1.z; v[7] *= i1.w;
      }
      ushort hi[8], lo[8];
#pragma unroll
      for (int j = 0; j < 8; ++j) split_bf16(v[j], hi[j], lo[j]);
      *(short8*)&WhP[(size_t)ci * 8] = *(short8*)hi;
      *(short8*)&WlP[(size_t)ci * 8] = *(short8*)lo;
    } else if (ci < 8192 + 768) {
      int c = ci - 8192;
      int ct = c >> 8, ks = (c >> 6) & 3, ln = c & 63;
      int colw = ct * 16 + (ln & 15);
      int k = ks * 32 + (ln >> 4) * 8;
      float v[8];
      if (colw < C_CLS) {
        float4 f0 = *(const float4*)&Wh2[(size_t)colw * F + k];
        float4 f1 = *(const float4*)&Wh2[(size_t)colw * F + k + 4];
        v[0] = f0.x; v[1] = f0.y; v[2] = f0.z; v[3] = f0.w;
        v[4] = f1.x; v[5] = f1.y; v[6] = f1.z; v[7] = f1.w;
      } else {
#pragma unroll
        for (int j = 0; j < 8; ++j) v[j] = 0.f;
      }
      ushort hi[8], lo[8];
#pragma unroll
      for (int j = 0; j < 8; ++j) split_bf16(v[j], hi[j], lo[j]);
      *(short8*)&W2hH[(size_t)c * 8] = *(short8*)hi;
      *(short8*)&W2lH[(size_t)c * 8] = *(short8*)lo;
    }
  } else {
    int lb = b - nbCv - NWSPLIT;
    int e = lb * 256 + threadIdx.x;
    if (e < ne) atomicAdd(&cnt8[(size_t)(lb & 7) * n + col[e]], 1);
  }
}

// ---------------- scan1: sum cnt8 slices + dinv/invdeg + block-local scan ----------------
__global__ __launch_bounds__(256) void scan1_kernel(const int* __restrict__ cnt8,
    int* off, int* bsums, float* dinv, float* invdeg, int n) {
  __shared__ int lds[256];
  int t = threadIdx.x;
  int base = blockIdx.x * 1024 + t * 4;
  int v[4], s = 0;
#pragma unroll
  for (int j = 0; j < 4; ++j) {
    int i = base + j;
    int c = 0;
    if (i < n) {
#pragma unroll
      for (int xx = 0; xx < 8; ++xx) c += cnt8[(size_t)xx * n + i];
      float d = (float)(c + 1);
      dinv[i] = rsqrtf(d);
      invdeg[i] = 1.0f / d;
    }
    v[j] = c;
    s += c;
  }
  lds[t] = s;
  __syncthreads();
  int incl = s;
  for (int d = 1; d < 256; d <<= 1) {
    int y = (t >= d) ? lds[t - d] : 0;
    __syncthreads();
    incl += y;
    lds[t] = incl;
    __syncthreads();
  }
  int run = incl - s;
#pragma unroll
  for (int j = 0; j < 4; ++j) {
    if (base + j < n) off[base + j] = run;
    run += v[j];
  }
  if (t == 255) bsums[blockIdx.x] = incl;
}

__global__ __launch_bounds__(128) void scan2_kernel(const int* __restrict__ bsums,
    int* boffs, int nb) {
  __shared__ int lds[128];
  int t = threadIdx.x;
  int s = (t < nb) ? bsums[t] : 0;
  lds[t] = s;
  __syncthreads();
  int incl = s;
  for (int d = 1; d < 128; d <<= 1) {
    int y = (t >= d) ? lds[t - d] : 0;
    __syncthreads();
    incl += y;
    lds[t] = incl;
    __syncthreads();
  }
  if (t < nb) boffs[t] = incl - s;
}

// scan3: finalize off; seed the 8 privatized cursors with per-slice prefixes
__global__ __launch_bounds__(256) void scan3_kernel(int* off, int* cursor8,
    const int* __restrict__ cnt8, const int* __restrict__ boffs, int n, int ne) {
  int i = blockIdx.x * 256 + threadIdx.x;
  if (i < n) {
    int v = off[i] + boffs[i >> 10];
    off[i] = v;
    int s = v;
#pragma unroll
    for (int xx = 0; xx < 8; ++xx) {
      cursor8[(size_t)xx * n + i] = s;
      s += cnt8[(size_t)xx * n + i];
    }
  }
  if (i == 0) off[n] = ne;
}

// fill: privatized cursor (slice = block & 7, same mapping as count), packed int2
__global__ __launch_bounds__(256) void fill_kernel(const int* __restrict__ row,
    const int* __restrict__ col, const float* __restrict__ dinv,
    int* cursor8, int2* __restrict__ csr, int ne, int n) {
  int e = blockIdx.x * 256 + threadIdx.x;
  if (e >= ne) return;
  int r = row[e], c = col[e];
  int p = atomicAdd(&cursor8[(size_t)(blockIdx.x & 7) * n + c], 1);
  int2 v;
  v.x = r;
  v.y = __float_as_int(dinv[r] * dinv[c]);
  csr[p] = v;
}

// ---------------- bf16 MFMA GEMM, single-barrier structure ----------------
__global__ __launch_bounds__(256) void gemm_bf16(const ushort* __restrict__ IN,
    const ushort* __restrict__ Wh, const ushort* __restrict__ Wl,
    const float* __restrict__ bias, ushort* __restrict__ OUT, int nrows, int relu) {
  __shared__ ushort sWh[16384], sWl[16384];  // 64 KB
  const int t = threadIdx.x;
  const int rbase = blockIdx.x * 128;
  const int w = t >> 6, lane = t & 63;
  const int quad = lane >> 4, cl = lane & 15;

#pragma unroll
  for (int pp = 0; pp < 8; ++pp) {
    int ci = t + pp * 256;
    *(short8*)&sWh[ci * 8] = *(const short8*)&Wh[(size_t)ci * 8];
    *(short8*)&sWl[ci * 8] = *(const short8*)&Wl[(size_t)ci * 8];
  }
  __syncthreads();

  float4v acc[2][8];
#pragma unroll
  for (int rt = 0; rt < 2; ++rt)
#pragma unroll
    for (int ct = 0; ct < 8; ++ct) acc[rt][ct] = (float4v){0.f, 0.f, 0.f, 0.f};

  const int sl = swz(lane);
  const int arow0 = rbase + w * 32 + cl;
#pragma unroll
  for (int ks = 0; ks < 4; ++ks) {
    short8 a[2];
#pragma unroll
    for (int rt = 0; rt < 2; ++rt) {
      int gr = arow0 + rt * 16;
      if (gr < nrows) a[rt] = *(const short8*)&IN[(size_t)gr * F + ks * 32 + quad * 8];
      else a[rt] = (short8){0, 0, 0, 0, 0, 0, 0, 0};
    }
    const int base = ((ks >> 1) * 1024 + (ks & 1) * 64 + sl) * 8;
#pragma unroll
    for (int ct = 0; ct < 8; ++ct) {
      int chunk = base + ct * 128 * 8;
      short8 b_h = *(short8*)&sWh[chunk];
      short8 b_l = *(short8*)&sWl[chunk];
#pragma unroll
      for (int rt = 0; rt < 2; ++rt) {
        acc[rt][ct] = __builtin_amdgcn_mfma_f32_16x16x32_bf16(a[rt], b_h, acc[rt][ct], 0, 0, 0);
        acc[rt][ct] = __builtin_amdgcn_mfma_f32_16x16x32_bf16(a[rt], b_l, acc[rt][ct], 0, 0, 0);
      }
    }
  }
#pragma unroll
  for (int ct = 0; ct < 8; ++ct) {
    int gc = ct * 16 + cl;
    float bv = bias[gc];
#pragma unroll
    for (int rt = 0; rt < 2; ++rt) {
#pragma unroll
      for (int reg = 0; reg < 4; ++reg) {
        int gr = rbase + w * 32 + rt * 16 + quad * 4 + reg;
        if (gr < nrows) {
          float val = acc[rt][ct][reg] + bv;
          if (relu) val = fmaxf(val, 0.f);
          OUT[(size_t)gr * F + gc] = f2bf(val);
        }
      }
    }
  }
}

// ---------------- gather + finalize (fused), packed int2 CSR ----------------
__global__ __launch_bounds__(256) void gather_kernel(const int* __restrict__ off,
    const int2* __restrict__ csr, const ushort* __restrict__ B,
    const float* __restrict__ invdeg, const float* __restrict__ bc,
    ushort* __restrict__ A, int n) {
  int node = blockIdx.x * 4 + (threadIdx.x >> 6);
  if (node >= n) return;
  int lane = threadIdx.x & 63;
  int g = lane >> 4;
  int j = (lane & 15) * 8;
  int e0 = off[node], e1 = off[node + 1];
  float acc[8] = {0.f, 0.f, 0.f, 0.f, 0.f, 0.f, 0.f, 0.f};
  for (int e = e0 + g; e < e1; e += 4) {
    int2 en = csr[e];
    int s = en.x;
    float f = __int_as_float(en.y);
    short8 v = *(const short8*)&B[(size_t)s * F + j];
#pragma unroll
    for (int q = 0; q < 8; ++q) acc[q] += f * bf2f((ushort)v[q]);
  }
#pragma unroll
  for (int q = 0; q < 8; ++q) {
    acc[q] += __shfl_xor(acc[q], 16);
    acc[q] += __shfl_xor(acc[q], 32);
  }
  if (g == 0) {
    float id = invdeg[node];
    short8 sv = *(const short8*)&B[(size_t)node * F + j];
    ushort o[8];
#pragma unroll
    for (int q = 0; q < 8; ++q)
      o[q] = f2bf(fmaxf((acc[q] + bf2f((ushort)sv[q]) * id) * id + bc[j + q], 0.f));
    *(short8*)&A[(size_t)node * F + j] = *(short8*)o;
  }
}

// ---------------- logits via MFMA + fused log_softmax (bf16 input) ----------------
__global__ __launch_bounds__(256) void logits_mfma(const ushort* __restrict__ X,
    const ushort* __restrict__ W2h, const ushort* __restrict__ W2l,
    const float* __restrict__ b2, float* __restrict__ out, int nrows) {
  __shared__ ushort sWh[6144], sWl[6144];
  __shared__ float b2s[48];
  const int t = threadIdx.x;
#pragma unroll
  for (int pp = 0; pp < 3; ++pp) {
    int c = t + pp * 256;
    *(short8*)&sWh[c * 8] = *(const short8*)&W2h[(size_t)c * 8];
    *(short8*)&sWl[c * 8] = *(const short8*)&W2l[(size_t)c * 8];
  }
  if (t < 48) b2s[t] = (t < C_CLS) ? b2[t] : -1e30f;
  __syncthreads();

  const int w = t >> 6, lane = t & 63;
  const int quad = lane >> 4, cl = lane & 15;
  const int row0 = (blockIdx.x * 4 + w) * 16;

  float4v acc[3];
#pragma unroll
  for (int ct = 0; ct < 3; ++ct) acc[ct] = (float4v){0.f, 0.f, 0.f, 0.f};

#pragma unroll
  for (int ks = 0; ks < 4; ++ks) {
    int gr = row0 + cl;
    short8 a;
    if (gr < nrows) a = *(const short8*)&X[(size_t)gr * F + ks * 32 + quad * 8];
    else a = (short8){0, 0, 0, 0, 0, 0, 0, 0};
#pragma unroll
    for (int ct = 0; ct < 3; ++ct) {
      int chunk = ((ct * 4 + ks) * 64 + lane) * 8;
      short8 b_h = *(short8*)&sWh[chunk];
      short8 b_l = *(short8*)&sWl[chunk];
      acc[ct] = __builtin_amdgcn_mfma_f32_16x16x32_bf16(a, b_h, acc[ct], 0, 0, 0);
      acc[ct] = __builtin_amdgcn_mfma_f32_16x16x32_bf16(a, b_l, acc[ct], 0, 0, 0);
    }
  }

  float b0 = b2s[cl], b1 = b2s[16 + cl], b2v = b2s[32 + cl];
  float lse[4];
#pragma unroll
  for (int reg = 0; reg < 4; ++reg) {
    float v0 = acc[0][reg] + b0;
    float v1 = acc[1][reg] + b1;
    float v2 = acc[2][reg] + b2v;
    acc[0][reg] = v0; acc[1][reg] = v1; acc[2][reg] = v2;
    float m = fmaxf(fmaxf(v0, v1), v2);
#pragma unroll
    for (int o = 1; o < 16; o <<= 1) m = fmaxf(m, __shfl_xor(m, o));
    float s = __expf(v0 - m) + __expf(v1 - m) + __expf(v2 - m);
#pragma unroll
    for (int o = 1; o < 16; o <<= 1) s += __shfl_xor(s, o);
    lse[reg] = logf(s) + m;
  }
#pragma unroll
  for (int reg = 0; reg < 4; ++reg) {
    int gr = row0 + quad * 4 + reg;
    if (gr < nrows) {
      out[(size_t)gr * C_CLS + cl] = acc[0][reg] - lse[reg];
      out[(size_t)gr * C_CLS + 16 + cl] = acc[1][reg] - lse[reg];
      if (cl < 8) out[(size_t)gr * C_CLS + 32 + cl] = acc[2][reg] - lse[reg];
    }
  }
}

extern "C" void kernel_launch(void* const* d_in, const int* in_sizes, int n_in,
                              void* d_out, int out_size, void* d_ws, size_t ws_size,
                              hipStream_t stream) {
  const float* x    = (const float*)d_in[0];
  const int*   ei   = (const int*)d_in[1];
  const float* imp  = (const float*)d_in[2];
  const float* W1   = (const float*)d_in[3];
  const float* bl1  = (const float*)d_in[4];
  const float* bc1  = (const float*)d_in[5];
  const float* W2   = (const float*)d_in[6];
  const float* bl2  = (const float*)d_in[7];
  const float* bc2  = (const float*)d_in[8];
  const float* W3   = (const float*)d_in[9];
  const float* bl3  = (const float*)d_in[10];
  const float* bc3  = (const float*)d_in[11];
  const float* Wl1  = (const float*)d_in[12];
  const float* bli1 = (const float*)d_in[13];
  const float* Wl2  = (const float*)d_in[14];
  const float* bli2 = (const float*)d_in[15];
  float* out = (float*)d_out;

  const int N = in_sizes[0] / F;      // 100000
  const int E = in_sizes[1] / 2;      // 600000

  ushort* X16 = (ushort*)d_ws;                 // N*F
  ushort* A16 = X16 + (size_t)N * F;           // N*F
  ushort* B16 = A16 + (size_t)N * F;           // N*F
  ushort* WhP = B16 + (size_t)N * F;           // 8192*8
  ushort* WlP = WhP + 65536;                   // 8192*8
  ushort* W2hH = WlP + 65536;                  // 768*8
  ushort* W2lH = W2hH + 6144;                  // 768*8
  int2*  csr  = (int2*)(W2lH + 6144);          // E (8 B each)
  float* dinv = (float*)(csr + E);             // N
  float* invdeg = dinv + N;                    // N
  int*   cnt8 = (int*)(invdeg + N);            // 8N
  int*   cursor8 = cnt8 + (size_t)8 * N;       // 8N
  int*   off  = cursor8 + (size_t)8 * N;       // N+1
  int*   bsums = off + N + 1;                  // <=128
  int*   boffs = bsums + 128;                  // <=128

  const int* rowv = ei;
  const int* colv = ei + E;

  int nbN  = (N + 255) / 256;
  int nbE  = (E + 255) / 256;
  int nbG  = (N + 127) / 128;
  int nbS1 = (N + 1023) / 1024;
  int nbGa = (N + 3) / 4;
  int nbLo = (N + 63) / 64;
  int nbCv = (N * F / 8 + 255) / 256;

  // ---- one-time prep: fused cvt + weight-split + privatized count ----
  hipMemsetAsync(cnt8, 0, (size_t)8 * N * sizeof(int), stream);
  setup_kernel<<<nbCv + NWSPLIT + nbE, 256, 0, stream>>>(
      x, X16, N * F / 8, W1, imp, W2, W3, Wl1, Wl2,
      WhP, WlP, W2hH, W2lH, colv, cnt8, E, N, nbCv);
  scan1_kernel<<<nbS1, 256, 0, stream>>>(cnt8, off, bsums, dinv, invdeg, N);
  scan2_kernel<<<1, 128, 0, stream>>>(bsums, boffs, nbS1);
  scan3_kernel<<<nbN, 256, 0, stream>>>(off, cursor8, cnt8, boffs, N, E);
  fill_kernel<<<nbE, 256, 0, stream>>>(rowv, colv, dinv, cursor8, csr, E, N);

  // ---- conv layer 1 ----
  gemm_bf16<<<nbG, 256, 0, stream>>>(X16, WhP, WlP, bl1, B16, N, 0);
  gather_kernel<<<nbGa, 256, 0, stream>>>(off, csr, B16, invdeg, bc1, A16, N);

  // ---- conv layer 2 ----
  gemm_bf16<<<nbG, 256, 0, stream>>>(A16, WhP + 16384, WlP + 16384, bl2, B16, N, 0);
  gather_kernel<<<nbGa, 256, 0, stream>>>(off, csr, B16, invdeg, bc2, A16, N);

  // ---- conv layer 3 ----
  gemm_bf16<<<nbG, 256, 0, stream>>>(A16, WhP + 32768, WlP + 32768, bl3, B16, N, 0);
  gather_kernel<<<nbGa, 256, 0, stream>>>(off, csr, B16, invdeg, bc3, A16, N);

  // ---- dense head ----
  gemm_bf16<<<nbG, 256, 0, stream>>>(A16, WhP + 49152, WlP + 49152, bli1, B16, N, 1);
  logits_mfma<<<nbLo, 256, 0, stream>>>(B16, W2hH, W2lH, bli2, out, N);
}

// Round 8
// 417.826 us; speedup vs baseline: 8.6147x; 1.0450x over previous
//
#include <hip/hip_runtime.h>
#include <hip/hip_bf16.h>

#define F 128
#define C_CLS 40
#define NWSPLIT 35

typedef __attribute__((ext_vector_type(8))) short short8;
typedef __attribute__((ext_vector_type(4))) float float4v;
typedef unsigned short ushort;

__device__ inline float bf2f(ushort u) {
  unsigned int x = ((unsigned int)u) << 16;
  return __builtin_bit_cast(float, x);
}
__device__ inline ushort f2bf(float f) {
  __hip_bfloat16 h = __float2bfloat16(f);
  return __builtin_bit_cast(ushort, h);
}
__device__ inline void split_bf16(float f, ushort& hi, ushort& lo) {
  hi = f2bf(f);
  lo = f2bf(f - bf2f(hi));
}
__device__ inline int swz(int lane) { return lane ^ ((lane >> 4) & 3); }

// ---------------- setup (heterogeneous): cvt | weight-split | count8 ----------------
__global__ __launch_bounds__(256) void setup_kernel(
    const float* __restrict__ x, ushort* __restrict__ X16, int n8,
    const float* __restrict__ W1, const float* __restrict__ imp,
    const float* __restrict__ W2, const float* __restrict__ W3,
    const float* __restrict__ Wl1, const float* __restrict__ Wh2,
    ushort* __restrict__ WhP, ushort* __restrict__ WlP,
    ushort* __restrict__ W2hH, ushort* __restrict__ W2lH,
    const int* __restrict__ col, int* __restrict__ cnt8,
    int ne, int n, int nbCv) {
  int b = blockIdx.x;
  if (b < nbCv) {
    int i = b * 256 + threadIdx.x;
    if (i >= n8) return;
    float4 f0 = *(const float4*)&x[(size_t)i * 8];
    float4 f1 = *(const float4*)&x[(size_t)i * 8 + 4];
    ushort h[8] = {f2bf(f0.x), f2bf(f0.y), f2bf(f0.z), f2bf(f0.w),
                   f2bf(f1.x), f2bf(f1.y), f2bf(f1.z), f2bf(f1.w)};
    *(short8*)&X16[(size_t)i * 8] = *(short8*)h;
  } else if (b < nbCv + NWSPLIT) {
    int ci = (b - nbCv) * 256 + threadIdx.x;
    if (ci < 8192) {
      const float* src[4] = {W1, W2, W3, Wl1};
      int p = ci >> 11, c = ci & 2047;
      int kc = c >> 10, ct = (c >> 7) & 7, ks = (c >> 6) & 1, ln = c & 63;
      int dl = swz(ln);
      int colw = ct * 16 + (dl & 15);
      int k = kc * 64 + ks * 32 + (dl >> 4) * 8;
      float4 f0 = *(const float4*)&src[p][(size_t)colw * F + k];
      float4 f1 = *(const float4*)&src[p][(size_t)colw * F + k + 4];
      float v[8] = {f0.x, f0.y, f0.z, f0.w, f1.x, f1.y, f1.z, f1.w};
      if (p == 0) {
        float4 i0 = *(const float4*)&imp[k];
        float4 i1 = *(const float4*)&imp[k + 4];
        v[0] *= i0.x; v[1] *= i0.y; v[2] *= i0.z; v[3] *= i0.w;
        v[4] *= i1.x; v[5] *= i1.y; v[6] *= i1.z; v[7] *= i1.w;
      }
      ushort hi[8], lo[8];
#pragma unroll
      for (int j = 0; j < 8; ++j) split_bf16(v[j], hi[j], lo[j]);
      *(short8*)&WhP[(size_t)ci * 8] = *(short8*)hi;
      *(short8*)&WlP[(size_t)ci * 8] = *(short8*)lo;
    } else if (ci < 8192 + 768) {
      int c = ci - 8192;
      int ct = c >> 8, ks = (c >> 6) & 3, ln = c & 63;
      int colw = ct * 16 + (ln & 15);
      int k = ks * 32 + (ln >> 4) * 8;
      float v[8];
      if (colw < C_CLS) {
        float4 f0 = *(const float4*)&Wh2[(size_t)colw * F + k];
        float4 f1 = *(const float4*)&Wh2[(size_t)colw * F + k + 4];
        v[0] = f0.x; v[1] = f0.y; v[2] = f0.z; v[3] = f0.w;
        v[4] = f1.x; v[5] = f1.y; v[6] = f1.z; v[7] = f1.w;
      } else {
#pragma unroll
        for (int j = 0; j < 8; ++j) v[j] = 0.f;
      }
      ushort hi[8], lo[8];
#pragma unroll
      for (int j = 0; j < 8; ++j) split_bf16(v[j], hi[j], lo[j]);
      *(short8*)&W2hH[(size_t)c * 8] = *(short8*)hi;
      *(short8*)&W2lH[(size_t)c * 8] = *(short8*)lo;
    }
  } else {
    int lb = b - nbCv - NWSPLIT;
    int e = lb * 256 + threadIdx.x;
    if (e < ne) atomicAdd(&cnt8[(size_t)(lb & 7) * n + col[e]], 1);
  }
}

// ---------------- scan1: sum cnt8 slices + dinv/invdeg + block-local scan ----------------
__global__ __launch_bounds__(256) void scan1_kernel(const int* __restrict__ cnt8,
    int* off, int* bsums, float* dinv, float* invdeg, int n) {
  __shared__ int lds[256];
  int t = threadIdx.x;
  int base = blockIdx.x * 1024 + t * 4;
  int v[4], s = 0;
#pragma unroll
  for (int j = 0; j < 4; ++j) {
    int i = base + j;
    int c = 0;
    if (i < n) {
#pragma unroll
      for (int xx = 0; xx < 8; ++xx) c += cnt8[(size_t)xx * n + i];
      float d = (float)(c + 1);
      dinv[i] = rsqrtf(d);
      invdeg[i] = 1.0f / d;
    }
    v[j] = c;
    s += c;
  }
  lds[t] = s;
  __syncthreads();
  int incl = s;
  for (int d = 1; d < 256; d <<= 1) {
    int y = (t >= d) ? lds[t - d] : 0;
    __syncthreads();
    incl += y;
    lds[t] = incl;
    __syncthreads();
  }
  int run = incl - s;
#pragma unroll
  for (int j = 0; j < 4; ++j) {
    if (base + j < n) off[base + j] = run;
    run += v[j];
  }
  if (t == 255) bsums[blockIdx.x] = incl;
}

__global__ __launch_bounds__(128) void scan2_kernel(const int* __restrict__ bsums,
    int* boffs, int nb) {
  __shared__ int lds[128];
  int t = threadIdx.x;
  int s = (t < nb) ? bsums[t] : 0;
  lds[t] = s;
  __syncthreads();
  int incl = s;
  for (int d = 1; d < 128; d <<= 1) {
    int y = (t >= d) ? lds[t - d] : 0;
    __syncthreads();
    incl += y;
    lds[t] = incl;
    __syncthreads();
  }
  if (t < nb) boffs[t] = incl - s;
}

// scan3: finalize off; seed the 8 privatized cursors with per-slice prefixes
__global__ __launch_bounds__(256) void scan3_kernel(int* off, int* cursor8,
    const int* __restrict__ cnt8, const int* __restrict__ boffs, int n, int ne) {
  int i = blockIdx.x * 256 + threadIdx.x;
  if (i < n) {
    int v = off[i] + boffs[i >> 10];
    off[i] = v;
    int s = v;
#pragma unroll
    for (int xx = 0; xx < 8; ++xx) {
      cursor8[(size_t)xx * n + i] = s;
      s += cnt8[(size_t)xx * n + i];
    }
  }
  if (i == 0) off[n] = ne;
}

// fill: privatized cursor (slice = block & 7, same mapping as count), packed int2
__global__ __launch_bounds__(256) void fill_kernel(const int* __restrict__ row,
    const int* __restrict__ col, const float* __restrict__ dinv,
    int* cursor8, int2* __restrict__ csr, int ne, int n) {
  int e = blockIdx.x * 256 + threadIdx.x;
  if (e >= ne) return;
  int r = row[e], c = col[e];
  int p = atomicAdd(&cursor8[(size_t)(blockIdx.x & 7) * n + c], 1);
  int2 v;
  v.x = r;
  v.y = __float_as_int(dinv[r] * dinv[c]);
  csr[p] = v;
}

// ---------------- bf16 MFMA GEMM, single-barrier, 256-row tiles ----------------
// Weights (full K=128, hi+lo, fragment-ordered, swizzle baked) staged once into
// 64 KB LDS; A fragments straight from global. Block: 256 rows x 128 cols,
// 4 waves x (64 rows x 128 cols). ds_read:MFMA = 64:256 per wave K-loop.
__global__ __launch_bounds__(256, 2) void gemm_bf16(const ushort* __restrict__ IN,
    const ushort* __restrict__ Wh, const ushort* __restrict__ Wl,
    const float* __restrict__ bias, ushort* __restrict__ OUT, int nrows, int relu) {
  __shared__ ushort sWh[16384], sWl[16384];  // 64 KB
  const int t = threadIdx.x;
  const int rbase = blockIdx.x * 256;
  const int w = t >> 6, lane = t & 63;
  const int quad = lane >> 4, cl = lane & 15;

#pragma unroll
  for (int pp = 0; pp < 8; ++pp) {
    int ci = t + pp * 256;
    *(short8*)&sWh[ci * 8] = *(const short8*)&Wh[(size_t)ci * 8];
    *(short8*)&sWl[ci * 8] = *(const short8*)&Wl[(size_t)ci * 8];
  }
  __syncthreads();

  float4v acc[4][8];
#pragma unroll
  for (int rt = 0; rt < 4; ++rt)
#pragma unroll
    for (int ct = 0; ct < 8; ++ct) acc[rt][ct] = (float4v){0.f, 0.f, 0.f, 0.f};

  const int sl = swz(lane);
  const int arow0 = rbase + w * 64 + cl;
#pragma unroll
  for (int ks = 0; ks < 4; ++ks) {
    short8 a[4];
#pragma unroll
    for (int rt = 0; rt < 4; ++rt) {
      int gr = arow0 + rt * 16;
      if (gr < nrows) a[rt] = *(const short8*)&IN[(size_t)gr * F + ks * 32 + quad * 8];
      else a[rt] = (short8){0, 0, 0, 0, 0, 0, 0, 0};
    }
    const int base = ((ks >> 1) * 1024 + (ks & 1) * 64 + sl) * 8;
#pragma unroll
    for (int ct = 0; ct < 8; ++ct) {
      int chunk = base + ct * 128 * 8;
      short8 b_h = *(short8*)&sWh[chunk];
      short8 b_l = *(short8*)&sWl[chunk];
#pragma unroll
      for (int rt = 0; rt < 4; ++rt) {
        acc[rt][ct] = __builtin_amdgcn_mfma_f32_16x16x32_bf16(a[rt], b_h, acc[rt][ct], 0, 0, 0);
        acc[rt][ct] = __builtin_amdgcn_mfma_f32_16x16x32_bf16(a[rt], b_l, acc[rt][ct], 0, 0, 0);
      }
    }
  }
#pragma unroll
  for (int ct = 0; ct < 8; ++ct) {
    int gc = ct * 16 + cl;
    float bv = bias[gc];
#pragma unroll
    for (int rt = 0; rt < 4; ++rt) {
#pragma unroll
      for (int reg = 0; reg < 4; ++reg) {
        int gr = rbase + w * 64 + rt * 16 + quad * 4 + reg;
        if (gr < nrows) {
          float val = acc[rt][ct][reg] + bv;
          if (relu) val = fmaxf(val, 0.f);
          OUT[(size_t)gr * F + gc] = f2bf(val);
        }
      }
    }
  }
}

// ---------------- gather + finalize (fused), packed int2 CSR, 2-way unrolled ----------------
// one wave per node; 4 groups of 16 lanes; each group runs 2 edge-chains in
// flight (e, e+4) -> 8 concurrent chains per wave. Lane owns 8 feats (16 B).
__global__ __launch_bounds__(256) void gather_kernel(const int* __restrict__ off,
    const int2* __restrict__ csr, const ushort* __restrict__ B,
    const float* __restrict__ invdeg, const float* __restrict__ bc,
    ushort* __restrict__ A, int n) {
  int node = blockIdx.x * 4 + (threadIdx.x >> 6);
  if (node >= n) return;
  int lane = threadIdx.x & 63;
  int g = lane >> 4;
  int j = (lane & 15) * 8;
  int e0 = off[node], e1 = off[node + 1];
  float acc0[8] = {0.f, 0.f, 0.f, 0.f, 0.f, 0.f, 0.f, 0.f};
  float acc1[8] = {0.f, 0.f, 0.f, 0.f, 0.f, 0.f, 0.f, 0.f};
  int e = e0 + g;
  for (; e + 4 < e1; e += 8) {
    int2 en0 = csr[e];
    int2 en1 = csr[e + 4];
    short8 v0 = *(const short8*)&B[(size_t)en0.x * F + j];
    short8 v1 = *(const short8*)&B[(size_t)en1.x * F + j];
    float f0 = __int_as_float(en0.y);
    float f1 = __int_as_float(en1.y);
#pragma unroll
    for (int q = 0; q < 8; ++q) {
      acc0[q] += f0 * bf2f((ushort)v0[q]);
      acc1[q] += f1 * bf2f((ushort)v1[q]);
    }
  }
  if (e < e1) {
    int2 en0 = csr[e];
    short8 v0 = *(const short8*)&B[(size_t)en0.x * F + j];
    float f0 = __int_as_float(en0.y);
#pragma unroll
    for (int q = 0; q < 8; ++q) acc0[q] += f0 * bf2f((ushort)v0[q]);
  }
#pragma unroll
  for (int q = 0; q < 8; ++q) {
    float a = acc0[q] + acc1[q];
    a += __shfl_xor(a, 16);
    a += __shfl_xor(a, 32);
    acc0[q] = a;
  }
  if (g == 0) {
    float id = invdeg[node];
    short8 sv = *(const short8*)&B[(size_t)node * F + j];
    ushort o[8];
#pragma unroll
    for (int q = 0; q < 8; ++q)
      o[q] = f2bf(fmaxf((acc0[q] + bf2f((ushort)sv[q]) * id) * id + bc[j + q], 0.f));
    *(short8*)&A[(size_t)node * F + j] = *(short8*)o;
  }
}

// ---------------- logits via MFMA + fused log_softmax (bf16 input) ----------------
__global__ __launch_bounds__(256) void logits_mfma(const ushort* __restrict__ X,
    const ushort* __restrict__ W2h, const ushort* __restrict__ W2l,
    const float* __restrict__ b2, float* __restrict__ out, int nrows) {
  __shared__ ushort sWh[6144], sWl[6144];
  __shared__ float b2s[48];
  const int t = threadIdx.x;
#pragma unroll
  for (int pp = 0; pp < 3; ++pp) {
    int c = t + pp * 256;
    *(short8*)&sWh[c * 8] = *(const short8*)&W2h[(size_t)c * 8];
    *(short8*)&sWl[c * 8] = *(const short8*)&W2l[(size_t)c * 8];
  }
  if (t < 48) b2s[t] = (t < C_CLS) ? b2[t] : -1e30f;
  __syncthreads();

  const int w = t >> 6, lane = t & 63;
  const int quad = lane >> 4, cl = lane & 15;
  const int row0 = (blockIdx.x * 4 + w) * 16;

  float4v acc[3];
#pragma unroll
  for (int ct = 0; ct < 3; ++ct) acc[ct] = (float4v){0.f, 0.f, 0.f, 0.f};

#pragma unroll
  for (int ks = 0; ks < 4; ++ks) {
    int gr = row0 + cl;
    short8 a;
    if (gr < nrows) a = *(const short8*)&X[(size_t)gr * F + ks * 32 + quad * 8];
    else a = (short8){0, 0, 0, 0, 0, 0, 0, 0};
#pragma unroll
    for (int ct = 0; ct < 3; ++ct) {
      int chunk = ((ct * 4 + ks) * 64 + lane) * 8;
      short8 b_h = *(short8*)&sWh[chunk];
      short8 b_l = *(short8*)&sWl[chunk];
      acc[ct] = __builtin_amdgcn_mfma_f32_16x16x32_bf16(a, b_h, acc[ct], 0, 0, 0);
      acc[ct] = __builtin_amdgcn_mfma_f32_16x16x32_bf16(a, b_l, acc[ct], 0, 0, 0);
    }
  }

  float b0 = b2s[cl], b1 = b2s[16 + cl], b2v = b2s[32 + cl];
  float lse[4];
#pragma unroll
  for (int reg = 0; reg < 4; ++reg) {
    float v0 = acc[0][reg] + b0;
    float v1 = acc[1][reg] + b1;
    float v2 = acc[2][reg] + b2v;
    acc[0][reg] = v0; acc[1][reg] = v1; acc[2][reg] = v2;
    float m = fmaxf(fmaxf(v0, v1), v2);
#pragma unroll
    for (int o = 1; o < 16; o <<= 1) m = fmaxf(m, __shfl_xor(m, o));
    float s = __expf(v0 - m) + __expf(v1 - m) + __expf(v2 - m);
#pragma unroll
    for (int o = 1; o < 16; o <<= 1) s += __shfl_xor(s, o);
    lse[reg] = logf(s) + m;
  }
#pragma unroll
  for (int reg = 0; reg < 4; ++reg) {
    int gr = row0 + quad * 4 + reg;
    if (gr < nrows) {
      out[(size_t)gr * C_CLS + cl] = acc[0][reg] - lse[reg];
      out[(size_t)gr * C_CLS + 16 + cl] = acc[1][reg] - lse[reg];
      if (cl < 8) out[(size_t)gr * C_CLS + 32 + cl] = acc[2][reg] - lse[reg];
    }
  }
}

extern "C" void kernel_launch(void* const* d_in, const int* in_sizes, int n_in,
                              void* d_out, int out_size, void* d_ws, size_t ws_size,
                              hipStream_t stream) {
  const float* x    = (const float*)d_in[0];
  const int*   ei   = (const int*)d_in[1];
  const float* imp  = (const float*)d_in[2];
  const float* W1   = (const float*)d_in[3];
  const float* bl1  = (const float*)d_in[4];
  const float* bc1  = (const float*)d_in[5];
  const float* W2   = (const float*)d_in[6];
  const float* bl2  = (const float*)d_in[7];
  const float* bc2  = (const float*)d_in[8];
  const float* W3   = (const float*)d_in[9];
  const float* bl3  = (const float*)d_in[10];
  const float* bc3  = (const float*)d_in[11];
  const float* Wl1  = (const float*)d_in[12];
  const float* bli1 = (const float*)d_in[13];
  const float* Wl2  = (const float*)d_in[14];
  const float* bli2 = (const float*)d_in[15];
  float* out = (float*)d_out;

  const int N = in_sizes[0] / F;      // 100000
  const int E = in_sizes[1] / 2;      // 600000

  ushort* X16 = (ushort*)d_ws;                 // N*F
  ushort* A16 = X16 + (size_t)N * F;           // N*F
  ushort* B16 = A16 + (size_t)N * F;           // N*F
  ushort* WhP = B16 + (size_t)N * F;           // 8192*8
  ushort* WlP = WhP + 65536;                   // 8192*8
  ushort* W2hH = WlP + 65536;                  // 768*8
  ushort* W2lH = W2hH + 6144;                  // 768*8
  int2*  csr  = (int2*)(W2lH + 6144);          // E (8 B each)
  float* dinv = (float*)(csr + E);             // N
  float* invdeg = dinv + N;                    // N
  int*   cnt8 = (int*)(invdeg + N);            // 8N
  int*   cursor8 = cnt8 + (size_t)8 * N;       // 8N
  int*   off  = cursor8 + (size_t)8 * N;       // N+1
  int*   bsums = off + N + 1;                  // <=128
  int*   boffs = bsums + 128;                  // <=128

  const int* rowv = ei;
  const int* colv = ei + E;

  int nbN  = (N + 255) / 256;
  int nbE  = (E + 255) / 256;
  int nbG  = (N + 255) / 256;
  int nbS1 = (N + 1023) / 1024;
  int nbGa = (N + 3) / 4;
  int nbLo = (N + 63) / 64;
  int nbCv = (N * F / 8 + 255) / 256;

  // ---- one-time prep: fused cvt + weight-split + privatized count ----
  hipMemsetAsync(cnt8, 0, (size_t)8 * N * sizeof(int), stream);
  setup_kernel<<<nbCv + NWSPLIT + nbE, 256, 0, stream>>>(
      x, X16, N * F / 8, W1, imp, W2, W3, Wl1, Wl2,
      WhP, WlP, W2hH, W2lH, colv, cnt8, E, N, nbCv);
  scan1_kernel<<<nbS1, 256, 0, stream>>>(cnt8, off, bsums, dinv, invdeg, N);
  scan2_kernel<<<1, 128, 0, stream>>>(bsums, boffs, nbS1);
  scan3_kernel<<<nbN, 256, 0, stream>>>(off, cursor8, cnt8, boffs, N, E);
  fill_kernel<<<nbE, 256, 0, stream>>>(rowv, colv, dinv, cursor8, csr, E, N);

  // ---- conv layer 1 ----
  gemm_bf16<<<nbG, 256, 0, stream>>>(X16, WhP, WlP, bl1, B16, N, 0);
  gather_kernel<<<nbGa, 256, 0, stream>>>(off, csr, B16, invdeg, bc1, A16, N);

  // ---- conv layer 2 ----
  gemm_bf16<<<nbG, 256, 0, stream>>>(A16, WhP + 16384, WlP + 16384, bl2, B16, N, 0);
  gather_kernel<<<nbGa, 256, 0, stream>>>(off, csr, B16, invdeg, bc2, A16, N);

  // ---- conv layer 3 ----
  gemm_bf16<<<nbG, 256, 0, stream>>>(A16, WhP + 32768, WlP + 32768, bl3, B16, N, 0);
  gather_kernel<<<nbGa, 256, 0, stream>>>(off, csr, B16, invdeg, bc3, A16, N);

  // ---- dense head ----
  gemm_bf16<<<nbG, 256, 0, stream>>>(A16, WhP + 49152, WlP + 49152, bli1, B16, N, 1);
  logits_mfma<<<nbLo, 256, 0, stream>>>(B16, W2hH, W2lH, bli2, out, N);
}

// Round 9
// 361.911 us; speedup vs baseline: 9.9457x; 1.1545x over previous
//
#include <hip/hip_runtime.h>
#include <hip/hip_bf16.h>

#define F 128
#define C_CLS 40
#define NWSPLIT 35

typedef __attribute__((ext_vector_type(8))) short short8;
typedef __attribute__((ext_vector_type(4))) float float4v;
typedef unsigned short ushort;

__device__ inline float bf2f(ushort u) {
  unsigned int x = ((unsigned int)u) << 16;
  return __builtin_bit_cast(float, x);
}
__device__ inline ushort f2bf(float f) {
  __hip_bfloat16 h = __float2bfloat16(f);
  return __builtin_bit_cast(ushort, h);
}
__device__ inline void split_bf16(float f, ushort& hi, ushort& lo) {
  hi = f2bf(f);
  lo = f2bf(f - bf2f(hi));
}
__device__ inline int swz(int lane) { return lane ^ ((lane >> 4) & 3); }

// ---------------- setup (heterogeneous): cvt | weight-split | count8 ----------------
__global__ __launch_bounds__(256) void setup_kernel(
    const float* __restrict__ x, ushort* __restrict__ X16, int n8,
    const float* __restrict__ W1, const float* __restrict__ imp,
    const float* __restrict__ W2, const float* __restrict__ W3,
    const float* __restrict__ Wl1, const float* __restrict__ Wh2,
    ushort* __restrict__ WhP, ushort* __restrict__ WlP,
    ushort* __restrict__ W2hH, ushort* __restrict__ W2lH,
    const int* __restrict__ col, int* __restrict__ cnt8,
    int ne, int n, int nbCv) {
  int b = blockIdx.x;
  if (b < nbCv) {
    int i = b * 256 + threadIdx.x;
    if (i >= n8) return;
    float4 f0 = *(const float4*)&x[(size_t)i * 8];
    float4 f1 = *(const float4*)&x[(size_t)i * 8 + 4];
    ushort h[8] = {f2bf(f0.x), f2bf(f0.y), f2bf(f0.z), f2bf(f0.w),
                   f2bf(f1.x), f2bf(f1.y), f2bf(f1.z), f2bf(f1.w)};
    *(short8*)&X16[(size_t)i * 8] = *(short8*)h;
  } else if (b < nbCv + NWSPLIT) {
    int ci = (b - nbCv) * 256 + threadIdx.x;
    if (ci < 8192) {
      const float* src[4] = {W1, W2, W3, Wl1};
      int p = ci >> 11, c = ci & 2047;
      int kc = c >> 10, ct = (c >> 7) & 7, ks = (c >> 6) & 1, ln = c & 63;
      int dl = swz(ln);
      int colw = ct * 16 + (dl & 15);
      int k = kc * 64 + ks * 32 + (dl >> 4) * 8;
      float4 f0 = *(const float4*)&src[p][(size_t)colw * F + k];
      float4 f1 = *(const float4*)&src[p][(size_t)colw * F + k + 4];
      float v[8] = {f0.x, f0.y, f0.z, f0.w, f1.x, f1.y, f1.z, f1.w};
      if (p == 0) {
        float4 i0 = *(const float4*)&imp[k];
        float4 i1 = *(const float4*)&imp[k + 4];
        v[0] *= i0.x; v[1] *= i0.y; v[2] *= i0.z; v[3] *= i0.w;
        v[4] *= i1.x; v[5] *= i1.y; v[6] *= i1.z; v[7] *= i1.w;
      }
      ushort hi[8], lo[8];
#pragma unroll
      for (int j = 0; j < 8; ++j) split_bf16(v[j], hi[j], lo[j]);
      *(short8*)&WhP[(size_t)ci * 8] = *(short8*)hi;
      *(short8*)&WlP[(size_t)ci * 8] = *(short8*)lo;
    } else if (ci < 8192 + 768) {
      int c = ci - 8192;
      int ct = c >> 8, ks = (c >> 6) & 3, ln = c & 63;
      int colw = ct * 16 + (ln & 15);
      int k = ks * 32 + (ln >> 4) * 8;
      float v[8];
      if (colw < C_CLS) {
        float4 f0 = *(const float4*)&Wh2[(size_t)colw * F + k];
        float4 f1 = *(const float4*)&Wh2[(size_t)colw * F + k + 4];
        v[0] = f0.x; v[1] = f0.y; v[2] = f0.z; v[3] = f0.w;
        v[4] = f1.x; v[5] = f1.y; v[6] = f1.z; v[7] = f1.w;
      } else {
#pragma unroll
        for (int j = 0; j < 8; ++j) v[j] = 0.f;
      }
      ushort hi[8], lo[8];
#pragma unroll
      for (int j = 0; j < 8; ++j) split_bf16(v[j], hi[j], lo[j]);
      *(short8*)&W2hH[(size_t)c * 8] = *(short8*)hi;
      *(short8*)&W2lH[(size_t)c * 8] = *(short8*)lo;
    }
  } else {
    int lb = b - nbCv - NWSPLIT;
    int e = lb * 256 + threadIdx.x;
    if (e < ne) atomicAdd(&cnt8[(size_t)(lb & 7) * n + col[e]], 1);
  }
}

// ---------------- scan1: sum cnt8 slices + dinv/invdeg + block-local scan ----------------
__global__ __launch_bounds__(256) void scan1_kernel(const int* __restrict__ cnt8,
    int* off, int* bsums, float* dinv, float* invdeg, int n) {
  __shared__ int lds[256];
  int t = threadIdx.x;
  int base = blockIdx.x * 1024 + t * 4;
  int v[4], s = 0;
#pragma unroll
  for (int j = 0; j < 4; ++j) {
    int i = base + j;
    int c = 0;
    if (i < n) {
#pragma unroll
      for (int xx = 0; xx < 8; ++xx) c += cnt8[(size_t)xx * n + i];
      float d = (float)(c + 1);
      dinv[i] = rsqrtf(d);
      invdeg[i] = 1.0f / d;
    }
    v[j] = c;
    s += c;
  }
  lds[t] = s;
  __syncthreads();
  int incl = s;
  for (int d = 1; d < 256; d <<= 1) {
    int y = (t >= d) ? lds[t - d] : 0;
    __syncthreads();
    incl += y;
    lds[t] = incl;
    __syncthreads();
  }
  int run = incl - s;
#pragma unroll
  for (int j = 0; j < 4; ++j) {
    if (base + j < n) off[base + j] = run;
    run += v[j];
  }
  if (t == 255) bsums[blockIdx.x] = incl;
}

__global__ __launch_bounds__(128) void scan2_kernel(const int* __restrict__ bsums,
    int* boffs, int nb) {
  __shared__ int lds[128];
  int t = threadIdx.x;
  int s = (t < nb) ? bsums[t] : 0;
  lds[t] = s;
  __syncthreads();
  int incl = s;
  for (int d = 1; d < 128; d <<= 1) {
    int y = (t >= d) ? lds[t - d] : 0;
    __syncthreads();
    incl += y;
    lds[t] = incl;
    __syncthreads();
  }
  if (t < nb) boffs[t] = incl - s;
}

// scan3: finalize off; seed the 8 privatized cursors with per-slice prefixes
__global__ __launch_bounds__(256) void scan3_kernel(int* off, int* cursor8,
    const int* __restrict__ cnt8, const int* __restrict__ boffs, int n, int ne) {
  int i = blockIdx.x * 256 + threadIdx.x;
  if (i < n) {
    int v = off[i] + boffs[i >> 10];
    off[i] = v;
    int s = v;
#pragma unroll
    for (int xx = 0; xx < 8; ++xx) {
      cursor8[(size_t)xx * n + i] = s;
      s += cnt8[(size_t)xx * n + i];
    }
  }
  if (i == 0) off[n] = ne;
}

// fill: privatized cursor (slice = block & 7, same mapping as count), packed int2
__global__ __launch_bounds__(256) void fill_kernel(const int* __restrict__ row,
    const int* __restrict__ col, const float* __restrict__ dinv,
    int* cursor8, int2* __restrict__ csr, int ne, int n) {
  int e = blockIdx.x * 256 + threadIdx.x;
  if (e >= ne) return;
  int r = row[e], c = col[e];
  int p = atomicAdd(&cursor8[(size_t)(blockIdx.x & 7) * n + c], 1);
  int2 v;
  v.x = r;
  v.y = __float_as_int(dinv[r] * dinv[c]);
  csr[p] = v;
}

// ---------------- bf16 MFMA GEMM, single-barrier, swapped operands ----------------
// mfma(Wfrag, INfrag, acc): output-col -> quad*4+reg, input-row -> lane&15.
// Epilogue: each lane packs 4 consecutive output cols -> one 8B store.
// Block: 256 input rows x 128 outs; 4 waves x (64 rows x 128 outs).
__global__ __launch_bounds__(256, 2) void gemm_bf16(const ushort* __restrict__ IN,
    const ushort* __restrict__ Wh, const ushort* __restrict__ Wl,
    const float* __restrict__ bias, ushort* __restrict__ OUT, int nrows, int relu) {
  __shared__ ushort sWh[16384], sWl[16384];  // 64 KB
  const int t = threadIdx.x;
  const int rbase = blockIdx.x * 256;
  const int w = t >> 6, lane = t & 63;
  const int quad = lane >> 4, cl = lane & 15;

#pragma unroll
  for (int pp = 0; pp < 8; ++pp) {
    int ci = t + pp * 256;
    *(short8*)&sWh[ci * 8] = *(const short8*)&Wh[(size_t)ci * 8];
    *(short8*)&sWl[ci * 8] = *(const short8*)&Wl[(size_t)ci * 8];
  }
  __syncthreads();

  float4v acc[4][8];  // [nt: input-row tile][mt: output-col tile]
#pragma unroll
  for (int nt = 0; nt < 4; ++nt)
#pragma unroll
    for (int mt = 0; mt < 8; ++mt) acc[nt][mt] = (float4v){0.f, 0.f, 0.f, 0.f};

  const int sl = swz(lane);
  const int nrow0 = rbase + w * 64 + cl;
#pragma unroll
  for (int ks = 0; ks < 4; ++ks) {
    short8 b[4];
#pragma unroll
    for (int nt = 0; nt < 4; ++nt) {
      int gr = nrow0 + nt * 16;
      if (gr < nrows) b[nt] = *(const short8*)&IN[(size_t)gr * F + ks * 32 + quad * 8];
      else b[nt] = (short8){0, 0, 0, 0, 0, 0, 0, 0};
    }
    const int base = ((ks >> 1) * 1024 + (ks & 1) * 64 + sl) * 8;
#pragma unroll
    for (int mt = 0; mt < 8; ++mt) {
      int chunk = base + mt * 128 * 8;
      short8 a_h = *(short8*)&sWh[chunk];
      short8 a_l = *(short8*)&sWl[chunk];
#pragma unroll
      for (int nt = 0; nt < 4; ++nt) {
        acc[nt][mt] = __builtin_amdgcn_mfma_f32_16x16x32_bf16(a_h, b[nt], acc[nt][mt], 0, 0, 0);
        acc[nt][mt] = __builtin_amdgcn_mfma_f32_16x16x32_bf16(a_l, b[nt], acc[nt][mt], 0, 0, 0);
      }
    }
  }
  // epilogue: lane holds input row (nrow0+nt*16), output cols mt*16+quad*4+(0..3)
#pragma unroll
  for (int mt = 0; mt < 8; ++mt) {
    float4 bv = *(const float4*)&bias[mt * 16 + quad * 4];
#pragma unroll
    for (int nt = 0; nt < 4; ++nt) {
      int gr = nrow0 + nt * 16;
      if (gr < nrows) {
        float v0 = acc[nt][mt][0] + bv.x;
        float v1 = acc[nt][mt][1] + bv.y;
        float v2 = acc[nt][mt][2] + bv.z;
        float v3 = acc[nt][mt][3] + bv.w;
        if (relu) {
          v0 = fmaxf(v0, 0.f); v1 = fmaxf(v1, 0.f);
          v2 = fmaxf(v2, 0.f); v3 = fmaxf(v3, 0.f);
        }
        ushort o[4] = {f2bf(v0), f2bf(v1), f2bf(v2), f2bf(v3)};
        *(ushort4*)&OUT[(size_t)gr * F + mt * 16 + quad * 4] = *(ushort4*)o;
      }
    }
  }
}

// ---------------- gather + finalize (fused): one 16-lane group per node ----------------
// 4 nodes per wave, 16 nodes per block. No cross-group reduction; epilogue at
// full lane efficiency. 2-way unrolled edge loop (2 chains/group, 8/wave).
__global__ __launch_bounds__(256) void gather_kernel(const int* __restrict__ off,
    const int2* __restrict__ csr, const ushort* __restrict__ B,
    const float* __restrict__ invdeg, const float* __restrict__ bc,
    ushort* __restrict__ A, int n) {
  int node = blockIdx.x * 16 + (threadIdx.x >> 4);
  if (node >= n) return;
  int j = (threadIdx.x & 15) * 8;
  int e0 = off[node], e1 = off[node + 1];
  float acc0[8] = {0.f, 0.f, 0.f, 0.f, 0.f, 0.f, 0.f, 0.f};
  float acc1[8] = {0.f, 0.f, 0.f, 0.f, 0.f, 0.f, 0.f, 0.f};
  int e = e0;
  for (; e + 1 < e1; e += 2) {
    int2 en0 = csr[e];
    int2 en1 = csr[e + 1];
    short8 v0 = *(const short8*)&B[(size_t)en0.x * F + j];
    short8 v1 = *(const short8*)&B[(size_t)en1.x * F + j];
    float f0 = __int_as_float(en0.y);
    float f1 = __int_as_float(en1.y);
#pragma unroll
    for (int q = 0; q < 8; ++q) {
      acc0[q] += f0 * bf2f((ushort)v0[q]);
      acc1[q] += f1 * bf2f((ushort)v1[q]);
    }
  }
  if (e < e1) {
    int2 en = csr[e];
    short8 v = *(const short8*)&B[(size_t)en.x * F + j];
    float f = __int_as_float(en.y);
#pragma unroll
    for (int q = 0; q < 8; ++q) acc0[q] += f * bf2f((ushort)v[q]);
  }
  float id = invdeg[node];
  short8 sv = *(const short8*)&B[(size_t)node * F + j];
  ushort o[8];
#pragma unroll
  for (int q = 0; q < 8; ++q)
    o[q] = f2bf(fmaxf((acc0[q] + acc1[q] + bf2f((ushort)sv[q]) * id) * id + bc[j + q], 0.f));
  *(short8*)&A[(size_t)node * F + j] = *(short8*)o;
}

// ---------------- logits via MFMA + fused log_softmax (bf16 input) ----------------
__global__ __launch_bounds__(256) void logits_mfma(const ushort* __restrict__ X,
    const ushort* __restrict__ W2h, const ushort* __restrict__ W2l,
    const float* __restrict__ b2, float* __restrict__ out, int nrows) {
  __shared__ ushort sWh[6144], sWl[6144];
  __shared__ float b2s[48];
  const int t = threadIdx.x;
#pragma unroll
  for (int pp = 0; pp < 3; ++pp) {
    int c = t + pp * 256;
    *(short8*)&sWh[c * 8] = *(const short8*)&W2h[(size_t)c * 8];
    *(short8*)&sWl[c * 8] = *(const short8*)&W2l[(size_t)c * 8];
  }
  if (t < 48) b2s[t] = (t < C_CLS) ? b2[t] : -1e30f;
  __syncthreads();

  const int w = t >> 6, lane = t & 63;
  const int quad = lane >> 4, cl = lane & 15;
  const int row0 = (blockIdx.x * 4 + w) * 16;

  float4v acc[3];
#pragma unroll
  for (int ct = 0; ct < 3; ++ct) acc[ct] = (float4v){0.f, 0.f, 0.f, 0.f};

#pragma unroll
  for (int ks = 0; ks < 4; ++ks) {
    int gr = row0 + cl;
    short8 a;
    if (gr < nrows) a = *(const short8*)&X[(size_t)gr * F + ks * 32 + quad * 8];
    else a = (short8){0, 0, 0, 0, 0, 0, 0, 0};
#pragma unroll
    for (int ct = 0; ct < 3; ++ct) {
      int chunk = ((ct * 4 + ks) * 64 + lane) * 8;
      short8 b_h = *(short8*)&sWh[chunk];
      short8 b_l = *(short8*)&sWl[chunk];
      acc[ct] = __builtin_amdgcn_mfma_f32_16x16x32_bf16(a, b_h, acc[ct], 0, 0, 0);
      acc[ct] = __builtin_amdgcn_mfma_f32_16x16x32_bf16(a, b_l, acc[ct], 0, 0, 0);
    }
  }

  float b0 = b2s[cl], b1 = b2s[16 + cl], b2v = b2s[32 + cl];
  float lse[4];
#pragma unroll
  for (int reg = 0; reg < 4; ++reg) {
    float v0 = acc[0][reg] + b0;
    float v1 = acc[1][reg] + b1;
    float v2 = acc[2][reg] + b2v;
    acc[0][reg] = v0; acc[1][reg] = v1; acc[2][reg] = v2;
    float m = fmaxf(fmaxf(v0, v1), v2);
#pragma unroll
    for (int o = 1; o < 16; o <<= 1) m = fmaxf(m, __shfl_xor(m, o));
    float s = __expf(v0 - m) + __expf(v1 - m) + __expf(v2 - m);
#pragma unroll
    for (int o = 1; o < 16; o <<= 1) s += __shfl_xor(s, o);
    lse[reg] = logf(s) + m;
  }
#pragma unroll
  for (int reg = 0; reg < 4; ++reg) {
    int gr = row0 + quad * 4 + reg;
    if (gr < nrows) {
      out[(size_t)gr * C_CLS + cl] = acc[0][reg] - lse[reg];
      out[(size_t)gr * C_CLS + 16 + cl] = acc[1][reg] - lse[reg];
      if (cl < 8) out[(size_t)gr * C_CLS + 32 + cl] = acc[2][reg] - lse[reg];
    }
  }
}

extern "C" void kernel_launch(void* const* d_in, const int* in_sizes, int n_in,
                              void* d_out, int out_size, void* d_ws, size_t ws_size,
                              hipStream_t stream) {
  const float* x    = (const float*)d_in[0];
  const int*   ei   = (const int*)d_in[1];
  const float* imp  = (const float*)d_in[2];
  const float* W1   = (const float*)d_in[3];
  const float* bl1  = (const float*)d_in[4];
  const float* bc1  = (const float*)d_in[5];
  const float* W2   = (const float*)d_in[6];
  const float* bl2  = (const float*)d_in[7];
  const float* bc2  = (const float*)d_in[8];
  const float* W3   = (const float*)d_in[9];
  const float* bl3  = (const float*)d_in[10];
  const float* bc3  = (const float*)d_in[11];
  const float* Wl1  = (const float*)d_in[12];
  const float* bli1 = (const float*)d_in[13];
  const float* Wl2  = (const float*)d_in[14];
  const float* bli2 = (const float*)d_in[15];
  float* out = (float*)d_out;

  const int N = in_sizes[0] / F;      // 100000
  const int E = in_sizes[1] / 2;      // 600000

  ushort* X16 = (ushort*)d_ws;                 // N*F
  ushort* A16 = X16 + (size_t)N * F;           // N*F
  ushort* B16 = A16 + (size_t)N * F;           // N*F
  ushort* WhP = B16 + (size_t)N * F;           // 8192*8
  ushort* WlP = WhP + 65536;                   // 8192*8
  ushort* W2hH = WlP + 65536;                  // 768*8
  ushort* W2lH = W2hH + 6144;                  // 768*8
  int2*  csr  = (int2*)(W2lH + 6144);          // E (8 B each)
  float* dinv = (float*)(csr + E);             // N
  float* invdeg = dinv + N;                    // N
  int*   cnt8 = (int*)(invdeg + N);            // 8N
  int*   cursor8 = cnt8 + (size_t)8 * N;       // 8N
  int*   off  = cursor8 + (size_t)8 * N;       // N+1
  int*   bsums = off + N + 1;                  // <=128
  int*   boffs = bsums + 128;                  // <=128

  const int* rowv = ei;
  const int* colv = ei + E;

  int nbN  = (N + 255) / 256;
  int nbE  = (E + 255) / 256;
  int nbG  = (N + 255) / 256;
  int nbS1 = (N + 1023) / 1024;
  int nbGa = (N + 15) / 16;
  int nbLo = (N + 63) / 64;
  int nbCv = (N * F / 8 + 255) / 256;

  // ---- one-time prep: fused cvt + weight-split + privatized count ----
  hipMemsetAsync(cnt8, 0, (size_t)8 * N * sizeof(int), stream);
  setup_kernel<<<nbCv + NWSPLIT + nbE, 256, 0, stream>>>(
      x, X16, N * F / 8, W1, imp, W2, W3, Wl1, Wl2,
      WhP, WlP, W2hH, W2lH, colv, cnt8, E, N, nbCv);
  scan1_kernel<<<nbS1, 256, 0, stream>>>(cnt8, off, bsums, dinv, invdeg, N);
  scan2_kernel<<<1, 128, 0, stream>>>(bsums, boffs, nbS1);
  scan3_kernel<<<nbN, 256, 0, stream>>>(off, cursor8, cnt8, boffs, N, E);
  fill_kernel<<<nbE, 256, 0, stream>>>(rowv, colv, dinv, cursor8, csr, E, N);

  // ---- conv layer 1 ----
  gemm_bf16<<<nbG, 256, 0, stream>>>(X16, WhP, WlP, bl1, B16, N, 0);
  gather_kernel<<<nbGa, 256, 0, stream>>>(off, csr, B16, invdeg, bc1, A16, N);

  // ---- conv layer 2 ----
  gemm_bf16<<<nbG, 256, 0, stream>>>(A16, WhP + 16384, WlP + 16384, bl2, B16, N, 0);
  gather_kernel<<<nbGa, 256, 0, stream>>>(off, csr, B16, invdeg, bc2, A16, N);

  // ---- conv layer 3 ----
  gemm_bf16<<<nbG, 256, 0, stream>>>(A16, WhP + 32768, WlP + 32768, bl3, B16, N, 0);
  gather_kernel<<<nbGa, 256, 0, stream>>>(off, csr, B16, invdeg, bc3, A16, N);

  // ---- dense head ----
  gemm_bf16<<<nbG, 256, 0, stream>>>(A16, WhP + 49152, WlP + 49152, bli1, B16, N, 1);
  logits_mfma<<<nbLo, 256, 0, stream>>>(B16, W2hH, W2lH, bli2, out, N);
}

// Round 10
// 361.264 us; speedup vs baseline: 9.9635x; 1.0018x over previous
//
#include <hip/hip_runtime.h>
#include <hip/hip_bf16.h>

#define F 128
#define C_CLS 40
#define NWSPLIT 35

typedef __attribute__((ext_vector_type(8))) short short8;
typedef __attribute__((ext_vector_type(4))) float float4v;
typedef unsigned short ushort;

__device__ inline float bf2f(ushort u) {
  unsigned int x = ((unsigned int)u) << 16;
  return __builtin_bit_cast(float, x);
}
__device__ inline ushort f2bf(float f) {
  __hip_bfloat16 h = __float2bfloat16(f);
  return __builtin_bit_cast(ushort, h);
}
__device__ inline void split_bf16(float f, ushort& hi, ushort& lo) {
  hi = f2bf(f);
  lo = f2bf(f - bf2f(hi));
}
__device__ inline int swz(int lane) { return lane ^ ((lane >> 4) & 3); }

// ---------------- setup (heterogeneous): weight-split | count8 ----------------
__global__ __launch_bounds__(256) void setup_kernel(
    const float* __restrict__ W1, const float* __restrict__ imp,
    const float* __restrict__ W2, const float* __restrict__ W3,
    const float* __restrict__ Wl1, const float* __restrict__ Wh2,
    ushort* __restrict__ WhP, ushort* __restrict__ WlP,
    ushort* __restrict__ W2hH, ushort* __restrict__ W2lH,
    const int* __restrict__ col, int* __restrict__ cnt8,
    int ne, int n) {
  int b = blockIdx.x;
  if (b < NWSPLIT) {
    int ci = b * 256 + threadIdx.x;
    if (ci < 8192) {
      const float* src[4] = {W1, W2, W3, Wl1};
      int p = ci >> 11, c = ci & 2047;
      int kc = c >> 10, ct = (c >> 7) & 7, ks = (c >> 6) & 1, ln = c & 63;
      int dl = swz(ln);
      int colw = ct * 16 + (dl & 15);
      int k = kc * 64 + ks * 32 + (dl >> 4) * 8;
      float4 f0 = *(const float4*)&src[p][(size_t)colw * F + k];
      float4 f1 = *(const float4*)&src[p][(size_t)colw * F + k + 4];
      float v[8] = {f0.x, f0.y, f0.z, f0.w, f1.x, f1.y, f1.z, f1.w};
      if (p == 0) {
        float4 i0 = *(const float4*)&imp[k];
        float4 i1 = *(const float4*)&imp[k + 4];
        v[0] *= i0.x; v[1] *= i0.y; v[2] *= i0.z; v[3] *= i0.w;
        v[4] *= i1.x; v[5] *= i1.y; v[6] *= i1.z; v[7] *= i1.w;
      }
      ushort hi[8], lo[8];
#pragma unroll
      for (int j = 0; j < 8; ++j) split_bf16(v[j], hi[j], lo[j]);
      *(short8*)&WhP[(size_t)ci * 8] = *(short8*)hi;
      *(short8*)&WlP[(size_t)ci * 8] = *(short8*)lo;
    } else if (ci < 8192 + 768) {
      int c = ci - 8192;
      int ct = c >> 8, ks = (c >> 6) & 3, ln = c & 63;
      int colw = ct * 16 + (ln & 15);
      int k = ks * 32 + (ln >> 4) * 8;
      float v[8];
      if (colw < C_CLS) {
        float4 f0 = *(const float4*)&Wh2[(size_t)colw * F + k];
        float4 f1 = *(const float4*)&Wh2[(size_t)colw * F + k + 4];
        v[0] = f0.x; v[1] = f0.y; v[2] = f0.z; v[3] = f0.w;
        v[4] = f1.x; v[5] = f1.y; v[6] = f1.z; v[7] = f1.w;
      } else {
#pragma unroll
        for (int j = 0; j < 8; ++j) v[j] = 0.f;
      }
      ushort hi[8], lo[8];
#pragma unroll
      for (int j = 0; j < 8; ++j) split_bf16(v[j], hi[j], lo[j]);
      *(short8*)&W2hH[(size_t)c * 8] = *(short8*)hi;
      *(short8*)&W2lH[(size_t)c * 8] = *(short8*)lo;
    }
  } else {
    int lb = b - NWSPLIT;
    int e = lb * 256 + threadIdx.x;
    if (e < ne) atomicAdd(&cnt8[(size_t)(lb & 7) * n + col[e]], 1);
  }
}

// ---------------- scan1: sum cnt8 slices + dinv/invdeg + block-local scan ----------------
__global__ __launch_bounds__(256) void scan1_kernel(const int* __restrict__ cnt8,
    int* off, int* bsums, float* dinv, float* invdeg, int n) {
  __shared__ int lds[256];
  int t = threadIdx.x;
  int base = blockIdx.x * 1024 + t * 4;
  int v[4], s = 0;
#pragma unroll
  for (int j = 0; j < 4; ++j) {
    int i = base + j;
    int c = 0;
    if (i < n) {
#pragma unroll
      for (int xx = 0; xx < 8; ++xx) c += cnt8[(size_t)xx * n + i];
      float d = (float)(c + 1);
      dinv[i] = rsqrtf(d);
      invdeg[i] = 1.0f / d;
    }
    v[j] = c;
    s += c;
  }
  lds[t] = s;
  __syncthreads();
  int incl = s;
  for (int d = 1; d < 256; d <<= 1) {
    int y = (t >= d) ? lds[t - d] : 0;
    __syncthreads();
    incl += y;
    lds[t] = incl;
    __syncthreads();
  }
  int run = incl - s;
#pragma unroll
  for (int j = 0; j < 4; ++j) {
    if (base + j < n) off[base + j] = run;
    run += v[j];
  }
  if (t == 255) bsums[blockIdx.x] = incl;
}

__global__ __launch_bounds__(128) void scan2_kernel(const int* __restrict__ bsums,
    int* boffs, int nb) {
  __shared__ int lds[128];
  int t = threadIdx.x;
  int s = (t < nb) ? bsums[t] : 0;
  lds[t] = s;
  __syncthreads();
  int incl = s;
  for (int d = 1; d < 128; d <<= 1) {
    int y = (t >= d) ? lds[t - d] : 0;
    __syncthreads();
    incl += y;
    lds[t] = incl;
    __syncthreads();
  }
  if (t < nb) boffs[t] = incl - s;
}

// scan3: finalize off; seed the 8 privatized cursors with per-slice prefixes
__global__ __launch_bounds__(256) void scan3_kernel(int* off, int* cursor8,
    const int* __restrict__ cnt8, const int* __restrict__ boffs, int n, int ne) {
  int i = blockIdx.x * 256 + threadIdx.x;
  if (i < n) {
    int v = off[i] + boffs[i >> 10];
    off[i] = v;
    int s = v;
#pragma unroll
    for (int xx = 0; xx < 8; ++xx) {
      cursor8[(size_t)xx * n + i] = s;
      s += cnt8[(size_t)xx * n + i];
    }
  }
  if (i == 0) off[n] = ne;
}

// fill: privatized cursor (slice = block & 7, same mapping as count), packed int2
__global__ __launch_bounds__(256) void fill_kernel(const int* __restrict__ row,
    const int* __restrict__ col, const float* __restrict__ dinv,
    int* cursor8, int2* __restrict__ csr, int ne, int n) {
  int e = blockIdx.x * 256 + threadIdx.x;
  if (e >= ne) return;
  int r = row[e], c = col[e];
  int p = atomicAdd(&cursor8[(size_t)(blockIdx.x & 7) * n + c], 1);
  int2 v;
  v.x = r;
  v.y = __float_as_int(dinv[r] * dinv[c]);
  csr[p] = v;
}

// ---------------- bf16 MFMA GEMM, single-barrier, swapped operands ----------------
// Templated input dtype: F32IN=true reads fp32 rows and converts in-register
// (layer 1 consumes x directly — no separate conversion pass).
// mfma(Wfrag, INfrag, acc): output-col -> quad*4+reg, input-row -> lane&15.
template <bool F32IN>
__global__ __launch_bounds__(256, 2) void gemm_any(const void* __restrict__ INv,
    const ushort* __restrict__ Wh, const ushort* __restrict__ Wl,
    const float* __restrict__ bias, ushort* __restrict__ OUT, int nrows, int relu) {
  __shared__ ushort sWh[16384], sWl[16384];  // 64 KB
  const int t = threadIdx.x;
  const int rbase = blockIdx.x * 256;
  const int w = t >> 6, lane = t & 63;
  const int quad = lane >> 4, cl = lane & 15;

#pragma unroll
  for (int pp = 0; pp < 8; ++pp) {
    int ci = t + pp * 256;
    *(short8*)&sWh[ci * 8] = *(const short8*)&Wh[(size_t)ci * 8];
    *(short8*)&sWl[ci * 8] = *(const short8*)&Wl[(size_t)ci * 8];
  }
  __syncthreads();

  float4v acc[4][8];  // [nt: input-row tile][mt: output-col tile]
#pragma unroll
  for (int nt = 0; nt < 4; ++nt)
#pragma unroll
    for (int mt = 0; mt < 8; ++mt) acc[nt][mt] = (float4v){0.f, 0.f, 0.f, 0.f};

  const int sl = swz(lane);
  const int nrow0 = rbase + w * 64 + cl;
#pragma unroll
  for (int ks = 0; ks < 4; ++ks) {
    short8 b[4];
#pragma unroll
    for (int nt = 0; nt < 4; ++nt) {
      int gr = nrow0 + nt * 16;
      if (gr < nrows) {
        if (F32IN) {
          const float* INf = (const float*)INv;
          float4 f0 = *(const float4*)&INf[(size_t)gr * F + ks * 32 + quad * 8];
          float4 f1 = *(const float4*)&INf[(size_t)gr * F + ks * 32 + quad * 8 + 4];
          ushort h[8] = {f2bf(f0.x), f2bf(f0.y), f2bf(f0.z), f2bf(f0.w),
                         f2bf(f1.x), f2bf(f1.y), f2bf(f1.z), f2bf(f1.w)};
          b[nt] = *(short8*)h;
        } else {
          const ushort* IN = (const ushort*)INv;
          b[nt] = *(const short8*)&IN[(size_t)gr * F + ks * 32 + quad * 8];
        }
      } else {
        b[nt] = (short8){0, 0, 0, 0, 0, 0, 0, 0};
      }
    }
    const int base = ((ks >> 1) * 1024 + (ks & 1) * 64 + sl) * 8;
#pragma unroll
    for (int mt = 0; mt < 8; ++mt) {
      int chunk = base + mt * 128 * 8;
      short8 a_h = *(short8*)&sWh[chunk];
      short8 a_l = *(short8*)&sWl[chunk];
#pragma unroll
      for (int nt = 0; nt < 4; ++nt) {
        acc[nt][mt] = __builtin_amdgcn_mfma_f32_16x16x32_bf16(a_h, b[nt], acc[nt][mt], 0, 0, 0);
        acc[nt][mt] = __builtin_amdgcn_mfma_f32_16x16x32_bf16(a_l, b[nt], acc[nt][mt], 0, 0, 0);
      }
    }
  }
  // epilogue: lane holds input row (nrow0+nt*16), output cols mt*16+quad*4+(0..3)
#pragma unroll
  for (int mt = 0; mt < 8; ++mt) {
    float4 bv = *(const float4*)&bias[mt * 16 + quad * 4];
#pragma unroll
    for (int nt = 0; nt < 4; ++nt) {
      int gr = nrow0 + nt * 16;
      if (gr < nrows) {
        float v0 = acc[nt][mt][0] + bv.x;
        float v1 = acc[nt][mt][1] + bv.y;
        float v2 = acc[nt][mt][2] + bv.z;
        float v3 = acc[nt][mt][3] + bv.w;
        if (relu) {
          v0 = fmaxf(v0, 0.f); v1 = fmaxf(v1, 0.f);
          v2 = fmaxf(v2, 0.f); v3 = fmaxf(v3, 0.f);
        }
        ushort o[4] = {f2bf(v0), f2bf(v1), f2bf(v2), f2bf(v3)};
        *(ushort4*)&OUT[(size_t)gr * F + mt * 16 + quad * 4] = *(ushort4*)o;
      }
    }
  }
}

// ---------------- gather + finalize (fused): one 16-lane group per node ----------------
__global__ __launch_bounds__(256) void gather_kernel(const int* __restrict__ off,
    const int2* __restrict__ csr, const ushort* __restrict__ B,
    const float* __restrict__ invdeg, const float* __restrict__ bc,
    ushort* __restrict__ A, int n) {
  int node = blockIdx.x * 16 + (threadIdx.x >> 4);
  if (node >= n) return;
  int j = (threadIdx.x & 15) * 8;
  int e0 = off[node], e1 = off[node + 1];
  float acc0[8] = {0.f, 0.f, 0.f, 0.f, 0.f, 0.f, 0.f, 0.f};
  float acc1[8] = {0.f, 0.f, 0.f, 0.f, 0.f, 0.f, 0.f, 0.f};
  int e = e0;
  for (; e + 1 < e1; e += 2) {
    int2 en0 = csr[e];
    int2 en1 = csr[e + 1];
    short8 v0 = *(const short8*)&B[(size_t)en0.x * F + j];
    short8 v1 = *(const short8*)&B[(size_t)en1.x * F + j];
    float f0 = __int_as_float(en0.y);
    float f1 = __int_as_float(en1.y);
#pragma unroll
    for (int q = 0; q < 8; ++q) {
      acc0[q] += f0 * bf2f((ushort)v0[q]);
      acc1[q] += f1 * bf2f((ushort)v1[q]);
    }
  }
  if (e < e1) {
    int2 en = csr[e];
    short8 v = *(const short8*)&B[(size_t)en.x * F + j];
    float f = __int_as_float(en.y);
#pragma unroll
    for (int q = 0; q < 8; ++q) acc0[q] += f * bf2f((ushort)v[q]);
  }
  float id = invdeg[node];
  short8 sv = *(const short8*)&B[(size_t)node * F + j];
  float4 b0 = *(const float4*)&bc[j];
  float4 b1 = *(const float4*)&bc[j + 4];
  float bcv[8] = {b0.x, b0.y, b0.z, b0.w, b1.x, b1.y, b1.z, b1.w};
  ushort o[8];
#pragma unroll
  for (int q = 0; q < 8; ++q)
    o[q] = f2bf(fmaxf((acc0[q] + acc1[q] + bf2f((ushort)sv[q]) * id) * id + bcv[q], 0.f));
  *(short8*)&A[(size_t)node * F + j] = *(short8*)o;
}

// ---------------- logits via MFMA + fused log_softmax (bf16 input) ----------------
__global__ __launch_bounds__(256) void logits_mfma(const ushort* __restrict__ X,
    const ushort* __restrict__ W2h, const ushort* __restrict__ W2l,
    const float* __restrict__ b2, float* __restrict__ out, int nrows) {
  __shared__ ushort sWh[6144], sWl[6144];
  __shared__ float b2s[48];
  const int t = threadIdx.x;
#pragma unroll
  for (int pp = 0; pp < 3; ++pp) {
    int c = t + pp * 256;
    *(short8*)&sWh[c * 8] = *(const short8*)&W2h[(size_t)c * 8];
    *(short8*)&sWl[c * 8] = *(const short8*)&W2l[(size_t)c * 8];
  }
  if (t < 48) b2s[t] = (t < C_CLS) ? b2[t] : -1e30f;
  __syncthreads();

  const int w = t >> 6, lane = t & 63;
  const int quad = lane >> 4, cl = lane & 15;
  const int row0 = (blockIdx.x * 4 + w) * 16;

  float4v acc[3];
#pragma unroll
  for (int ct = 0; ct < 3; ++ct) acc[ct] = (float4v){0.f, 0.f, 0.f, 0.f};

#pragma unroll
  for (int ks = 0; ks < 4; ++ks) {
    int gr = row0 + cl;
    short8 a;
    if (gr < nrows) a = *(const short8*)&X[(size_t)gr * F + ks * 32 + quad * 8];
    else a = (short8){0, 0, 0, 0, 0, 0, 0, 0};
#pragma unroll
    for (int ct = 0; ct < 3; ++ct) {
      int chunk = ((ct * 4 + ks) * 64 + lane) * 8;
      short8 b_h = *(short8*)&sWh[chunk];
      short8 b_l = *(short8*)&sWl[chunk];
      acc[ct] = __builtin_amdgcn_mfma_f32_16x16x32_bf16(a, b_h, acc[ct], 0, 0, 0);
      acc[ct] = __builtin_amdgcn_mfma_f32_16x16x32_bf16(a, b_l, acc[ct], 0, 0, 0);
    }
  }

  float b0 = b2s[cl], b1 = b2s[16 + cl], b2v = b2s[32 + cl];
  float lse[4];
#pragma unroll
  for (int reg = 0; reg < 4; ++reg) {
    float v0 = acc[0][reg] + b0;
    float v1 = acc[1][reg] + b1;
    float v2 = acc[2][reg] + b2v;
    acc[0][reg] = v0; acc[1][reg] = v1; acc[2][reg] = v2;
    float m = fmaxf(fmaxf(v0, v1), v2);
#pragma unroll
    for (int o = 1; o < 16; o <<= 1) m = fmaxf(m, __shfl_xor(m, o));
    float s = __expf(v0 - m) + __expf(v1 - m) + __expf(v2 - m);
#pragma unroll
    for (int o = 1; o < 16; o <<= 1) s += __shfl_xor(s, o);
    lse[reg] = logf(s) + m;
  }
#pragma unroll
  for (int reg = 0; reg < 4; ++reg) {
    int gr = row0 + quad * 4 + reg;
    if (gr < nrows) {
      out[(size_t)gr * C_CLS + cl] = acc[0][reg] - lse[reg];
      out[(size_t)gr * C_CLS + 16 + cl] = acc[1][reg] - lse[reg];
      if (cl < 8) out[(size_t)gr * C_CLS + 32 + cl] = acc[2][reg] - lse[reg];
    }
  }
}

extern "C" void kernel_launch(void* const* d_in, const int* in_sizes, int n_in,
                              void* d_out, int out_size, void* d_ws, size_t ws_size,
                              hipStream_t stream) {
  const float* x    = (const float*)d_in[0];
  const int*   ei   = (const int*)d_in[1];
  const float* imp  = (const float*)d_in[2];
  const float* W1   = (const float*)d_in[3];
  const float* bl1  = (const float*)d_in[4];
  const float* bc1  = (const float*)d_in[5];
  const float* W2   = (const float*)d_in[6];
  const float* bl2  = (const float*)d_in[7];
  const float* bc2  = (const float*)d_in[8];
  const float* W3   = (const float*)d_in[9];
  const float* bl3  = (const float*)d_in[10];
  const float* bc3  = (const float*)d_in[11];
  const float* Wl1  = (const float*)d_in[12];
  const float* bli1 = (const float*)d_in[13];
  const float* Wl2  = (const float*)d_in[14];
  const float* bli2 = (const float*)d_in[15];
  float* out = (float*)d_out;

  const int N = in_sizes[0] / F;      // 100000
  const int E = in_sizes[1] / 2;      // 600000

  ushort* A16 = (ushort*)d_ws;                 // N*F
  ushort* B16 = A16 + (size_t)N * F;           // N*F
  ushort* WhP = B16 + (size_t)N * F;           // 8192*8
  ushort* WlP = WhP + 65536;                   // 8192*8
  ushort* W2hH = WlP + 65536;                  // 768*8
  ushort* W2lH = W2hH + 6144;                  // 768*8
  int2*  csr  = (int2*)(W2lH + 6144);          // E (8 B each)
  float* dinv = (float*)(csr + E);             // N
  float* invdeg = dinv + N;                    // N
  int*   cnt8 = (int*)(invdeg + N);            // 8N
  int*   cursor8 = cnt8 + (size_t)8 * N;       // 8N
  int*   off  = cursor8 + (size_t)8 * N;       // N+1
  int*   bsums = off + N + 1;                  // <=128
  int*   boffs = bsums + 128;                  // <=128

  const int* rowv = ei;
  const int* colv = ei + E;

  int nbN  = (N + 255) / 256;
  int nbE  = (E + 255) / 256;
  int nbG  = (N + 255) / 256;
  int nbS1 = (N + 1023) / 1024;
  int nbGa = (N + 15) / 16;
  int nbLo = (N + 63) / 64;

  // ---- one-time prep: fused weight-split + privatized count ----
  hipMemsetAsync(cnt8, 0, (size_t)8 * N * sizeof(int), stream);
  setup_kernel<<<NWSPLIT + nbE, 256, 0, stream>>>(
      W1, imp, W2, W3, Wl1, Wl2, WhP, WlP, W2hH, W2lH, colv, cnt8, E, N);
  scan1_kernel<<<nbS1, 256, 0, stream>>>(cnt8, off, bsums, dinv, invdeg, N);
  scan2_kernel<<<1, 128, 0, stream>>>(bsums, boffs, nbS1);
  scan3_kernel<<<nbN, 256, 0, stream>>>(off, cursor8, cnt8, boffs, N, E);
  fill_kernel<<<nbE, 256, 0, stream>>>(rowv, colv, dinv, cursor8, csr, E, N);

  // ---- conv layer 1 (reads fp32 x directly; importance folded into WhP/WlP) ----
  gemm_any<true><<<nbG, 256, 0, stream>>>(x, WhP, WlP, bl1, B16, N, 0);
  gather_kernel<<<nbGa, 256, 0, stream>>>(off, csr, B16, invdeg, bc1, A16, N);

  // ---- conv layer 2 ----
  gemm_any<false><<<nbG, 256, 0, stream>>>(A16, WhP + 16384, WlP + 16384, bl2, B16, N, 0);
  gather_kernel<<<nbGa, 256, 0, stream>>>(off, csr, B16, invdeg, bc2, A16, N);

  // ---- conv layer 3 ----
  gemm_any<false><<<nbG, 256, 0, stream>>>(A16, WhP + 32768, WlP + 32768, bl3, B16, N, 0);
  gather_kernel<<<nbGa, 256, 0, stream>>>(off, csr, B16, invdeg, bc3, A16, N);

  // ---- dense head ----
  gemm_any<false><<<nbG, 256, 0, stream>>>(A16, WhP + 49152, WlP + 49152, bli1, B16, N, 1);
  logits_mfma<<<nbLo, 256, 0, stream>>>(B16, W2hH, W2lH, bli2, out, N);
}

// Round 11
// 355.731 us; speedup vs baseline: 10.1185x; 1.0156x over previous
//
#include <hip/hip_runtime.h>
#include <hip/hip_bf16.h>

#define F 128
#define C_CLS 40
#define NWSPLIT 35

typedef __attribute__((ext_vector_type(8))) short short8;
typedef __attribute__((ext_vector_type(4))) float float4v;
typedef unsigned short ushort;

__device__ inline float bf2f(ushort u) {
  unsigned int x = ((unsigned int)u) << 16;
  return __builtin_bit_cast(float, x);
}
__device__ inline ushort f2bf(float f) {
  __hip_bfloat16 h = __float2bfloat16(f);
  return __builtin_bit_cast(ushort, h);
}
__device__ inline void split_bf16(float f, ushort& hi, ushort& lo) {
  hi = f2bf(f);
  lo = f2bf(f - bf2f(hi));
}
__device__ inline int swz(int lane) { return lane ^ ((lane >> 4) & 3); }

// ---------------- setup (heterogeneous): weight-split | count8 ----------------
// Main planes: hi-only bf16 (activation bf16 rounding dominates error budget).
// Head plane (logits): hi+lo retained (final output precision).
__global__ __launch_bounds__(256) void setup_kernel(
    const float* __restrict__ W1, const float* __restrict__ imp,
    const float* __restrict__ W2, const float* __restrict__ W3,
    const float* __restrict__ Wl1, const float* __restrict__ Wh2,
    ushort* __restrict__ WhP,
    ushort* __restrict__ W2hH, ushort* __restrict__ W2lH,
    const int* __restrict__ col, int* __restrict__ cnt8,
    int ne, int n) {
  int b = blockIdx.x;
  if (b < NWSPLIT) {
    int ci = b * 256 + threadIdx.x;
    if (ci < 8192) {
      const float* src[4] = {W1, W2, W3, Wl1};
      int p = ci >> 11, c = ci & 2047;
      int kc = c >> 10, ct = (c >> 7) & 7, ks = (c >> 6) & 1, ln = c & 63;
      int dl = swz(ln);
      int colw = ct * 16 + (dl & 15);
      int k = kc * 64 + ks * 32 + (dl >> 4) * 8;
      float4 f0 = *(const float4*)&src[p][(size_t)colw * F + k];
      float4 f1 = *(const float4*)&src[p][(size_t)colw * F + k + 4];
      float v[8] = {f0.x, f0.y, f0.z, f0.w, f1.x, f1.y, f1.z, f1.w};
      if (p == 0) {
        float4 i0 = *(const float4*)&imp[k];
        float4 i1 = *(const float4*)&imp[k + 4];
        v[0] *= i0.x; v[1] *= i0.y; v[2] *= i0.z; v[3] *= i0.w;
        v[4] *= i1.x; v[5] *= i1.y; v[6] *= i1.z; v[7] *= i1.w;
      }
      ushort hi[8];
#pragma unroll
      for (int j = 0; j < 8; ++j) hi[j] = f2bf(v[j]);
      *(short8*)&WhP[(size_t)ci * 8] = *(short8*)hi;
    } else if (ci < 8192 + 768) {
      int c = ci - 8192;
      int ct = c >> 8, ks = (c >> 6) & 3, ln = c & 63;
      int colw = ct * 16 + (ln & 15);
      int k = ks * 32 + (ln >> 4) * 8;
      float v[8];
      if (colw < C_CLS) {
        float4 f0 = *(const float4*)&Wh2[(size_t)colw * F + k];
        float4 f1 = *(const float4*)&Wh2[(size_t)colw * F + k + 4];
        v[0] = f0.x; v[1] = f0.y; v[2] = f0.z; v[3] = f0.w;
        v[4] = f1.x; v[5] = f1.y; v[6] = f1.z; v[7] = f1.w;
      } else {
#pragma unroll
        for (int j = 0; j < 8; ++j) v[j] = 0.f;
      }
      ushort hi[8], lo[8];
#pragma unroll
      for (int j = 0; j < 8; ++j) split_bf16(v[j], hi[j], lo[j]);
      *(short8*)&W2hH[(size_t)c * 8] = *(short8*)hi;
      *(short8*)&W2lH[(size_t)c * 8] = *(short8*)lo;
    }
  } else {
    int lb = b - NWSPLIT;
    int e = lb * 256 + threadIdx.x;
    if (e < ne) atomicAdd(&cnt8[(size_t)(lb & 7) * n + col[e]], 1);
  }
}

// ---------------- scan1: sum cnt8 slices + dinv/invdeg + block-local scan ----------------
__global__ __launch_bounds__(256) void scan1_kernel(const int* __restrict__ cnt8,
    int* off, int* bsums, float* dinv, float* invdeg, int n) {
  __shared__ int lds[256];
  int t = threadIdx.x;
  int base = blockIdx.x * 1024 + t * 4;
  int v[4], s = 0;
#pragma unroll
  for (int j = 0; j < 4; ++j) {
    int i = base + j;
    int c = 0;
    if (i < n) {
#pragma unroll
      for (int xx = 0; xx < 8; ++xx) c += cnt8[(size_t)xx * n + i];
      float d = (float)(c + 1);
      dinv[i] = rsqrtf(d);
      invdeg[i] = 1.0f / d;
    }
    v[j] = c;
    s += c;
  }
  lds[t] = s;
  __syncthreads();
  int incl = s;
  for (int d = 1; d < 256; d <<= 1) {
    int y = (t >= d) ? lds[t - d] : 0;
    __syncthreads();
    incl += y;
    lds[t] = incl;
    __syncthreads();
  }
  int run = incl - s;
#pragma unroll
  for (int j = 0; j < 4; ++j) {
    if (base + j < n) off[base + j] = run;
    run += v[j];
  }
  if (t == 255) bsums[blockIdx.x] = incl;
}

__global__ __launch_bounds__(128) void scan2_kernel(const int* __restrict__ bsums,
    int* boffs, int nb) {
  __shared__ int lds[128];
  int t = threadIdx.x;
  int s = (t < nb) ? bsums[t] : 0;
  lds[t] = s;
  __syncthreads();
  int incl = s;
  for (int d = 1; d < 128; d <<= 1) {
    int y = (t >= d) ? lds[t - d] : 0;
    __syncthreads();
    incl += y;
    lds[t] = incl;
    __syncthreads();
  }
  if (t < nb) boffs[t] = incl - s;
}

// scan3: finalize off; seed the 8 privatized cursors with per-slice prefixes
__global__ __launch_bounds__(256) void scan3_kernel(int* off, int* cursor8,
    const int* __restrict__ cnt8, const int* __restrict__ boffs, int n, int ne) {
  int i = blockIdx.x * 256 + threadIdx.x;
  if (i < n) {
    int v = off[i] + boffs[i >> 10];
    off[i] = v;
    int s = v;
#pragma unroll
    for (int xx = 0; xx < 8; ++xx) {
      cursor8[(size_t)xx * n + i] = s;
      s += cnt8[(size_t)xx * n + i];
    }
  }
  if (i == 0) off[n] = ne;
}

// fill: privatized cursor (slice = block & 7, same mapping as count), packed int2
__global__ __launch_bounds__(256) void fill_kernel(const int* __restrict__ row,
    const int* __restrict__ col, const float* __restrict__ dinv,
    int* cursor8, int2* __restrict__ csr, int ne, int n) {
  int e = blockIdx.x * 256 + threadIdx.x;
  if (e >= ne) return;
  int r = row[e], c = col[e];
  int p = atomicAdd(&cursor8[(size_t)(blockIdx.x & 7) * n + c], 1);
  int2 v;
  v.x = r;
  v.y = __float_as_int(dinv[r] * dinv[c]);
  csr[p] = v;
}

// ---------------- bf16 MFMA GEMM, single-barrier, hi-only weights ----------------
// mfma(Wfrag, INfrag, acc): output-col -> quad*4+reg, input-row -> lane&15.
// 32 KB LDS (weights staged once); A fragments straight from global.
template <bool F32IN>
__global__ __launch_bounds__(256, 2) void gemm_any(const void* __restrict__ INv,
    const ushort* __restrict__ Wh,
    const float* __restrict__ bias, ushort* __restrict__ OUT, int nrows, int relu) {
  __shared__ ushort sWh[16384];  // 32 KB
  const int t = threadIdx.x;
  const int rbase = blockIdx.x * 256;
  const int w = t >> 6, lane = t & 63;
  const int quad = lane >> 4, cl = lane & 15;

#pragma unroll
  for (int pp = 0; pp < 8; ++pp) {
    int ci = t + pp * 256;
    *(short8*)&sWh[ci * 8] = *(const short8*)&Wh[(size_t)ci * 8];
  }
  __syncthreads();

  float4v acc[4][8];  // [nt: input-row tile][mt: output-col tile]
#pragma unroll
  for (int nt = 0; nt < 4; ++nt)
#pragma unroll
    for (int mt = 0; mt < 8; ++mt) acc[nt][mt] = (float4v){0.f, 0.f, 0.f, 0.f};

  const int sl = swz(lane);
  const int nrow0 = rbase + w * 64 + cl;
#pragma unroll
  for (int ks = 0; ks < 4; ++ks) {
    short8 b[4];
#pragma unroll
    for (int nt = 0; nt < 4; ++nt) {
      int gr = nrow0 + nt * 16;
      if (gr < nrows) {
        if (F32IN) {
          const float* INf = (const float*)INv;
          float4 f0 = *(const float4*)&INf[(size_t)gr * F + ks * 32 + quad * 8];
          float4 f1 = *(const float4*)&INf[(size_t)gr * F + ks * 32 + quad * 8 + 4];
          ushort h[8] = {f2bf(f0.x), f2bf(f0.y), f2bf(f0.z), f2bf(f0.w),
                         f2bf(f1.x), f2bf(f1.y), f2bf(f1.z), f2bf(f1.w)};
          b[nt] = *(short8*)h;
        } else {
          const ushort* IN = (const ushort*)INv;
          b[nt] = *(const short8*)&IN[(size_t)gr * F + ks * 32 + quad * 8];
        }
      } else {
        b[nt] = (short8){0, 0, 0, 0, 0, 0, 0, 0};
      }
    }
    const int base = ((ks >> 1) * 1024 + (ks & 1) * 64 + sl) * 8;
#pragma unroll
    for (int mt = 0; mt < 8; ++mt) {
      short8 a_h = *(short8*)&sWh[base + mt * 128 * 8];
#pragma unroll
      for (int nt = 0; nt < 4; ++nt)
        acc[nt][mt] = __builtin_amdgcn_mfma_f32_16x16x32_bf16(a_h, b[nt], acc[nt][mt], 0, 0, 0);
    }
  }
  // epilogue: lane holds input row (nrow0+nt*16), output cols mt*16+quad*4+(0..3)
#pragma unroll
  for (int mt = 0; mt < 8; ++mt) {
    float4 bv = *(const float4*)&bias[mt * 16 + quad * 4];
#pragma unroll
    for (int nt = 0; nt < 4; ++nt) {
      int gr = nrow0 + nt * 16;
      if (gr < nrows) {
        float v0 = acc[nt][mt][0] + bv.x;
        float v1 = acc[nt][mt][1] + bv.y;
        float v2 = acc[nt][mt][2] + bv.z;
        float v3 = acc[nt][mt][3] + bv.w;
        if (relu) {
          v0 = fmaxf(v0, 0.f); v1 = fmaxf(v1, 0.f);
          v2 = fmaxf(v2, 0.f); v3 = fmaxf(v3, 0.f);
        }
        ushort o[4] = {f2bf(v0), f2bf(v1), f2bf(v2), f2bf(v3)};
        *(ushort4*)&OUT[(size_t)gr * F + mt * 16 + quad * 4] = *(ushort4*)o;
      }
    }
  }
}

// ---------------- gather + finalize: one 16-lane group per node, 4 chains ----------------
__global__ __launch_bounds__(256) void gather_kernel(const int* __restrict__ off,
    const int2* __restrict__ csr, const ushort* __restrict__ B,
    const float* __restrict__ invdeg, const float* __restrict__ bc,
    ushort* __restrict__ A, int n) {
  int node = blockIdx.x * 16 + (threadIdx.x >> 4);
  if (node >= n) return;
  int j = (threadIdx.x & 15) * 8;
  int e0 = off[node], e1 = off[node + 1];
  float a0[8] = {0, 0, 0, 0, 0, 0, 0, 0};
  float a1[8] = {0, 0, 0, 0, 0, 0, 0, 0};
  float a2[8] = {0, 0, 0, 0, 0, 0, 0, 0};
  float a3[8] = {0, 0, 0, 0, 0, 0, 0, 0};
  int e = e0;
  for (; e + 3 < e1; e += 4) {
    int2 en0 = csr[e], en1 = csr[e + 1], en2 = csr[e + 2], en3 = csr[e + 3];
    short8 v0 = *(const short8*)&B[(size_t)en0.x * F + j];
    short8 v1 = *(const short8*)&B[(size_t)en1.x * F + j];
    short8 v2 = *(const short8*)&B[(size_t)en2.x * F + j];
    short8 v3 = *(const short8*)&B[(size_t)en3.x * F + j];
    float f0 = __int_as_float(en0.y), f1 = __int_as_float(en1.y);
    float f2 = __int_as_float(en2.y), f3 = __int_as_float(en3.y);
#pragma unroll
    for (int q = 0; q < 8; ++q) {
      a0[q] += f0 * bf2f((ushort)v0[q]);
      a1[q] += f1 * bf2f((ushort)v1[q]);
      a2[q] += f2 * bf2f((ushort)v2[q]);
      a3[q] += f3 * bf2f((ushort)v3[q]);
    }
  }
  if (e + 1 < e1) {  // 2-3 remaining: take two
    int2 en0 = csr[e], en1 = csr[e + 1];
    short8 v0 = *(const short8*)&B[(size_t)en0.x * F + j];
    short8 v1 = *(const short8*)&B[(size_t)en1.x * F + j];
    float f0 = __int_as_float(en0.y), f1 = __int_as_float(en1.y);
#pragma unroll
    for (int q = 0; q < 8; ++q) {
      a0[q] += f0 * bf2f((ushort)v0[q]);
      a1[q] += f1 * bf2f((ushort)v1[q]);
    }
    e += 2;
  }
  if (e < e1) {  // last one
    int2 en = csr[e];
    short8 v = *(const short8*)&B[(size_t)en.x * F + j];
    float f = __int_as_float(en.y);
#pragma unroll
    for (int q = 0; q < 8; ++q) a0[q] += f * bf2f((ushort)v[q]);
  }
  float id = invdeg[node];
  short8 sv = *(const short8*)&B[(size_t)node * F + j];
  float4 b0 = *(const float4*)&bc[j];
  float4 b1 = *(const float4*)&bc[j + 4];
  float bcv[8] = {b0.x, b0.y, b0.z, b0.w, b1.x, b1.y, b1.z, b1.w};
  ushort o[8];
#pragma unroll
  for (int q = 0; q < 8; ++q) {
    float s = (a0[q] + a1[q]) + (a2[q] + a3[q]);
    o[q] = f2bf(fmaxf((s + bf2f((ushort)sv[q]) * id) * id + bcv[q], 0.f));
  }
  *(short8*)&A[(size_t)node * F + j] = *(short8*)o;
}

// ---------------- logits via MFMA + fused log_softmax (bf16 input, hi+lo W) ----------------
__global__ __launch_bounds__(256) void logits_mfma(const ushort* __restrict__ X,
    const ushort* __restrict__ W2h, const ushort* __restrict__ W2l,
    const float* __restrict__ b2, float* __restrict__ out, int nrows) {
  __shared__ ushort sWh[6144], sWl[6144];
  __shared__ float b2s[48];
  const int t = threadIdx.x;
#pragma unroll
  for (int pp = 0; pp < 3; ++pp) {
    int c = t + pp * 256;
    *(short8*)&sWh[c * 8] = *(const short8*)&W2h[(size_t)c * 8];
    *(short8*)&sWl[c * 8] = *(const short8*)&W2l[(size_t)c * 8];
  }
  if (t < 48) b2s[t] = (t < C_CLS) ? b2[t] : -1e30f;
  __syncthreads();

  const int w = t >> 6, lane = t & 63;
  const int quad = lane >> 4, cl = lane & 15;
  const int row0 = (blockIdx.x * 4 + w) * 16;

  float4v acc[3];
#pragma unroll
  for (int ct = 0; ct < 3; ++ct) acc[ct] = (float4v){0.f, 0.f, 0.f, 0.f};

#pragma unroll
  for (int ks = 0; ks < 4; ++ks) {
    int gr = row0 + cl;
    short8 a;
    if (gr < nrows) a = *(const short8*)&X[(size_t)gr * F + ks * 32 + quad * 8];
    else a = (short8){0, 0, 0, 0, 0, 0, 0, 0};
#pragma unroll
    for (int ct = 0; ct < 3; ++ct) {
      int chunk = ((ct * 4 + ks) * 64 + lane) * 8;
      short8 b_h = *(short8*)&sWh[chunk];
      short8 b_l = *(short8*)&sWl[chunk];
      acc[ct] = __builtin_amdgcn_mfma_f32_16x16x32_bf16(a, b_h, acc[ct], 0, 0, 0);
      acc[ct] = __builtin_amdgcn_mfma_f32_16x16x32_bf16(a, b_l, acc[ct], 0, 0, 0);
    }
  }

  float b0 = b2s[cl], b1 = b2s[16 + cl], b2v = b2s[32 + cl];
  float lse[4];
#pragma unroll
  for (int reg = 0; reg < 4; ++reg) {
    float v0 = acc[0][reg] + b0;
    float v1 = acc[1][reg] + b1;
    float v2 = acc[2][reg] + b2v;
    acc[0][reg] = v0; acc[1][reg] = v1; acc[2][reg] = v2;
    float m = fmaxf(fmaxf(v0, v1), v2);
#pragma unroll
    for (int o = 1; o < 16; o <<= 1) m = fmaxf(m, __shfl_xor(m, o));
    float s = __expf(v0 - m) + __expf(v1 - m) + __expf(v2 - m);
#pragma unroll
    for (int o = 1; o < 16; o <<= 1) s += __shfl_xor(s, o);
    lse[reg] = logf(s) + m;
  }
#pragma unroll
  for (int reg = 0; reg < 4; ++reg) {
    int gr = row0 + quad * 4 + reg;
    if (gr < nrows) {
      out[(size_t)gr * C_CLS + cl] = acc[0][reg] - lse[reg];
      out[(size_t)gr * C_CLS + 16 + cl] = acc[1][reg] - lse[reg];
      if (cl < 8) out[(size_t)gr * C_CLS + 32 + cl] = acc[2][reg] - lse[reg];
    }
  }
}

extern "C" void kernel_launch(void* const* d_in, const int* in_sizes, int n_in,
                              void* d_out, int out_size, void* d_ws, size_t ws_size,
                              hipStream_t stream) {
  const float* x    = (const float*)d_in[0];
  const int*   ei   = (const int*)d_in[1];
  const float* imp  = (const float*)d_in[2];
  const float* W1   = (const float*)d_in[3];
  const float* bl1  = (const float*)d_in[4];
  const float* bc1  = (const float*)d_in[5];
  const float* W2   = (const float*)d_in[6];
  const float* bl2  = (const float*)d_in[7];
  const float* bc2  = (const float*)d_in[8];
  const float* W3   = (const float*)d_in[9];
  const float* bl3  = (const float*)d_in[10];
  const float* bc3  = (const float*)d_in[11];
  const float* Wl1  = (const float*)d_in[12];
  const float* bli1 = (const float*)d_in[13];
  const float* Wl2  = (const float*)d_in[14];
  const float* bli2 = (const float*)d_in[15];
  float* out = (float*)d_out;

  const int N = in_sizes[0] / F;      // 100000
  const int E = in_sizes[1] / 2;      // 600000

  ushort* A16 = (ushort*)d_ws;                 // N*F
  ushort* B16 = A16 + (size_t)N * F;           // N*F
  ushort* WhP = B16 + (size_t)N * F;           // 8192*8
  ushort* W2hH = WhP + 65536;                  // 768*8
  ushort* W2lH = W2hH + 6144;                  // 768*8
  int2*  csr  = (int2*)(W2lH + 6144);          // E (8 B each)
  float* dinv = (float*)(csr + E);             // N
  float* invdeg = dinv + N;                    // N
  int*   cnt8 = (int*)(invdeg + N);            // 8N
  int*   cursor8 = cnt8 + (size_t)8 * N;       // 8N
  int*   off  = cursor8 + (size_t)8 * N;       // N+1
  int*   bsums = off + N + 1;                  // <=128
  int*   boffs = bsums + 128;                  // <=128

  const int* rowv = ei;
  const int* colv = ei + E;

  int nbN  = (N + 255) / 256;
  int nbE  = (E + 255) / 256;
  int nbG  = (N + 255) / 256;
  int nbS1 = (N + 1023) / 1024;
  int nbGa = (N + 15) / 16;
  int nbLo = (N + 63) / 64;

  // ---- one-time prep: fused weight-split + privatized count ----
  hipMemsetAsync(cnt8, 0, (size_t)8 * N * sizeof(int), stream);
  setup_kernel<<<NWSPLIT + nbE, 256, 0, stream>>>(
      W1, imp, W2, W3, Wl1, Wl2, WhP, W2hH, W2lH, colv, cnt8, E, N);
  scan1_kernel<<<nbS1, 256, 0, stream>>>(cnt8, off, bsums, dinv, invdeg, N);
  scan2_kernel<<<1, 128, 0, stream>>>(bsums, boffs, nbS1);
  scan3_kernel<<<nbN, 256, 0, stream>>>(off, cursor8, cnt8, boffs, N, E);
  fill_kernel<<<nbE, 256, 0, stream>>>(rowv, colv, dinv, cursor8, csr, E, N);

  // ---- conv layer 1 (reads fp32 x directly; importance folded into WhP) ----
  gemm_any<true><<<nbG, 256, 0, stream>>>(x, WhP, bl1, B16, N, 0);
  gather_kernel<<<nbGa, 256, 0, stream>>>(off, csr, B16, invdeg, bc1, A16, N);

  // ---- conv layer 2 ----
  gemm_any<false><<<nbG, 256, 0, stream>>>(A16, WhP + 16384, bl2, B16, N, 0);
  gather_kernel<<<nbGa, 256, 0, stream>>>(off, csr, B16, invdeg, bc2, A16, N);

  // ---- conv layer 3 ----
  gemm_any<false><<<nbG, 256, 0, stream>>>(A16, WhP + 32768, bl3, B16, N, 0);
  gather_kernel<<<nbGa, 256, 0, stream>>>(off, csr, B16, invdeg, bc3, A16, N);

  // ---- dense head ----
  gemm_any<false><<<nbG, 256, 0, stream>>>(A16, WhP + 49152, bli1, B16, N, 1);
  logits_mfma<<<nbLo, 256, 0, stream>>>(B16, W2hH, W2lH, bli2, out, N);
}

// Round 12
// 327.488 us; speedup vs baseline: 10.9911x; 1.0862x over previous
//
#include <hip/hip_runtime.h>
#include <hip/hip_bf16.h>

#define F 128
#define C_CLS 40
#define NWSPLIT 35
#define ELLCAP 32

typedef __attribute__((ext_vector_type(8))) short short8;
typedef __attribute__((ext_vector_type(4))) float float4v;
typedef unsigned short ushort;

__device__ inline float bf2f(ushort u) {
  unsigned int x = ((unsigned int)u) << 16;
  return __builtin_bit_cast(float, x);
}
__device__ inline ushort f2bf(float f) {
  __hip_bfloat16 h = __float2bfloat16(f);
  return __builtin_bit_cast(ushort, h);
}
__device__ inline void split_bf16(float f, ushort& hi, ushort& lo) {
  hi = f2bf(f);
  lo = f2bf(f - bf2f(hi));
}
__device__ inline int swz(int lane) { return lane ^ ((lane >> 4) & 3); }

// ---------------- setup (heterogeneous): weight-split | one-pass ELL fill ----------------
// cntPad: one counter per 64B line (no false sharing). ell[c*32+p] = src row.
__global__ __launch_bounds__(256) void setup_kernel(
    const float* __restrict__ W1, const float* __restrict__ imp,
    const float* __restrict__ W2, const float* __restrict__ W3,
    const float* __restrict__ Wl1, const float* __restrict__ Wh2,
    ushort* __restrict__ WhP,
    ushort* __restrict__ W2hH, ushort* __restrict__ W2lH,
    const int* __restrict__ row, const int* __restrict__ col,
    int* __restrict__ cntPad, int* __restrict__ ell,
    int ne, int n) {
  int b = blockIdx.x;
  if (b < NWSPLIT) {
    int ci = b * 256 + threadIdx.x;
    if (ci < 8192) {
      const float* src[4] = {W1, W2, W3, Wl1};
      int p = ci >> 11, c = ci & 2047;
      int kc = c >> 10, ct = (c >> 7) & 7, ks = (c >> 6) & 1, ln = c & 63;
      int dl = swz(ln);
      int colw = ct * 16 + (dl & 15);
      int k = kc * 64 + ks * 32 + (dl >> 4) * 8;
      float4 f0 = *(const float4*)&src[p][(size_t)colw * F + k];
      float4 f1 = *(const float4*)&src[p][(size_t)colw * F + k + 4];
      float v[8] = {f0.x, f0.y, f0.z, f0.w, f1.x, f1.y, f1.z, f1.w};
      if (p == 0) {
        float4 i0 = *(const float4*)&imp[k];
        float4 i1 = *(const float4*)&imp[k + 4];
        v[0] *= i0.x; v[1] *= i0.y; v[2] *= i0.z; v[3] *= i0.w;
        v[4] *= i1.x; v[5] *= i1.y; v[6] *= i1.z; v[7] *= i1.w;
      }
      ushort hi[8];
#pragma unroll
      for (int j = 0; j < 8; ++j) hi[j] = f2bf(v[j]);
      *(short8*)&WhP[(size_t)ci * 8] = *(short8*)hi;
    } else if (ci < 8192 + 768) {
      int c = ci - 8192;
      int ct = c >> 8, ks = (c >> 6) & 3, ln = c & 63;
      int colw = ct * 16 + (ln & 15);
      int k = ks * 32 + (ln >> 4) * 8;
      float v[8];
      if (colw < C_CLS) {
        float4 f0 = *(const float4*)&Wh2[(size_t)colw * F + k];
        float4 f1 = *(const float4*)&Wh2[(size_t)colw * F + k + 4];
        v[0] = f0.x; v[1] = f0.y; v[2] = f0.z; v[3] = f0.w;
        v[4] = f1.x; v[5] = f1.y; v[6] = f1.z; v[7] = f1.w;
      } else {
#pragma unroll
        for (int j = 0; j < 8; ++j) v[j] = 0.f;
      }
      ushort hi[8], lo[8];
#pragma unroll
      for (int j = 0; j < 8; ++j) split_bf16(v[j], hi[j], lo[j]);
      *(short8*)&W2hH[(size_t)c * 8] = *(short8*)hi;
      *(short8*)&W2lH[(size_t)c * 8] = *(short8*)lo;
    }
  } else {
    int e = (b - NWSPLIT) * 256 + threadIdx.x;
    if (e < ne) {
      int r = row[e], c = col[e];
      int p = atomicAdd(&cntPad[c * 16], 1);
      if (p < ELLCAP) ell[(size_t)c * ELLCAP + p] = r;
    }
  }
}

// ---------------- dinv: compact counts + dinv + invdeg ----------------
__global__ __launch_bounds__(256) void dinv_kernel(const int* __restrict__ cntPad,
    int* __restrict__ cntC, float* __restrict__ dinv, float* __restrict__ invdeg,
    int n) {
  int i = blockIdx.x * 256 + threadIdx.x;
  if (i >= n) return;
  int c = cntPad[i * 16];
  float d = (float)(c + 1);
  cntC[i] = c;
  dinv[i] = rsqrtf(d);
  invdeg[i] = 1.0f / d;
}

// ---------------- bf16 MFMA GEMM, single-barrier, hi-only weights ----------------
template <bool F32IN>
__global__ __launch_bounds__(256, 2) void gemm_any(const void* __restrict__ INv,
    const ushort* __restrict__ Wh,
    const float* __restrict__ bias, ushort* __restrict__ OUT, int nrows, int relu) {
  __shared__ ushort sWh[16384];  // 32 KB
  const int t = threadIdx.x;
  const int rbase = blockIdx.x * 256;
  const int w = t >> 6, lane = t & 63;
  const int quad = lane >> 4, cl = lane & 15;

#pragma unroll
  for (int pp = 0; pp < 8; ++pp) {
    int ci = t + pp * 256;
    *(short8*)&sWh[ci * 8] = *(const short8*)&Wh[(size_t)ci * 8];
  }
  __syncthreads();

  float4v acc[4][8];
#pragma unroll
  for (int nt = 0; nt < 4; ++nt)
#pragma unroll
    for (int mt = 0; mt < 8; ++mt) acc[nt][mt] = (float4v){0.f, 0.f, 0.f, 0.f};

  const int sl = swz(lane);
  const int nrow0 = rbase + w * 64 + cl;
#pragma unroll
  for (int ks = 0; ks < 4; ++ks) {
    short8 b[4];
#pragma unroll
    for (int nt = 0; nt < 4; ++nt) {
      int gr = nrow0 + nt * 16;
      if (gr < nrows) {
        if (F32IN) {
          const float* INf = (const float*)INv;
          float4 f0 = *(const float4*)&INf[(size_t)gr * F + ks * 32 + quad * 8];
          float4 f1 = *(const float4*)&INf[(size_t)gr * F + ks * 32 + quad * 8 + 4];
          ushort h[8] = {f2bf(f0.x), f2bf(f0.y), f2bf(f0.z), f2bf(f0.w),
                         f2bf(f1.x), f2bf(f1.y), f2bf(f1.z), f2bf(f1.w)};
          b[nt] = *(short8*)h;
        } else {
          const ushort* IN = (const ushort*)INv;
          b[nt] = *(const short8*)&IN[(size_t)gr * F + ks * 32 + quad * 8];
        }
      } else {
        b[nt] = (short8){0, 0, 0, 0, 0, 0, 0, 0};
      }
    }
    const int base = ((ks >> 1) * 1024 + (ks & 1) * 64 + sl) * 8;
#pragma unroll
    for (int mt = 0; mt < 8; ++mt) {
      short8 a_h = *(short8*)&sWh[base + mt * 128 * 8];
#pragma unroll
      for (int nt = 0; nt < 4; ++nt)
        acc[nt][mt] = __builtin_amdgcn_mfma_f32_16x16x32_bf16(a_h, b[nt], acc[nt][mt], 0, 0, 0);
    }
  }
#pragma unroll
  for (int mt = 0; mt < 8; ++mt) {
    float4 bv = *(const float4*)&bias[mt * 16 + quad * 4];
#pragma unroll
    for (int nt = 0; nt < 4; ++nt) {
      int gr = nrow0 + nt * 16;
      if (gr < nrows) {
        float v0 = acc[nt][mt][0] + bv.x;
        float v1 = acc[nt][mt][1] + bv.y;
        float v2 = acc[nt][mt][2] + bv.z;
        float v3 = acc[nt][mt][3] + bv.w;
        if (relu) {
          v0 = fmaxf(v0, 0.f); v1 = fmaxf(v1, 0.f);
          v2 = fmaxf(v2, 0.f); v3 = fmaxf(v3, 0.f);
        }
        ushort o[4] = {f2bf(v0), f2bf(v1), f2bf(v2), f2bf(v3)};
        *(ushort4*)&OUT[(size_t)gr * F + mt * 16 + quad * 4] = *(ushort4*)o;
      }
    }
  }
}

// ---------------- gather + finalize: dense ELL, int4 edge loads, on-the-fly norm ----------------
// One 16-lane group per node; 4 edges per int4; norm = dinv[r]*dinv[c] folded as
// dc * sum(dinv[r]*row). Tail slots are pre-zeroed -> row 0 loads, weight 0.
__global__ __launch_bounds__(256) void gather_kernel(const int* __restrict__ cntC,
    const int* __restrict__ ell, const ushort* __restrict__ B,
    const float* __restrict__ dinv, const float* __restrict__ invdeg,
    const float* __restrict__ bc, ushort* __restrict__ A, int n) {
  int node = blockIdx.x * 16 + (threadIdx.x >> 4);
  if (node >= n) return;
  int j = (threadIdx.x & 15) * 8;
  int cnt = cntC[node];
  float dc = dinv[node];
  const int4* ep = (const int4*)&ell[(size_t)node * ELLCAP];
  float a0[8] = {0, 0, 0, 0, 0, 0, 0, 0};
  float a1[8] = {0, 0, 0, 0, 0, 0, 0, 0};
  float a2[8] = {0, 0, 0, 0, 0, 0, 0, 0};
  float a3[8] = {0, 0, 0, 0, 0, 0, 0, 0};
  for (int base = 0; base < cnt; base += 4) {
    int4 rr = ep[base >> 2];
    float g0 = dinv[rr.x];
    float g1 = (base + 1 < cnt) ? dinv[rr.y] : 0.f;
    float g2 = (base + 2 < cnt) ? dinv[rr.z] : 0.f;
    float g3 = (base + 3 < cnt) ? dinv[rr.w] : 0.f;
    short8 v0 = *(const short8*)&B[(size_t)rr.x * F + j];
    short8 v1 = *(const short8*)&B[(size_t)rr.y * F + j];
    short8 v2 = *(const short8*)&B[(size_t)rr.z * F + j];
    short8 v3 = *(const short8*)&B[(size_t)rr.w * F + j];
#pragma unroll
    for (int q = 0; q < 8; ++q) {
      a0[q] += g0 * bf2f((ushort)v0[q]);
      a1[q] += g1 * bf2f((ushort)v1[q]);
      a2[q] += g2 * bf2f((ushort)v2[q]);
      a3[q] += g3 * bf2f((ushort)v3[q]);
    }
  }
  float id = invdeg[node];
  short8 sv = *(const short8*)&B[(size_t)node * F + j];
  float4 b0 = *(const float4*)&bc[j];
  float4 b1 = *(const float4*)&bc[j + 4];
  float bcv[8] = {b0.x, b0.y, b0.z, b0.w, b1.x, b1.y, b1.z, b1.w};
  ushort o[8];
#pragma unroll
  for (int q = 0; q < 8; ++q) {
    float s = dc * ((a0[q] + a1[q]) + (a2[q] + a3[q]));
    o[q] = f2bf(fmaxf((s + bf2f((ushort)sv[q]) * id) * id + bcv[q], 0.f));
  }
  *(short8*)&A[(size_t)node * F + j] = *(short8*)o;
}

// ---------------- logits via MFMA + fused log_softmax (bf16 input, hi+lo W) ----------------
__global__ __launch_bounds__(256) void logits_mfma(const ushort* __restrict__ X,
    const ushort* __restrict__ W2h, const ushort* __restrict__ W2l,
    const float* __restrict__ b2, float* __restrict__ out, int nrows) {
  __shared__ ushort sWh[6144], sWl[6144];
  __shared__ float b2s[48];
  const int t = threadIdx.x;
#pragma unroll
  for (int pp = 0; pp < 3; ++pp) {
    int c = t + pp * 256;
    *(short8*)&sWh[c * 8] = *(const short8*)&W2h[(size_t)c * 8];
    *(short8*)&sWl[c * 8] = *(const short8*)&W2l[(size_t)c * 8];
  }
  if (t < 48) b2s[t] = (t < C_CLS) ? b2[t] : -1e30f;
  __syncthreads();

  const int w = t >> 6, lane = t & 63;
  const int quad = lane >> 4, cl = lane & 15;
  const int row0 = (blockIdx.x * 4 + w) * 16;

  float4v acc[3];
#pragma unroll
  for (int ct = 0; ct < 3; ++ct) acc[ct] = (float4v){0.f, 0.f, 0.f, 0.f};

#pragma unroll
  for (int ks = 0; ks < 4; ++ks) {
    int gr = row0 + cl;
    short8 a;
    if (gr < nrows) a = *(const short8*)&X[(size_t)gr * F + ks * 32 + quad * 8];
    else a = (short8){0, 0, 0, 0, 0, 0, 0, 0};
#pragma unroll
    for (int ct = 0; ct < 3; ++ct) {
      int chunk = ((ct * 4 + ks) * 64 + lane) * 8;
      short8 b_h = *(short8*)&sWh[chunk];
      short8 b_l = *(short8*)&sWl[chunk];
      acc[ct] = __builtin_amdgcn_mfma_f32_16x16x32_bf16(a, b_h, acc[ct], 0, 0, 0);
      acc[ct] = __builtin_amdgcn_mfma_f32_16x16x32_bf16(a, b_l, acc[ct], 0, 0, 0);
    }
  }

  float b0 = b2s[cl], b1 = b2s[16 + cl], b2v = b2s[32 + cl];
  float lse[4];
#pragma unroll
  for (int reg = 0; reg < 4; ++reg) {
    float v0 = acc[0][reg] + b0;
    float v1 = acc[1][reg] + b1;
    float v2 = acc[2][reg] + b2v;
    acc[0][reg] = v0; acc[1][reg] = v1; acc[2][reg] = v2;
    float m = fmaxf(fmaxf(v0, v1), v2);
#pragma unroll
    for (int o = 1; o < 16; o <<= 1) m = fmaxf(m, __shfl_xor(m, o));
    float s = __expf(v0 - m) + __expf(v1 - m) + __expf(v2 - m);
#pragma unroll
    for (int o = 1; o < 16; o <<= 1) s += __shfl_xor(s, o);
    lse[reg] = logf(s) + m;
  }
#pragma unroll
  for (int reg = 0; reg < 4; ++reg) {
    int gr = row0 + quad * 4 + reg;
    if (gr < nrows) {
      out[(size_t)gr * C_CLS + cl] = acc[0][reg] - lse[reg];
      out[(size_t)gr * C_CLS + 16 + cl] = acc[1][reg] - lse[reg];
      if (cl < 8) out[(size_t)gr * C_CLS + 32 + cl] = acc[2][reg] - lse[reg];
    }
  }
}

extern "C" void kernel_launch(void* const* d_in, const int* in_sizes, int n_in,
                              void* d_out, int out_size, void* d_ws, size_t ws_size,
                              hipStream_t stream) {
  const float* x    = (const float*)d_in[0];
  const int*   ei   = (const int*)d_in[1];
  const float* imp  = (const float*)d_in[2];
  const float* W1   = (const float*)d_in[3];
  const float* bl1  = (const float*)d_in[4];
  const float* bc1  = (const float*)d_in[5];
  const float* W2   = (const float*)d_in[6];
  const float* bl2  = (const float*)d_in[7];
  const float* bc2  = (const float*)d_in[8];
  const float* W3   = (const float*)d_in[9];
  const float* bl3  = (const float*)d_in[10];
  const float* bc3  = (const float*)d_in[11];
  const float* Wl1  = (const float*)d_in[12];
  const float* bli1 = (const float*)d_in[13];
  const float* Wl2  = (const float*)d_in[14];
  const float* bli2 = (const float*)d_in[15];
  float* out = (float*)d_out;

  const int N = in_sizes[0] / F;      // 100000
  const int E = in_sizes[1] / 2;      // 600000

  ushort* A16 = (ushort*)d_ws;                 // N*F
  ushort* B16 = A16 + (size_t)N * F;           // N*F
  ushort* WhP = B16 + (size_t)N * F;           // 8192*8
  ushort* W2hH = WhP + 65536;                  // 768*8
  ushort* W2lH = W2hH + 6144;                  // 768*8
  float* dinv = (float*)(W2lH + 6144);         // N
  float* invdeg = dinv + N;                    // N
  int*   cntC = (int*)(invdeg + N);            // N
  int*   cntPad = cntC + N;                    // 16N (one ctr / 64B line)
  int*   ell  = cntPad + (size_t)16 * N;       // 32N
  // cntPad+ell contiguous: one memset zeroes both

  const int* rowv = ei;
  const int* colv = ei + E;

  int nbN  = (N + 255) / 256;
  int nbE  = (E + 255) / 256;
  int nbG  = (N + 255) / 256;
  int nbGa = (N + 15) / 16;
  int nbLo = (N + 63) / 64;

  // ---- one-time prep: zero counters+ELL, fused weight-split + one-pass ELL fill ----
  hipMemsetAsync(cntPad, 0, (size_t)48 * N * sizeof(int), stream);
  setup_kernel<<<NWSPLIT + nbE, 256, 0, stream>>>(
      W1, imp, W2, W3, Wl1, Wl2, WhP, W2hH, W2lH, rowv, colv, cntPad, ell, E, N);
  dinv_kernel<<<nbN, 256, 0, stream>>>(cntPad, cntC, dinv, invdeg, N);

  // ---- conv layer 1 (reads fp32 x directly; importance folded into WhP) ----
  gemm_any<true><<<nbG, 256, 0, stream>>>(x, WhP, bl1, B16, N, 0);
  gather_kernel<<<nbGa, 256, 0, stream>>>(cntC, ell, B16, dinv, invdeg, bc1, A16, N);

  // ---- conv layer 2 ----
  gemm_any<false><<<nbG, 256, 0, stream>>>(A16, WhP + 16384, bl2, B16, N, 0);
  gather_kernel<<<nbGa, 256, 0, stream>>>(cntC, ell, B16, dinv, invdeg, bc2, A16, N);

  // ---- conv layer 3 ----
  gemm_any<false><<<nbG, 256, 0, stream>>>(A16, WhP + 32768, bl3, B16, N, 0);
  gather_kernel<<<nbGa, 256, 0, stream>>>(cntC, ell, B16, dinv, invdeg, bc3, A16, N);

  // ---- dense head ----
  gemm_any<false><<<nbG, 256, 0, stream>>>(A16, WhP + 49152, bli1, B16, N, 1);
  logits_mfma<<<nbLo, 256, 0, stream>>>(B16, W2hH, W2lH, bli2, out, N);
}